// Round 4
// baseline (5961.740 us; speedup 1.0000x reference)
//
#include <hip/hip_runtime.h>
#include <hip/hip_bf16.h>

#define PI2F 9.869604401089358f

__device__ inline float gelu_tanh(float v) {
    float u = 0.7978845608028654f * (v + 0.044715f * v * v * v);
    float th = 1.f - 2.f / (1.f + __expf(2.f * u));
    return 0.5f * v * (1.f + th);
}

// =============== Kernel A: unfold + separable circular blur + conv0 + leaky + GN(G=4) ===========
__global__ __launch_bounds__(256) void k_blur_conv0(
    const float* __restrict__ img, const float* __restrict__ bfac,
    const float* __restrict__ w0, const float* __restrict__ b0c,
    const float* __restrict__ g1, const float* __restrict__ be1,
    float* __restrict__ d0)
{
    __shared__ float pa[512], pb[512], w0s[2048], d0s[2048], hsm[8];
    __shared__ float2 gstat[4];
    const int t = threadIdx.x, blk = blockIdx.x;
    const int b = blk >> 9, rem = blk & 511;
    const int zh = rem >> 6, yh = (rem >> 3) & 7, xh = rem & 7;

    #pragma unroll
    for (int i = 0; i < 2; i++) {
        int v = t + 256 * i;
        int z = v >> 6, y = (v >> 3) & 7, x = v & 7;
        pa[v] = img[(((size_t)(b * 8 + zh) * 8 + z) * 64 + yh * 8 + y) * 64 + xh * 8 + x];
    }
    for (int i = t; i < 2048; i += 256) w0s[i] = w0[i];
    if (t < 8) {
        float bf = bfac[blk];
        float c = bf * PI2F * (1.0f / 16.0f);
        float gk1 = __expf(-c), gk2 = __expf(-4.f * c), gk3 = __expf(-9.f * c), gk4 = __expf(-16.f * c);
        float d = (float)t;
        float h = 1.f + 2.f * (gk1 * cosf(0.7853981633974483f * d)
                             + gk2 * cosf(1.5707963267948966f * d)
                             + gk3 * cosf(2.356194490192345f * d))
                      + gk4 * cosf(3.141592653589793f * d);
        hsm[t] = 0.125f * h;
    }
    __syncthreads();
    // blur along x
    #pragma unroll
    for (int i = 0; i < 2; i++) {
        int v = t + 256 * i; int x = v & 7; int base = v & ~7;
        float s = 0.f;
        #pragma unroll
        for (int m = 0; m < 8; m++) s += hsm[(x - m) & 7] * pa[base + m];
        pb[v] = s;
    }
    __syncthreads();
    // blur along y
    #pragma unroll
    for (int i = 0; i < 2; i++) {
        int v = t + 256 * i; int y = (v >> 3) & 7; int base = (v & ~63) | (v & 7);
        float s = 0.f;
        #pragma unroll
        for (int m = 0; m < 8; m++) s += hsm[(y - m) & 7] * pb[base + m * 8];
        pa[v] = s;
    }
    __syncthreads();
    // blur along z
    #pragma unroll
    for (int i = 0; i < 2; i++) {
        int v = t + 256 * i; int z = v >> 6; int base = v & 63;
        float s = 0.f;
        #pragma unroll
        for (int m = 0; m < 8; m++) s += hsm[(z - m) & 7] * pa[base + m * 64];
        pb[v] = s;
    }
    __syncthreads();
    // conv0 (1->32ch, 4^3 k, stride2, pad1) + leaky
    #pragma unroll
    for (int i = 0; i < 8; i++) {
        int oi = t + 256 * i;
        int c = oi >> 6, vox = oi & 63;
        int oz = vox >> 4, oy = (vox >> 2) & 3, ox = vox & 3;
        float s = b0c[c];
        #pragma unroll
        for (int kz = 0; kz < 4; kz++) {
            int sz = 2 * oz - 1 + kz; if (sz < 0 || sz > 7) continue;
            #pragma unroll
            for (int ky = 0; ky < 4; ky++) {
                int sy = 2 * oy - 1 + ky; if (sy < 0 || sy > 7) continue;
                #pragma unroll
                for (int kx = 0; kx < 4; kx++) {
                    int sx = 2 * ox - 1 + kx; if (sx < 0 || sx > 7) continue;
                    s += pb[sz * 64 + sy * 8 + sx] * w0s[c * 64 + kz * 16 + ky * 4 + kx];
                }
            }
        }
        s = s >= 0.f ? s : 0.2f * s;
        d0s[oi] = s;
    }
    __syncthreads();
    // GroupNorm: 4 groups of (8ch x 64vox)=512, one wave per group
    {
        int g = t >> 6, lane = t & 63;
        float s = 0.f, sq = 0.f;
        #pragma unroll
        for (int j = 0; j < 8; j++) { float v = d0s[g * 512 + lane + 64 * j]; s += v; sq += v * v; }
        #pragma unroll
        for (int m = 1; m < 64; m <<= 1) { s += __shfl_xor(s, m, 64); sq += __shfl_xor(sq, m, 64); }
        if (lane == 0) {
            float mean = s * (1.f / 512.f);
            float var = sq * (1.f / 512.f) - mean * mean;
            gstat[g] = make_float2(mean, rsqrtf(var + 1e-5f));
        }
    }
    __syncthreads();
    size_t obase = (size_t)blk * 2048;
    #pragma unroll
    for (int i = 0; i < 8; i++) {
        int oi = t + 256 * i;
        int c = oi >> 6;
        float2 st = gstat[oi >> 9];
        d0[obase + oi] = (d0s[oi] - st.x) * st.y * g1[c] + be1[c];
    }
}

// ====== Kernel B (direct): conv1 (32->64, 4^3 s2 p1) + leaky + GN(G=2). 1 block = 1 patch ======
__global__ __launch_bounds__(512) void k_conv1(
    const float* __restrict__ d0, const float* __restrict__ w1g,
    const float* __restrict__ b1c, const float* __restrict__ g2, const float* __restrict__ be2,
    float* __restrict__ d1)
{
    __shared__ float d0s[2048];
    __shared__ float wsum[8], wsqs[8];
    const int t = threadIdx.x;
    const int p = blockIdx.x;
    #pragma unroll
    for (int i = 0; i < 4; i++) d0s[t + 512 * i] = d0[(size_t)p * 2048 + t + 512 * i];
    __syncthreads();
    const int c = t >> 3, vox = t & 7;
    const int oz = vox >> 2, oy = (vox >> 1) & 1, ox = vox & 1;
    const int z0 = oz, y0 = oy, x0 = ox;
    const int kzo = 1 - 2 * oz, kyo = 1 - 2 * oy, kxo = 1 - 2 * ox;
    float s = b1c[c];
    const float* wc = w1g + (size_t)c * 2048;
    for (int ci = 0; ci < 32; ci++) {
        const float* dci = d0s + ci * 64;
        const float* wci = wc + ci * 64;
        #pragma unroll
        for (int dz = 0; dz < 3; dz++) {
            int sz = z0 + dz, kz = sz + kzo;
            #pragma unroll
            for (int dy = 0; dy < 3; dy++) {
                int sy = y0 + dy, ky = sy + kyo;
                #pragma unroll
                for (int dx = 0; dx < 3; dx++) {
                    int sx = x0 + dx, kx = sx + kxo;
                    s += dci[sz * 16 + sy * 4 + sx] * wci[kz * 16 + ky * 4 + kx];
                }
            }
        }
    }
    s = s >= 0.f ? s : 0.2f * s;
    float sv = s, sq = s * s;
    #pragma unroll
    for (int m = 1; m < 64; m <<= 1) { sv += __shfl_xor(sv, m, 64); sq += __shfl_xor(sq, m, 64); }
    if ((t & 63) == 0) { wsum[t >> 6] = sv; wsqs[t >> 6] = sq; }
    __syncthreads();
    const int g = t >> 8;
    float gs = wsum[g * 4] + wsum[g * 4 + 1] + wsum[g * 4 + 2] + wsum[g * 4 + 3];
    float gq = wsqs[g * 4] + wsqs[g * 4 + 1] + wsqs[g * 4 + 2] + wsqs[g * 4 + 3];
    float mean = gs * (1.f / 256.f);
    float rs = rsqrtf(gq * (1.f / 256.f) - mean * mean + 1e-5f);
    d1[(size_t)p * 512 + t] = (s - mean) * rs * g2[c] + be2[c];
}

// ====== Kernel C (direct): conv2(64->128 -> 1^3)+leaky+GN(G=1)+convu(128->256)+LN(u)+LN(pos) ===
__global__ __launch_bounds__(256) void k_conv2_u_x(
    const float* __restrict__ d1, const float* __restrict__ w2g, const float* __restrict__ b2c,
    const float* __restrict__ g3, const float* __restrict__ be3,
    const float* __restrict__ wu, const float* __restrict__ bu,
    const float* __restrict__ pos, const float* __restrict__ lndg, const float* __restrict__ lndb,
    const float* __restrict__ lnpg, const float* __restrict__ lnpb,
    float* __restrict__ xb)
{
    __shared__ float d1s[512];
    __shared__ float d2s[128];
    __shared__ float red[4];
    __shared__ float stats[2];
    __shared__ float red2[16];
    const int t = threadIdx.x;
    const int p = blockIdx.x;
    d1s[t] = d1[(size_t)p * 512 + t];
    d1s[t + 256] = d1[(size_t)p * 512 + t + 256];
    __syncthreads();
    float dv = 0.f;
    if (t < 128) {
        float s = b2c[t];
        const float* wcc = w2g + (size_t)t * 4096;
        for (int ci = 0; ci < 64; ci++) {
            #pragma unroll
            for (int z = 0; z < 2; z++)
                #pragma unroll
                for (int y = 0; y < 2; y++)
                    #pragma unroll
                    for (int x = 0; x < 2; x++)
                        s += d1s[ci * 8 + z * 4 + y * 2 + x]
                           * wcc[ci * 64 + (z + 1) * 16 + (y + 1) * 4 + (x + 1)];
        }
        dv = s >= 0.f ? s : 0.2f * s;
    }
    {
        float sv = (t < 128) ? dv : 0.f, sq = (t < 128) ? dv * dv : 0.f;
        #pragma unroll
        for (int m = 1; m < 64; m <<= 1) { sv += __shfl_xor(sv, m, 64); sq += __shfl_xor(sq, m, 64); }
        if (t < 128 && (t & 63) == 0) { red[(t >> 6)] = sv; red[(t >> 6) + 2] = sq; }
    }
    __syncthreads();
    if (t == 0) {
        float gs = red[0] + red[1];
        float gq = red[2] + red[3];
        float mean = gs * (1.f / 128.f);
        stats[0] = mean;
        stats[1] = rsqrtf(gq * (1.f / 128.f) - mean * mean + 1e-5f);
    }
    __syncthreads();
    if (t < 128) d2s[t] = (dv - stats[0]) * stats[1] * g3[t] + be3[t];
    __syncthreads();
    float u = bu[t];
    {
        const float* wut = wu + (size_t)t * 128;
        #pragma unroll 4
        for (int ci = 0; ci < 128; ci++) u += d2s[ci] * wut[ci];
    }
    const int p512 = p & 511;
    float pe = pos[(size_t)p512 * 256 + t];
    float su = u, squ = u * u, sp = pe, sqp = pe * pe;
    #pragma unroll
    for (int m = 1; m < 64; m <<= 1) {
        su += __shfl_xor(su, m, 64); squ += __shfl_xor(squ, m, 64);
        sp += __shfl_xor(sp, m, 64); sqp += __shfl_xor(sqp, m, 64);
    }
    if ((t & 63) == 0) {
        int w = t >> 6;
        red2[w] = su; red2[4 + w] = squ; red2[8 + w] = sp; red2[12 + w] = sqp;
    }
    __syncthreads();
    float tsu = red2[0] + red2[1] + red2[2] + red2[3];
    float tsq = red2[4] + red2[5] + red2[6] + red2[7];
    float tsp = red2[8] + red2[9] + red2[10] + red2[11];
    float tqp = red2[12] + red2[13] + red2[14] + red2[15];
    float mu = tsu * (1.f / 256.f), ru = rsqrtf(tsq * (1.f / 256.f) - mu * mu + 1e-5f);
    float mp = tsp * (1.f / 256.f), rp = rsqrtf(tqp * (1.f / 256.f) - mp * mp + 1e-5f);
    float xv = (u - mu) * ru * lndg[t] + lndb[t] + (pe - mp) * rp * lnpg[t] + lnpb[t];
    xb[(size_t)p * 256 + t] = xv;
}

// =============== LayerNorm over 256 cols, one wave per row ===============
__global__ __launch_bounds__(256) void k_ln(
    const float* __restrict__ xin, const float* __restrict__ g, const float* __restrict__ b,
    float* __restrict__ out)
{
    const int t = threadIdx.x;
    const int row = blockIdx.x * 4 + (t >> 6);
    const int lane = t & 63;
    float4 v = ((const float4*)(xin + (size_t)row * 256))[lane];
    float s = v.x + v.y + v.z + v.w;
    float sq = v.x * v.x + v.y * v.y + v.z * v.z + v.w * v.w;
    #pragma unroll
    for (int m = 1; m < 64; m <<= 1) { s += __shfl_xor(s, m, 64); sq += __shfl_xor(sq, m, 64); }
    float mean = s * (1.f / 256.f);
    float rs = rsqrtf(sq * (1.f / 256.f) - mean * mean + 1e-5f);
    float4 gv = ((const float4*)g)[lane], bv = ((const float4*)b)[lane];
    float4 o;
    o.x = (v.x - mean) * rs * gv.x + bv.x;
    o.y = (v.y - mean) * rs * gv.y + bv.y;
    o.z = (v.z - mean) * rs * gv.z + bv.z;
    o.w = (v.w - mean) * rs * gv.w + bv.w;
    ((float4*)(out + (size_t)row * 256))[lane] = o;
}

// =============== Generic SIMT GEMM: C = act(A@W + bias) (+res). 64x64 tile, BK=32 ===============
__global__ __launch_bounds__(256) void k_gemm(
    const float* __restrict__ A, const float* __restrict__ W, const float* __restrict__ bias,
    const float* __restrict__ res, float* __restrict__ C,
    int M, int N, int K, int act)
{
    __shared__ float At[64][36];
    __shared__ float Wt[32][68];
    const int t = threadIdx.x;
    const int r0 = blockIdx.y * 64, c0 = blockIdx.x * 64;
    const int tr = t >> 4, tc = t & 15;
    float acc[4][4] = {};
    for (int k0 = 0; k0 < K; k0 += 32) {
        __syncthreads();
        {
            int r = t >> 2, kk0 = (t & 3) * 8;
            const float* src = A + (size_t)(r0 + r) * K + k0 + kk0;
            #pragma unroll
            for (int u = 0; u < 8; u++) At[r][kk0 + u] = src[u];
        }
        {
            int kk = t >> 3, cc0 = (t & 7) * 8;
            const float* src = W + (size_t)(k0 + kk) * N + c0 + cc0;
            #pragma unroll
            for (int u = 0; u < 8; u++) Wt[kk][cc0 + u] = src[u];
        }
        __syncthreads();
        #pragma unroll
        for (int k4 = 0; k4 < 8; k4++) {
            float4 a4[4];
            #pragma unroll
            for (int i = 0; i < 4; i++) a4[i] = *(const float4*)&At[tr * 4 + i][k4 * 4];
            #pragma unroll
            for (int kl = 0; kl < 4; kl++) {
                float4 w4 = *(const float4*)&Wt[k4 * 4 + kl][tc * 4];
                #pragma unroll
                for (int i = 0; i < 4; i++) {
                    float av = (kl == 0) ? a4[i].x : (kl == 1) ? a4[i].y : (kl == 2) ? a4[i].z : a4[i].w;
                    acc[i][0] += av * w4.x; acc[i][1] += av * w4.y;
                    acc[i][2] += av * w4.z; acc[i][3] += av * w4.w;
                }
            }
        }
    }
    float4 bv = *(const float4*)(bias + c0 + tc * 4);
    #pragma unroll
    for (int i = 0; i < 4; i++) {
        size_t off = (size_t)(r0 + tr * 4 + i) * N + c0 + tc * 4;
        float4 v;
        v.x = acc[i][0] + bv.x; v.y = acc[i][1] + bv.y;
        v.z = acc[i][2] + bv.z; v.w = acc[i][3] + bv.w;
        if (act == 1) { v.x = gelu_tanh(v.x); v.y = gelu_tanh(v.y); v.z = gelu_tanh(v.z); v.w = gelu_tanh(v.w); }
        if (res) {
            float4 rv = *(const float4*)(res + off);
            v.x += rv.x; v.y += rv.y; v.z += rv.z; v.w += rv.w;
        }
        *(float4*)(C + off) = v;
    }
}

// =============== Flash attention: H=8, hd=32, S=512. 1 block per (b,h); lane owns 2 q rows ======
__global__ __launch_bounds__(256) void k_attn(
    const float* __restrict__ qg, const float* __restrict__ kg, const float* __restrict__ vg,
    float* __restrict__ og)
{
    __shared__ float Ks[32][36];
    __shared__ float Vs[32][36];
    const int t = threadIdx.x;
    const int bid = blockIdx.x;
    const int b = bid >> 3, hh = bid & 7;
    const size_t q0 = (size_t)(b * 512 + t) * 256 + hh * 32;
    const size_t q1 = q0 + (size_t)256 * 256;
    float qr0[32], qr1[32], acc0[32], acc1[32];
    #pragma unroll
    for (int d4 = 0; d4 < 8; d4++) {
        float4 a = *(const float4*)(qg + q0 + d4 * 4);
        float4 c = *(const float4*)(qg + q1 + d4 * 4);
        qr0[d4 * 4 + 0] = a.x; qr0[d4 * 4 + 1] = a.y; qr0[d4 * 4 + 2] = a.z; qr0[d4 * 4 + 3] = a.w;
        qr1[d4 * 4 + 0] = c.x; qr1[d4 * 4 + 1] = c.y; qr1[d4 * 4 + 2] = c.z; qr1[d4 * 4 + 3] = c.w;
        acc0[d4 * 4 + 0] = 0.f; acc0[d4 * 4 + 1] = 0.f; acc0[d4 * 4 + 2] = 0.f; acc0[d4 * 4 + 3] = 0.f;
        acc1[d4 * 4 + 0] = 0.f; acc1[d4 * 4 + 1] = 0.f; acc1[d4 * 4 + 2] = 0.f; acc1[d4 * 4 + 3] = 0.f;
    }
    float m0 = -1e30f, m1 = -1e30f, l0 = 0.f, l1 = 0.f;
    const float scale = 0.17677669529663687f;
    for (int kt = 0; kt < 16; kt++) {
        __syncthreads();
        {
            int kk = t >> 3, dd = (t & 7) * 4;
            size_t base = (size_t)(b * 512 + kt * 32 + kk) * 256 + hh * 32 + dd;
            *(float4*)&Ks[kk][dd] = *(const float4*)(kg + base);
            *(float4*)&Vs[kk][dd] = *(const float4*)(vg + base);
        }
        __syncthreads();
        float s0[32], s1[32];
        #pragma unroll
        for (int kk = 0; kk < 32; kk++) {
            float d0 = 0.f, d1v = 0.f;
            #pragma unroll
            for (int d4 = 0; d4 < 8; d4++) {
                float4 kf = *(const float4*)&Ks[kk][d4 * 4];
                d0 += qr0[d4 * 4 + 0] * kf.x + qr0[d4 * 4 + 1] * kf.y + qr0[d4 * 4 + 2] * kf.z + qr0[d4 * 4 + 3] * kf.w;
                d1v += qr1[d4 * 4 + 0] * kf.x + qr1[d4 * 4 + 1] * kf.y + qr1[d4 * 4 + 2] * kf.z + qr1[d4 * 4 + 3] * kf.w;
            }
            s0[kk] = d0 * scale; s1[kk] = d1v * scale;
        }
        float mt0 = s0[0], mt1 = s1[0];
        #pragma unroll
        for (int kk = 1; kk < 32; kk++) { mt0 = fmaxf(mt0, s0[kk]); mt1 = fmaxf(mt1, s1[kk]); }
        float mn0 = fmaxf(m0, mt0), mn1 = fmaxf(m1, mt1);
        float c0 = __expf(m0 - mn0), c1 = __expf(m1 - mn1);
        l0 *= c0; l1 *= c1;
        #pragma unroll
        for (int d = 0; d < 32; d++) { acc0[d] *= c0; acc1[d] *= c1; }
        #pragma unroll
        for (int kk = 0; kk < 32; kk++) {
            float p0 = __expf(s0[kk] - mn0), p1 = __expf(s1[kk] - mn1);
            l0 += p0; l1 += p1;
            #pragma unroll
            for (int d4 = 0; d4 < 8; d4++) {
                float4 vf = *(const float4*)&Vs[kk][d4 * 4];
                acc0[d4 * 4 + 0] += p0 * vf.x; acc0[d4 * 4 + 1] += p0 * vf.y;
                acc0[d4 * 4 + 2] += p0 * vf.z; acc0[d4 * 4 + 3] += p0 * vf.w;
                acc1[d4 * 4 + 0] += p1 * vf.x; acc1[d4 * 4 + 1] += p1 * vf.y;
                acc1[d4 * 4 + 2] += p1 * vf.z; acc1[d4 * 4 + 3] += p1 * vf.w;
            }
        }
        m0 = mn0; m1 = mn1;
    }
    float i0 = 1.f / l0, i1 = 1.f / l1;
    #pragma unroll
    for (int d4 = 0; d4 < 8; d4++) {
        float4 o0, o1;
        o0.x = acc0[d4 * 4 + 0] * i0; o0.y = acc0[d4 * 4 + 1] * i0;
        o0.z = acc0[d4 * 4 + 2] * i0; o0.w = acc0[d4 * 4 + 3] * i0;
        o1.x = acc1[d4 * 4 + 0] * i1; o1.y = acc1[d4 * 4 + 1] * i1;
        o1.z = acc1[d4 * 4 + 2] * i1; o1.w = acc1[d4 * 4 + 3] * i1;
        *(float4*)(og + q0 + d4 * 4) = o0;
        *(float4*)(og + q1 + d4 * 4) = o1;
    }
}

extern "C" void kernel_launch(void* const* d_in, const int* in_sizes, int n_in,
                              void* d_out, int out_size, void* d_ws, size_t ws_size,
                              hipStream_t stream)
{
    const float* img  = (const float*)d_in[0];
    const float* bfac = (const float*)d_in[1];
    const float* w0  = (const float*)d_in[2];  const float* b0c = (const float*)d_in[3];
    const float* g1  = (const float*)d_in[4];  const float* be1 = (const float*)d_in[5];
    const float* w1  = (const float*)d_in[6];  const float* b1c = (const float*)d_in[7];
    const float* g2  = (const float*)d_in[8];  const float* be2 = (const float*)d_in[9];
    const float* w2  = (const float*)d_in[10]; const float* b2c = (const float*)d_in[11];
    const float* g3  = (const float*)d_in[12]; const float* be3 = (const float*)d_in[13];
    const float* wu  = (const float*)d_in[14]; const float* bu  = (const float*)d_in[15];
    const float* pos = (const float*)d_in[16];
    const float* lndg = (const float*)d_in[17]; const float* lndb = (const float*)d_in[18];
    const float* lnpg = (const float*)d_in[19]; const float* lnpb = (const float*)d_in[20];
    const float* Wq = (const float*)d_in[21]; const float* bq = (const float*)d_in[22];
    const float* Wk = (const float*)d_in[23]; const float* bk = (const float*)d_in[24];
    const float* Wv = (const float*)d_in[25]; const float* bv = (const float*)d_in[26];
    const float* Wo = (const float*)d_in[27]; const float* bo = (const float*)d_in[28];
    const float* l1g = (const float*)d_in[29]; const float* l1b = (const float*)d_in[30];
    const float* l2g = (const float*)d_in[31]; const float* l2b = (const float*)d_in[32];
    const float* W1 = (const float*)d_in[33]; const float* bf1 = (const float*)d_in[34];
    const float* W2 = (const float*)d_in[35]; const float* bf2 = (const float*)d_in[36];

    float* ws  = (float*)d_ws;
    float* d0b = ws;                       // 16,777,216 floats
    float* d1b = ws + 16777216;            //  4,194,304
    float* xb  = ws + 20971520;            //  2,097,152
    float* hb  = ws;                       //  reuse (phase D)
    float* qb  = ws + 2097152;
    float* kb  = ws + 4194304;
    float* vb  = ws + 6291456;
    float* ob  = ws + 8388608;
    float* m1b = ws + 10485760;            //  8,388,608 -> ends 18,874,368 < 20,971,520
    float* xout = (float*)d_out;           //  final x is float32, written directly

    k_blur_conv0<<<8192, 256, 0, stream>>>(img, bfac, w0, b0c, g1, be1, d0b);
    k_conv1<<<8192, 512, 0, stream>>>(d0b, w1, b1c, g2, be2, d1b);
    k_conv2_u_x<<<8192, 256, 0, stream>>>(d1b, w2, b2c, g3, be3, wu, bu, pos,
                                          lndg, lndb, lnpg, lnpb, xb);
    dim3 g256(4, 128), g1024(16, 128);
    for (int i = 0; i < 8; i++) {
        k_ln<<<2048, 256, 0, stream>>>(xb, l1g + i * 256, l1b + i * 256, hb);
        k_gemm<<<g256, 256, 0, stream>>>(hb, Wq + (size_t)i * 65536, bq + i * 256, nullptr, qb, 8192, 256, 256, 0);
        k_gemm<<<g256, 256, 0, stream>>>(hb, Wk + (size_t)i * 65536, bk + i * 256, nullptr, kb, 8192, 256, 256, 0);
        k_gemm<<<g256, 256, 0, stream>>>(hb, Wv + (size_t)i * 65536, bv + i * 256, nullptr, vb, 8192, 256, 256, 0);
        k_attn<<<128, 256, 0, stream>>>(qb, kb, vb, ob);
        k_gemm<<<g256, 256, 0, stream>>>(ob, Wo + (size_t)i * 65536, bo + i * 256, xb, xb, 8192, 256, 256, 0);
        k_ln<<<2048, 256, 0, stream>>>(xb, l2g + i * 256, l2b + i * 256, hb);
        k_gemm<<<g1024, 256, 0, stream>>>(hb, W1 + (size_t)i * 262144, bf1 + i * 1024, nullptr, m1b, 8192, 1024, 256, 1);
        float* outC = (i == 7) ? xout : xb;
        k_gemm<<<g256, 256, 0, stream>>>(m1b, W2 + (size_t)i * 262144, bf2 + i * 256, xb, outC, 8192, 256, 1024, 0);
    }
}

// Round 5
// 3746.139 us; speedup vs baseline: 1.5914x; 1.5914x over previous
//
#include <hip/hip_runtime.h>
#include <hip/hip_bf16.h>

#define PI2F 9.869604401089358f

__device__ inline float gelu_tanh(float v) {
    float u = 0.7978845608028654f * (v + 0.044715f * v * v * v);
    float th = 1.f - 2.f / (1.f + __expf(2.f * u));
    return 0.5f * v * (1.f + th);
}

// =============== Kernel A: unfold + separable circular blur + conv0 + leaky + GN(G=4) ===========
__global__ __launch_bounds__(256) void k_blur_conv0(
    const float* __restrict__ img, const float* __restrict__ bfac,
    const float* __restrict__ w0, const float* __restrict__ b0c,
    const float* __restrict__ g1, const float* __restrict__ be1,
    float* __restrict__ d0)
{
    __shared__ float pa[512], pb[512], w0s[2048], d0s[2048], hsm[8];
    __shared__ float2 gstat[4];
    const int t = threadIdx.x, blk = blockIdx.x;
    const int b = blk >> 9, rem = blk & 511;
    const int zh = rem >> 6, yh = (rem >> 3) & 7, xh = rem & 7;

    #pragma unroll
    for (int i = 0; i < 2; i++) {
        int v = t + 256 * i;
        int z = v >> 6, y = (v >> 3) & 7, x = v & 7;
        pa[v] = img[(((size_t)(b * 8 + zh) * 8 + z) * 64 + yh * 8 + y) * 64 + xh * 8 + x];
    }
    for (int i = t; i < 2048; i += 256) w0s[i] = w0[i];
    if (t < 8) {
        float bf = bfac[blk];
        float c = bf * PI2F * (1.0f / 16.0f);
        float gk1 = __expf(-c), gk2 = __expf(-4.f * c), gk3 = __expf(-9.f * c), gk4 = __expf(-16.f * c);
        float d = (float)t;
        float h = 1.f + 2.f * (gk1 * cosf(0.7853981633974483f * d)
                             + gk2 * cosf(1.5707963267948966f * d)
                             + gk3 * cosf(2.356194490192345f * d))
                      + gk4 * cosf(3.141592653589793f * d);
        hsm[t] = 0.125f * h;
    }
    __syncthreads();
    #pragma unroll
    for (int i = 0; i < 2; i++) {
        int v = t + 256 * i; int x = v & 7; int base = v & ~7;
        float s = 0.f;
        #pragma unroll
        for (int m = 0; m < 8; m++) s += hsm[(x - m) & 7] * pa[base + m];
        pb[v] = s;
    }
    __syncthreads();
    #pragma unroll
    for (int i = 0; i < 2; i++) {
        int v = t + 256 * i; int y = (v >> 3) & 7; int base = (v & ~63) | (v & 7);
        float s = 0.f;
        #pragma unroll
        for (int m = 0; m < 8; m++) s += hsm[(y - m) & 7] * pb[base + m * 8];
        pa[v] = s;
    }
    __syncthreads();
    #pragma unroll
    for (int i = 0; i < 2; i++) {
        int v = t + 256 * i; int z = v >> 6; int base = v & 63;
        float s = 0.f;
        #pragma unroll
        for (int m = 0; m < 8; m++) s += hsm[(z - m) & 7] * pa[base + m * 64];
        pb[v] = s;
    }
    __syncthreads();
    #pragma unroll
    for (int i = 0; i < 8; i++) {
        int oi = t + 256 * i;
        int c = oi >> 6, vox = oi & 63;
        int oz = vox >> 4, oy = (vox >> 2) & 3, ox = vox & 3;
        float s = b0c[c];
        #pragma unroll
        for (int kz = 0; kz < 4; kz++) {
            int sz = 2 * oz - 1 + kz; if (sz < 0 || sz > 7) continue;
            #pragma unroll
            for (int ky = 0; ky < 4; ky++) {
                int sy = 2 * oy - 1 + ky; if (sy < 0 || sy > 7) continue;
                #pragma unroll
                for (int kx = 0; kx < 4; kx++) {
                    int sx = 2 * ox - 1 + kx; if (sx < 0 || sx > 7) continue;
                    s += pb[sz * 64 + sy * 8 + sx] * w0s[c * 64 + kz * 16 + ky * 4 + kx];
                }
            }
        }
        s = s >= 0.f ? s : 0.2f * s;
        d0s[oi] = s;
    }
    __syncthreads();
    {
        int g = t >> 6, lane = t & 63;
        float s = 0.f, sq = 0.f;
        #pragma unroll
        for (int j = 0; j < 8; j++) { float v = d0s[g * 512 + lane + 64 * j]; s += v; sq += v * v; }
        #pragma unroll
        for (int m = 1; m < 64; m <<= 1) { s += __shfl_xor(s, m, 64); sq += __shfl_xor(sq, m, 64); }
        if (lane == 0) {
            float mean = s * (1.f / 512.f);
            float var = sq * (1.f / 512.f) - mean * mean;
            gstat[g] = make_float2(mean, rsqrtf(var + 1e-5f));
        }
    }
    __syncthreads();
    size_t obase = (size_t)blk * 2048;
    #pragma unroll
    for (int i = 0; i < 8; i++) {
        int oi = t + 256 * i;
        int c = oi >> 6;
        float2 st = gstat[oi >> 9];
        d0[obase + oi] = (d0s[oi] - st.x) * st.y * g1[c] + be1[c];
    }
}

// ====== Kernel B (direct): conv1 (32->64, 4^3 s2 p1) + leaky + GN(G=2). 1 block = 1 patch ======
__global__ __launch_bounds__(512) void k_conv1(
    const float* __restrict__ d0, const float* __restrict__ w1g,
    const float* __restrict__ b1c, const float* __restrict__ g2, const float* __restrict__ be2,
    float* __restrict__ d1)
{
    __shared__ float d0s[2048];
    __shared__ float wsum[8], wsqs[8];
    const int t = threadIdx.x;
    const int p = blockIdx.x;
    #pragma unroll
    for (int i = 0; i < 4; i++) d0s[t + 512 * i] = d0[(size_t)p * 2048 + t + 512 * i];
    __syncthreads();
    const int c = t >> 3, vox = t & 7;
    const int oz = vox >> 2, oy = (vox >> 1) & 1, ox = vox & 1;
    const int z0 = oz, y0 = oy, x0 = ox;
    const int kzo = 1 - 2 * oz, kyo = 1 - 2 * oy, kxo = 1 - 2 * ox;
    float s = b1c[c];
    const float* wc = w1g + (size_t)c * 2048;
    for (int ci = 0; ci < 32; ci++) {
        const float* dci = d0s + ci * 64;
        const float* wci = wc + ci * 64;
        #pragma unroll
        for (int dz = 0; dz < 3; dz++) {
            int sz = z0 + dz, kz = sz + kzo;
            #pragma unroll
            for (int dy = 0; dy < 3; dy++) {
                int sy = y0 + dy, ky = sy + kyo;
                #pragma unroll
                for (int dx = 0; dx < 3; dx++) {
                    int sx = x0 + dx, kx = sx + kxo;
                    s += dci[sz * 16 + sy * 4 + sx] * wci[kz * 16 + ky * 4 + kx];
                }
            }
        }
    }
    s = s >= 0.f ? s : 0.2f * s;
    float sv = s, sq = s * s;
    #pragma unroll
    for (int m = 1; m < 64; m <<= 1) { sv += __shfl_xor(sv, m, 64); sq += __shfl_xor(sq, m, 64); }
    if ((t & 63) == 0) { wsum[t >> 6] = sv; wsqs[t >> 6] = sq; }
    __syncthreads();
    const int g = t >> 8;
    float gs = wsum[g * 4] + wsum[g * 4 + 1] + wsum[g * 4 + 2] + wsum[g * 4 + 3];
    float gq = wsqs[g * 4] + wsqs[g * 4 + 1] + wsqs[g * 4 + 2] + wsqs[g * 4 + 3];
    float mean = gs * (1.f / 256.f);
    float rs = rsqrtf(gq * (1.f / 256.f) - mean * mean + 1e-5f);
    d1[(size_t)p * 512 + t] = (s - mean) * rs * g2[c] + be2[c];
}

// =============== Prep: pack w2 (OIDHW, only inner 2^3 taps used) into [K=512][N=128] ===========
__global__ __launch_bounds__(256) void k_prep_w2(const float* __restrict__ w2g, float* __restrict__ w2gem)
{
    int idx = blockIdx.x * 256 + threadIdx.x;   // 65536
    int k = idx >> 7, n = idx & 127;
    int ci = k >> 3, z = (k >> 2) & 1, y = (k >> 1) & 1, x = k & 1;
    w2gem[idx] = w2g[(size_t)n * 4096 + ci * 64 + (z + 1) * 16 + (y + 1) * 4 + (x + 1)];
}

// =============== Prep: transpose wu [256 out][128 in] -> wuT [128][256] ===============
__global__ __launch_bounds__(256) void k_prep_wu(const float* __restrict__ wu, float* __restrict__ wuT)
{
    int idx = blockIdx.x * 256 + threadIdx.x;   // 32768
    int k = idx >> 8, n = idx & 255;
    wuT[idx] = wu[(size_t)n * 128 + k];
}

// =============== GroupNorm(G=1) over 128 cols + affine, in-place. Wave per row. ===============
__global__ __launch_bounds__(256) void k_gn3(
    float* __restrict__ d2, const float* __restrict__ g3, const float* __restrict__ be3)
{
    const int t = threadIdx.x;
    const int row = blockIdx.x * 4 + (t >> 6);
    const int lane = t & 63;
    float2 v = ((const float2*)(d2 + (size_t)row * 128))[lane];
    float s = v.x + v.y, sq = v.x * v.x + v.y * v.y;
    #pragma unroll
    for (int m = 1; m < 64; m <<= 1) { s += __shfl_xor(s, m, 64); sq += __shfl_xor(sq, m, 64); }
    float mean = s * (1.f / 128.f);
    float rs = rsqrtf(sq * (1.f / 128.f) - mean * mean + 1e-5f);
    float2 gv = ((const float2*)g3)[lane], bv = ((const float2*)be3)[lane];
    float2 o;
    o.x = (v.x - mean) * rs * gv.x + bv.x;
    o.y = (v.y - mean) * rs * gv.y + bv.y;
    ((float2*)(d2 + (size_t)row * 128))[lane] = o;
}

// =============== LN(u) + LN(pos[row&511]) -> xb. Wave per row. ===============
__global__ __launch_bounds__(256) void k_lnpos(
    const float* __restrict__ u, const float* __restrict__ pos,
    const float* __restrict__ lndg, const float* __restrict__ lndb,
    const float* __restrict__ lnpg, const float* __restrict__ lnpb,
    float* __restrict__ xb)
{
    const int t = threadIdx.x;
    const int row = blockIdx.x * 4 + (t >> 6);
    const int lane = t & 63;
    float4 v = ((const float4*)(u + (size_t)row * 256))[lane];
    float4 w = ((const float4*)(pos + (size_t)(row & 511) * 256))[lane];
    float s = v.x + v.y + v.z + v.w;
    float sq = v.x * v.x + v.y * v.y + v.z * v.z + v.w * v.w;
    float sp = w.x + w.y + w.z + w.w;
    float qp = w.x * w.x + w.y * w.y + w.z * w.z + w.w * w.w;
    #pragma unroll
    for (int m = 1; m < 64; m <<= 1) {
        s += __shfl_xor(s, m, 64); sq += __shfl_xor(sq, m, 64);
        sp += __shfl_xor(sp, m, 64); qp += __shfl_xor(qp, m, 64);
    }
    float mu = s * (1.f / 256.f), ru = rsqrtf(sq * (1.f / 256.f) - mu * mu + 1e-5f);
    float mp = sp * (1.f / 256.f), rp = rsqrtf(qp * (1.f / 256.f) - mp * mp + 1e-5f);
    float4 ga = ((const float4*)lndg)[lane], ba = ((const float4*)lndb)[lane];
    float4 gp = ((const float4*)lnpg)[lane], bp = ((const float4*)lnpb)[lane];
    float4 o;
    o.x = (v.x - mu) * ru * ga.x + ba.x + (w.x - mp) * rp * gp.x + bp.x;
    o.y = (v.y - mu) * ru * ga.y + ba.y + (w.y - mp) * rp * gp.y + bp.y;
    o.z = (v.z - mu) * ru * ga.z + ba.z + (w.z - mp) * rp * gp.z + bp.z;
    o.w = (v.w - mu) * ru * ga.w + ba.w + (w.w - mp) * rp * gp.w + bp.w;
    ((float4*)(xb + (size_t)row * 256))[lane] = o;
}

// =============== LayerNorm over 256 cols, one wave per row ===============
__global__ __launch_bounds__(256) void k_ln(
    const float* __restrict__ xin, const float* __restrict__ g, const float* __restrict__ b,
    float* __restrict__ out)
{
    const int t = threadIdx.x;
    const int row = blockIdx.x * 4 + (t >> 6);
    const int lane = t & 63;
    float4 v = ((const float4*)(xin + (size_t)row * 256))[lane];
    float s = v.x + v.y + v.z + v.w;
    float sq = v.x * v.x + v.y * v.y + v.z * v.z + v.w * v.w;
    #pragma unroll
    for (int m = 1; m < 64; m <<= 1) { s += __shfl_xor(s, m, 64); sq += __shfl_xor(sq, m, 64); }
    float mean = s * (1.f / 256.f);
    float rs = rsqrtf(sq * (1.f / 256.f) - mean * mean + 1e-5f);
    float4 gv = ((const float4*)g)[lane], bv = ((const float4*)b)[lane];
    float4 o;
    o.x = (v.x - mean) * rs * gv.x + bv.x;
    o.y = (v.y - mean) * rs * gv.y + bv.y;
    o.z = (v.z - mean) * rs * gv.z + bv.z;
    o.w = (v.w - mean) * rs * gv.w + bv.w;
    ((float4*)(out + (size_t)row * 256))[lane] = o;
}

// ===== Generic SIMT GEMM: C = act(A@W + bias) (+res). 64x64 tile, BK=32. act: 0=none 1=gelu 2=leaky
__global__ __launch_bounds__(256) void k_gemm(
    const float* __restrict__ A, const float* __restrict__ W, const float* __restrict__ bias,
    const float* __restrict__ res, float* __restrict__ C,
    int M, int N, int K, int act)
{
    __shared__ float At[64][36];
    __shared__ float Wt[32][68];
    const int t = threadIdx.x;
    const int r0 = blockIdx.y * 64, c0 = blockIdx.x * 64;
    const int tr = t >> 4, tc = t & 15;
    float acc[4][4] = {};
    for (int k0 = 0; k0 < K; k0 += 32) {
        __syncthreads();
        {
            int r = t >> 2, kk0 = (t & 3) * 8;
            const float* src = A + (size_t)(r0 + r) * K + k0 + kk0;
            #pragma unroll
            for (int u = 0; u < 8; u++) At[r][kk0 + u] = src[u];
        }
        {
            int kk = t >> 3, cc0 = (t & 7) * 8;
            const float* src = W + (size_t)(k0 + kk) * N + c0 + cc0;
            #pragma unroll
            for (int u = 0; u < 8; u++) Wt[kk][cc0 + u] = src[u];
        }
        __syncthreads();
        #pragma unroll
        for (int k4 = 0; k4 < 8; k4++) {
            float4 a4[4];
            #pragma unroll
            for (int i = 0; i < 4; i++) a4[i] = *(const float4*)&At[tr * 4 + i][k4 * 4];
            #pragma unroll
            for (int kl = 0; kl < 4; kl++) {
                float4 w4 = *(const float4*)&Wt[k4 * 4 + kl][tc * 4];
                #pragma unroll
                for (int i = 0; i < 4; i++) {
                    float av = (kl == 0) ? a4[i].x : (kl == 1) ? a4[i].y : (kl == 2) ? a4[i].z : a4[i].w;
                    acc[i][0] += av * w4.x; acc[i][1] += av * w4.y;
                    acc[i][2] += av * w4.z; acc[i][3] += av * w4.w;
                }
            }
        }
    }
    float4 bv = *(const float4*)(bias + c0 + tc * 4);
    #pragma unroll
    for (int i = 0; i < 4; i++) {
        size_t off = (size_t)(r0 + tr * 4 + i) * N + c0 + tc * 4;
        float4 v;
        v.x = acc[i][0] + bv.x; v.y = acc[i][1] + bv.y;
        v.z = acc[i][2] + bv.z; v.w = acc[i][3] + bv.w;
        if (act == 1) { v.x = gelu_tanh(v.x); v.y = gelu_tanh(v.y); v.z = gelu_tanh(v.z); v.w = gelu_tanh(v.w); }
        if (act == 2) {
            v.x = v.x >= 0.f ? v.x : 0.2f * v.x; v.y = v.y >= 0.f ? v.y : 0.2f * v.y;
            v.z = v.z >= 0.f ? v.z : 0.2f * v.z; v.w = v.w >= 0.f ? v.w : 0.2f * v.w;
        }
        if (res) {
            float4 rv = *(const float4*)(res + off);
            v.x += rv.x; v.y += rv.y; v.z += rv.z; v.w += rv.w;
        }
        *(float4*)(C + off) = v;
    }
}

// ====== Flash attention v2: d-split. Block=(b,h,qc of 128 rows), 256 thr; lanes L/L+32 share a row
__global__ __launch_bounds__(256) void k_attn2(
    const float* __restrict__ qg, const float* __restrict__ kg, const float* __restrict__ vg,
    float* __restrict__ og)
{
    __shared__ float Ks[32][36], Vs[32][36];
    const int t = threadIdx.x;
    const int bid = blockIdx.x;                 // b*32 + h*4 + qc
    const int b = bid >> 5, hh = (bid >> 2) & 7, qc = bid & 3;
    const int lane = t & 63;
    const int row_in_blk = (t >> 6) * 32 + (lane & 31);
    const int half = lane >> 5;                 // 0: dims 0-15, 1: dims 16-31
    const size_t qbase = (size_t)(b * 512 + qc * 128 + row_in_blk) * 256 + hh * 32 + half * 16;
    float qr[16], acc[16];
    #pragma unroll
    for (int j4 = 0; j4 < 4; j4++) {
        float4 a = *(const float4*)(qg + qbase + j4 * 4);
        qr[j4 * 4 + 0] = a.x; qr[j4 * 4 + 1] = a.y; qr[j4 * 4 + 2] = a.z; qr[j4 * 4 + 3] = a.w;
        acc[j4 * 4 + 0] = 0.f; acc[j4 * 4 + 1] = 0.f; acc[j4 * 4 + 2] = 0.f; acc[j4 * 4 + 3] = 0.f;
    }
    float m = -1e30f, l = 0.f;
    const float scale = 0.17677669529663687f;
    for (int kt = 0; kt < 16; kt++) {
        __syncthreads();
        {
            int kk = t >> 3, dd = (t & 7) * 4;
            size_t base = (size_t)(b * 512 + kt * 32 + kk) * 256 + hh * 32 + dd;
            *(float4*)&Ks[kk][dd] = *(const float4*)(kg + base);
            *(float4*)&Vs[kk][dd] = *(const float4*)(vg + base);
        }
        __syncthreads();
        float s[32];
        #pragma unroll
        for (int kk = 0; kk < 32; kk++) {
            float d = 0.f;
            #pragma unroll
            for (int j4 = 0; j4 < 4; j4++) {
                float4 kf = *(const float4*)&Ks[kk][half * 16 + j4 * 4];
                d += qr[j4 * 4 + 0] * kf.x + qr[j4 * 4 + 1] * kf.y
                   + qr[j4 * 4 + 2] * kf.z + qr[j4 * 4 + 3] * kf.w;
            }
            d += __shfl_xor(d, 32, 64);         // combine halves -> full 32-dim dot
            s[kk] = d * scale;
        }
        float mt = s[0];
        #pragma unroll
        for (int kk = 1; kk < 32; kk++) mt = fmaxf(mt, s[kk]);
        float mn = fmaxf(m, mt);
        float cc = __expf(m - mn);
        l *= cc;
        #pragma unroll
        for (int j = 0; j < 16; j++) acc[j] *= cc;
        #pragma unroll
        for (int kk = 0; kk < 32; kk++) {
            float pw = __expf(s[kk] - mn);
            l += pw;
            #pragma unroll
            for (int j4 = 0; j4 < 4; j4++) {
                float4 vf = *(const float4*)&Vs[kk][half * 16 + j4 * 4];
                acc[j4 * 4 + 0] += pw * vf.x; acc[j4 * 4 + 1] += pw * vf.y;
                acc[j4 * 4 + 2] += pw * vf.z; acc[j4 * 4 + 3] += pw * vf.w;
            }
        }
        m = mn;
    }
    float inv = 1.f / l;
    #pragma unroll
    for (int j4 = 0; j4 < 4; j4++) {
        float4 o;
        o.x = acc[j4 * 4 + 0] * inv; o.y = acc[j4 * 4 + 1] * inv;
        o.z = acc[j4 * 4 + 2] * inv; o.w = acc[j4 * 4 + 3] * inv;
        *(float4*)(og + qbase + j4 * 4) = o;
    }
}

extern "C" void kernel_launch(void* const* d_in, const int* in_sizes, int n_in,
                              void* d_out, int out_size, void* d_ws, size_t ws_size,
                              hipStream_t stream)
{
    const float* img  = (const float*)d_in[0];
    const float* bfac = (const float*)d_in[1];
    const float* w0  = (const float*)d_in[2];  const float* b0c = (const float*)d_in[3];
    const float* g1  = (const float*)d_in[4];  const float* be1 = (const float*)d_in[5];
    const float* w1  = (const float*)d_in[6];  const float* b1c = (const float*)d_in[7];
    const float* w2  = (const float*)d_in[10]; const float* b2c = (const float*)d_in[11];
    const float* g2  = (const float*)d_in[8];  const float* be2 = (const float*)d_in[9];
    const float* g3  = (const float*)d_in[12]; const float* be3 = (const float*)d_in[13];
    const float* wu  = (const float*)d_in[14]; const float* bu  = (const float*)d_in[15];
    const float* pos = (const float*)d_in[16];
    const float* lndg = (const float*)d_in[17]; const float* lndb = (const float*)d_in[18];
    const float* lnpg = (const float*)d_in[19]; const float* lnpb = (const float*)d_in[20];
    const float* Wq = (const float*)d_in[21]; const float* bq = (const float*)d_in[22];
    const float* Wk = (const float*)d_in[23]; const float* bk = (const float*)d_in[24];
    const float* Wv = (const float*)d_in[25]; const float* bv = (const float*)d_in[26];
    const float* Wo = (const float*)d_in[27]; const float* bo = (const float*)d_in[28];
    const float* l1g = (const float*)d_in[29]; const float* l1b = (const float*)d_in[30];
    const float* l2g = (const float*)d_in[31]; const float* l2b = (const float*)d_in[32];
    const float* W1 = (const float*)d_in[33]; const float* bf1 = (const float*)d_in[34];
    const float* W2 = (const float*)d_in[35]; const float* bf2 = (const float*)d_in[36];

    float* ws  = (float*)d_ws;
    float* d0b = ws;                       // 16,777,216 floats (phase A-B)
    float* d1b = ws + 16777216;            //  4,194,304
    float* xb  = ws + 20971520;            //  2,097,152 (persists through phase D)
    // phase C scratch (inside dead d0b region after conv1):
    float* d2b   = ws;                     //  1,048,576 (8192x128)
    float* ub    = ws + 1048576;           //  2,097,152 (8192x256)
    float* w2gem = ws + 3145728;           //     65,536
    float* wuT   = ws + 3211264;           //     32,768
    // phase D (transformer) reuse:
    float* hb  = ws;
    float* qb  = ws + 2097152;
    float* kb  = ws + 4194304;
    float* vb  = ws + 6291456;
    float* ob  = ws + 8388608;
    float* m1b = ws + 10485760;            //  8,388,608 -> ends 18,874,368 < 20,971,520
    float* xout = (float*)d_out;

    k_blur_conv0<<<8192, 256, 0, stream>>>(img, bfac, w0, b0c, g1, be1, d0b);
    k_conv1<<<8192, 512, 0, stream>>>(d0b, w1, b1c, g2, be2, d1b);
    // conv2 + GN3 + convu + LN(u)+LN(pos), GEMM-ified
    k_prep_w2<<<256, 256, 0, stream>>>(w2, w2gem);
    k_prep_wu<<<128, 256, 0, stream>>>(wu, wuT);
    k_gemm<<<dim3(2, 128), 256, 0, stream>>>(d1b, w2gem, b2c, nullptr, d2b, 8192, 128, 512, 2);
    k_gn3<<<2048, 256, 0, stream>>>(d2b, g3, be3);
    k_gemm<<<dim3(4, 128), 256, 0, stream>>>(d2b, wuT, bu, nullptr, ub, 8192, 256, 128, 0);
    k_lnpos<<<2048, 256, 0, stream>>>(ub, pos, lndg, lndb, lnpg, lnpb, xb);

    dim3 g256(4, 128), g1024(16, 128);
    for (int i = 0; i < 8; i++) {
        k_ln<<<2048, 256, 0, stream>>>(xb, l1g + i * 256, l1b + i * 256, hb);
        k_gemm<<<g256, 256, 0, stream>>>(hb, Wq + (size_t)i * 65536, bq + i * 256, nullptr, qb, 8192, 256, 256, 0);
        k_gemm<<<g256, 256, 0, stream>>>(hb, Wk + (size_t)i * 65536, bk + i * 256, nullptr, kb, 8192, 256, 256, 0);
        k_gemm<<<g256, 256, 0, stream>>>(hb, Wv + (size_t)i * 65536, bv + i * 256, nullptr, vb, 8192, 256, 256, 0);
        k_attn2<<<512, 256, 0, stream>>>(qb, kb, vb, ob);
        k_gemm<<<g256, 256, 0, stream>>>(ob, Wo + (size_t)i * 65536, bo + i * 256, xb, xb, 8192, 256, 256, 0);
        k_ln<<<2048, 256, 0, stream>>>(xb, l2g + i * 256, l2b + i * 256, hb);
        k_gemm<<<g1024, 256, 0, stream>>>(hb, W1 + (size_t)i * 262144, bf1 + i * 1024, nullptr, m1b, 8192, 1024, 256, 1);
        float* outC = (i == 7) ? xout : xb;
        k_gemm<<<g256, 256, 0, stream>>>(m1b, W2 + (size_t)i * 262144, bf2 + i * 256, xb, outC, 8192, 256, 1024, 0);
    }
}

// Round 6
// 2280.910 us; speedup vs baseline: 2.6138x; 1.6424x over previous
//
#include <hip/hip_runtime.h>
#include <hip/hip_bf16.h>

#define PI2F 9.869604401089358f

typedef __attribute__((ext_vector_type(8))) short bf16x8;
typedef __attribute__((ext_vector_type(4))) float f32x4;

__device__ inline unsigned short f2b(float v) {
    union { float f; unsigned u; } x; x.f = v;
    unsigned r = x.u + 0x7fffu + ((x.u >> 16) & 1u);
    return (unsigned short)(r >> 16);
}

__device__ inline float gelu_tanh(float v) {
    float u = 0.7978845608028654f * (v + 0.044715f * v * v * v);
    float th = 1.f - 2.f / (1.f + __expf(2.f * u));
    return 0.5f * v * (1.f + th);
}

// =============== Kernel A: unfold + separable circular blur + conv0 + leaky + GN(G=4) ===========
__global__ __launch_bounds__(256) void k_blur_conv0(
    const float* __restrict__ img, const float* __restrict__ bfac,
    const float* __restrict__ w0, const float* __restrict__ b0c,
    const float* __restrict__ g1, const float* __restrict__ be1,
    unsigned short* __restrict__ d0)
{
    __shared__ float pa[512], pb[512], w0s[2048], d0s[2048], hsm[8];
    __shared__ float2 gstat[4];
    const int t = threadIdx.x, blk = blockIdx.x;
    const int b = blk >> 9, rem = blk & 511;
    const int zh = rem >> 6, yh = (rem >> 3) & 7, xh = rem & 7;

    #pragma unroll
    for (int i = 0; i < 2; i++) {
        int v = t + 256 * i;
        int z = v >> 6, y = (v >> 3) & 7, x = v & 7;
        pa[v] = img[(((size_t)(b * 8 + zh) * 8 + z) * 64 + yh * 8 + y) * 64 + xh * 8 + x];
    }
    for (int i = t; i < 2048; i += 256) w0s[i] = w0[i];
    if (t < 8) {
        float bf = bfac[blk];
        float c = bf * PI2F * (1.0f / 16.0f);
        float gk1 = __expf(-c), gk2 = __expf(-4.f * c), gk3 = __expf(-9.f * c), gk4 = __expf(-16.f * c);
        float d = (float)t;
        float h = 1.f + 2.f * (gk1 * cosf(0.7853981633974483f * d)
                             + gk2 * cosf(1.5707963267948966f * d)
                             + gk3 * cosf(2.356194490192345f * d))
                      + gk4 * cosf(3.141592653589793f * d);
        hsm[t] = 0.125f * h;
    }
    __syncthreads();
    #pragma unroll
    for (int i = 0; i < 2; i++) {
        int v = t + 256 * i; int x = v & 7; int base = v & ~7;
        float s = 0.f;
        #pragma unroll
        for (int m = 0; m < 8; m++) s += hsm[(x - m) & 7] * pa[base + m];
        pb[v] = s;
    }
    __syncthreads();
    #pragma unroll
    for (int i = 0; i < 2; i++) {
        int v = t + 256 * i; int y = (v >> 3) & 7; int base = (v & ~63) | (v & 7);
        float s = 0.f;
        #pragma unroll
        for (int m = 0; m < 8; m++) s += hsm[(y - m) & 7] * pb[base + m * 8];
        pa[v] = s;
    }
    __syncthreads();
    #pragma unroll
    for (int i = 0; i < 2; i++) {
        int v = t + 256 * i; int z = v >> 6; int base = v & 63;
        float s = 0.f;
        #pragma unroll
        for (int m = 0; m < 8; m++) s += hsm[(z - m) & 7] * pa[base + m * 64];
        pb[v] = s;
    }
    __syncthreads();
    #pragma unroll
    for (int i = 0; i < 8; i++) {
        int oi = t + 256 * i;
        int c = oi >> 6, vox = oi & 63;
        int oz = vox >> 4, oy = (vox >> 2) & 3, ox = vox & 3;
        float s = b0c[c];
        #pragma unroll
        for (int kz = 0; kz < 4; kz++) {
            int sz = 2 * oz - 1 + kz; if (sz < 0 || sz > 7) continue;
            #pragma unroll
            for (int ky = 0; ky < 4; ky++) {
                int sy = 2 * oy - 1 + ky; if (sy < 0 || sy > 7) continue;
                #pragma unroll
                for (int kx = 0; kx < 4; kx++) {
                    int sx = 2 * ox - 1 + kx; if (sx < 0 || sx > 7) continue;
                    s += pb[sz * 64 + sy * 8 + sx] * w0s[c * 64 + kz * 16 + ky * 4 + kx];
                }
            }
        }
        s = s >= 0.f ? s : 0.2f * s;
        d0s[oi] = s;
    }
    __syncthreads();
    {
        int g = t >> 6, lane = t & 63;
        float s = 0.f, sq = 0.f;
        #pragma unroll
        for (int j = 0; j < 8; j++) { float v = d0s[g * 512 + lane + 64 * j]; s += v; sq += v * v; }
        #pragma unroll
        for (int m = 1; m < 64; m <<= 1) { s += __shfl_xor(s, m, 64); sq += __shfl_xor(sq, m, 64); }
        if (lane == 0) {
            float mean = s * (1.f / 512.f);
            float var = sq * (1.f / 512.f) - mean * mean;
            gstat[g] = make_float2(mean, rsqrtf(var + 1e-5f));
        }
    }
    __syncthreads();
    size_t obase = (size_t)blk * 2048;
    #pragma unroll
    for (int i = 0; i < 8; i++) {
        int oi = t + 256 * i;
        int c = oi >> 6;
        float2 st = gstat[oi >> 9];
        d0[obase + oi] = f2b((d0s[oi] - st.x) * st.y * g1[c] + be1[c]);
    }
}

// =============== Weight prep kernels (f32 -> transposed bf16 [N][K]) ===============
__global__ __launch_bounds__(256) void k_prep_w1T(const float* __restrict__ w1, unsigned short* __restrict__ w1T)
{
    int idx = blockIdx.x * 256 + threadIdx.x;          // 512 x 2048
    int n = idx >> 11, k = idx & 2047;
    int oc = n >> 3, vox = n & 7;
    int oz = vox >> 2, oy = (vox >> 1) & 1, ox = vox & 1;
    int ci = k >> 6, sp = k & 63;
    int sz = sp >> 4, sy = (sp >> 2) & 3, sx = sp & 3;
    int kz = sz + 1 - 2 * oz, ky = sy + 1 - 2 * oy, kx = sx + 1 - 2 * ox;
    float v = 0.f;
    if ((unsigned)kz < 4u && (unsigned)ky < 4u && (unsigned)kx < 4u)
        v = w1[(size_t)oc * 2048 + ci * 64 + kz * 16 + ky * 4 + kx];
    w1T[idx] = f2b(v);
}

__global__ __launch_bounds__(256) void k_prep_w2T(const float* __restrict__ w2, unsigned short* __restrict__ w2T)
{
    int idx = blockIdx.x * 256 + threadIdx.x;          // 128 x 512
    int n = idx >> 9, k = idx & 511;
    int ci = k >> 3, v = k & 7;
    int z = v >> 2, y = (v >> 1) & 1, x = v & 1;
    w2T[idx] = f2b(w2[(size_t)n * 4096 + ci * 64 + (z + 1) * 16 + (y + 1) * 4 + (x + 1)]);
}

__global__ __launch_bounds__(256) void k_prep_wuT(const float* __restrict__ wu, unsigned short* __restrict__ wuT)
{
    int idx = blockIdx.x * 256 + threadIdx.x;          // wu already [256 out][128 in] = [N][K]
    wuT[idx] = f2b(wu[idx]);
}

__global__ __launch_bounds__(256) void k_prep_b1(const float* __restrict__ b1c, float* __restrict__ b1x)
{
    int idx = blockIdx.x * 256 + threadIdx.x;          // 512
    b1x[idx] = b1c[idx >> 3];
}

// generic: W [L][K][N] f32 -> WT [L][N][K] bf16; K = 1<<kshift
__global__ __launch_bounds__(256) void k_prep_T(const float* __restrict__ W, unsigned short* __restrict__ WT,
                                               int N, int kshift)
{
    int gid = blockIdx.x * 256 + threadIdx.x;
    int l = blockIdx.y;
    int K = 1 << kshift;
    int n = gid >> kshift, k = gid & (K - 1);
    size_t base = (size_t)l * ((size_t)N << kshift);
    WT[base + gid] = f2b(W[base + (size_t)k * N + n]);
}

// =============== MFMA GEMM: C[M][N] = act(A[M][K]bf16 @ WT[N][K]bf16^T + bias) (+res) ===========
// BM x 64 tile, BK=64, 256 threads = 4 waves (2x2). obf: write bf16 else f32.
template<int BM>
__global__ __launch_bounds__(256) void k_gemm_bf16(
    const unsigned short* __restrict__ A, const unsigned short* __restrict__ WT,
    const float* __restrict__ bias, const float* __restrict__ res,
    void* __restrict__ Cout, int M, int N, int K, int act, int obf)
{
    constexpr int MREP = BM / 32;
    __shared__ unsigned short Ash[BM][72];
    __shared__ unsigned short Bsh[64][72];
    const int t = threadIdx.x;
    const int c0 = blockIdx.x * 64;
    const int r0 = blockIdx.y * BM;
    const int wid = t >> 6, lane = t & 63;
    const int wr = wid >> 1, wc = wid & 1;
    const int lrow = lane & 15, lk = (lane >> 4) * 8;
    f32x4 acc[MREP][2] = {};
    for (int k0 = 0; k0 < K; k0 += 64) {
        __syncthreads();
        #pragma unroll
        for (int i = 0; i < BM / 32; i++) {
            int f = (i * 256 + t) * 8;
            int r = f >> 6, kk = f & 63;
            *(bf16x8*)&Ash[r][kk] = *(const bf16x8*)(A + (size_t)(r0 + r) * K + k0 + kk);
        }
        #pragma unroll
        for (int i = 0; i < 2; i++) {
            int f = (i * 256 + t) * 8;
            int r = f >> 6, kk = f & 63;
            *(bf16x8*)&Bsh[r][kk] = *(const bf16x8*)(WT + (size_t)(c0 + r) * K + k0 + kk);
        }
        __syncthreads();
        #pragma unroll
        for (int ks = 0; ks < 2; ks++) {
            bf16x8 b0 = *(const bf16x8*)&Bsh[wc * 32 + lrow][ks * 32 + lk];
            bf16x8 b1 = *(const bf16x8*)&Bsh[wc * 32 + 16 + lrow][ks * 32 + lk];
            #pragma unroll
            for (int m = 0; m < MREP; m++) {
                bf16x8 a = *(const bf16x8*)&Ash[wr * (BM / 2) + m * 16 + lrow][ks * 32 + lk];
                acc[m][0] = __builtin_amdgcn_mfma_f32_16x16x32_bf16(a, b0, acc[m][0], 0, 0, 0);
                acc[m][1] = __builtin_amdgcn_mfma_f32_16x16x32_bf16(a, b1, acc[m][1], 0, 0, 0);
            }
        }
    }
    const int rbase = r0 + wr * (BM / 2) + (lane >> 4) * 4;
    #pragma unroll
    for (int n = 0; n < 2; n++) {
        const int col = c0 + wc * 32 + n * 16 + lrow;
        const float bv = bias[col];
        #pragma unroll
        for (int m = 0; m < MREP; m++) {
            #pragma unroll
            for (int r = 0; r < 4; r++) {
                float v = acc[m][n][r] + bv;
                if (act == 1) v = gelu_tanh(v);
                else if (act == 2) v = v >= 0.f ? v : 0.2f * v;
                size_t off = (size_t)(rbase + m * 16 + r) * N + col;
                if (res) v += res[off];
                if (obf) ((unsigned short*)Cout)[off] = f2b(v);
                else ((float*)Cout)[off] = v;
            }
        }
    }
}

// =============== GN2: groups of 256 cols (2/row of 512); affine by oc=col>>3; bf16 out ==========
__global__ __launch_bounds__(256) void k_gn2(
    const float* __restrict__ din, const float* __restrict__ g2, const float* __restrict__ be2,
    unsigned short* __restrict__ dout)
{
    const int t = threadIdx.x;
    const int w = t >> 6, lane = t & 63;
    const int p = blockIdx.x * 2 + (w >> 1), g = w & 1;
    float4 v = ((const float4*)(din + (size_t)p * 512 + g * 256))[lane];
    float s = v.x + v.y + v.z + v.w;
    float sq = v.x * v.x + v.y * v.y + v.z * v.z + v.w * v.w;
    #pragma unroll
    for (int m = 1; m < 64; m <<= 1) { s += __shfl_xor(s, m, 64); sq += __shfl_xor(sq, m, 64); }
    float mean = s * (1.f / 256.f);
    float rs = rsqrtf(sq * (1.f / 256.f) - mean * mean + 1e-5f);
    int oc = g * 32 + (lane >> 1);
    float gg = g2[oc], bb = be2[oc];
    ushort4 o;
    o.x = f2b((v.x - mean) * rs * gg + bb);
    o.y = f2b((v.y - mean) * rs * gg + bb);
    o.z = f2b((v.z - mean) * rs * gg + bb);
    o.w = f2b((v.w - mean) * rs * gg + bb);
    ((ushort4*)(dout + (size_t)p * 512 + g * 256))[lane] = o;
}

// =============== GN3: per-row over 128; bf16 out ===============
__global__ __launch_bounds__(256) void k_gn3(
    const float* __restrict__ din, const float* __restrict__ g3, const float* __restrict__ be3,
    unsigned short* __restrict__ dout)
{
    const int t = threadIdx.x;
    const int row = blockIdx.x * 4 + (t >> 6);
    const int lane = t & 63;
    float2 v = ((const float2*)(din + (size_t)row * 128))[lane];
    float s = v.x + v.y, sq = v.x * v.x + v.y * v.y;
    #pragma unroll
    for (int m = 1; m < 64; m <<= 1) { s += __shfl_xor(s, m, 64); sq += __shfl_xor(sq, m, 64); }
    float mean = s * (1.f / 128.f);
    float rs = rsqrtf(sq * (1.f / 128.f) - mean * mean + 1e-5f);
    float2 gv = ((const float2*)g3)[lane], bv = ((const float2*)be3)[lane];
    ushort2 o;
    o.x = f2b((v.x - mean) * rs * gv.x + bv.x);
    o.y = f2b((v.y - mean) * rs * gv.y + bv.y);
    ((ushort2*)(dout + (size_t)row * 128))[lane] = o;
}

// =============== LN(u) + LN(pos[row&511]) -> xb f32. Wave per row. ===============
__global__ __launch_bounds__(256) void k_lnpos(
    const float* __restrict__ u, const float* __restrict__ pos,
    const float* __restrict__ lndg, const float* __restrict__ lndb,
    const float* __restrict__ lnpg, const float* __restrict__ lnpb,
    float* __restrict__ xb)
{
    const int t = threadIdx.x;
    const int row = blockIdx.x * 4 + (t >> 6);
    const int lane = t & 63;
    float4 v = ((const float4*)(u + (size_t)row * 256))[lane];
    float4 w = ((const float4*)(pos + (size_t)(row & 511) * 256))[lane];
    float s = v.x + v.y + v.z + v.w;
    float sq = v.x * v.x + v.y * v.y + v.z * v.z + v.w * v.w;
    float sp = w.x + w.y + w.z + w.w;
    float qp = w.x * w.x + w.y * w.y + w.z * w.z + w.w * w.w;
    #pragma unroll
    for (int m = 1; m < 64; m <<= 1) {
        s += __shfl_xor(s, m, 64); sq += __shfl_xor(sq, m, 64);
        sp += __shfl_xor(sp, m, 64); qp += __shfl_xor(qp, m, 64);
    }
    float mu = s * (1.f / 256.f), ru = rsqrtf(sq * (1.f / 256.f) - mu * mu + 1e-5f);
    float mp = sp * (1.f / 256.f), rp = rsqrtf(qp * (1.f / 256.f) - mp * mp + 1e-5f);
    float4 ga = ((const float4*)lndg)[lane], ba = ((const float4*)lndb)[lane];
    float4 gp = ((const float4*)lnpg)[lane], bp = ((const float4*)lnpb)[lane];
    float4 o;
    o.x = (v.x - mu) * ru * ga.x + ba.x + (w.x - mp) * rp * gp.x + bp.x;
    o.y = (v.y - mu) * ru * ga.y + ba.y + (w.y - mp) * rp * gp.y + bp.y;
    o.z = (v.z - mu) * ru * ga.z + ba.z + (w.z - mp) * rp * gp.z + bp.z;
    o.w = (v.w - mu) * ru * ga.w + ba.w + (w.w - mp) * rp * gp.w + bp.w;
    ((float4*)(xb + (size_t)row * 256))[lane] = o;
}

// =============== LayerNorm over 256 cols -> bf16 out. Wave per row. ===============
__global__ __launch_bounds__(256) void k_ln(
    const float* __restrict__ xin, const float* __restrict__ g, const float* __restrict__ b,
    unsigned short* __restrict__ out)
{
    const int t = threadIdx.x;
    const int row = blockIdx.x * 4 + (t >> 6);
    const int lane = t & 63;
    float4 v = ((const float4*)(xin + (size_t)row * 256))[lane];
    float s = v.x + v.y + v.z + v.w;
    float sq = v.x * v.x + v.y * v.y + v.z * v.z + v.w * v.w;
    #pragma unroll
    for (int m = 1; m < 64; m <<= 1) { s += __shfl_xor(s, m, 64); sq += __shfl_xor(sq, m, 64); }
    float mean = s * (1.f / 256.f);
    float rs = rsqrtf(sq * (1.f / 256.f) - mean * mean + 1e-5f);
    float4 gv = ((const float4*)g)[lane], bv = ((const float4*)b)[lane];
    ushort4 o;
    o.x = f2b((v.x - mean) * rs * gv.x + bv.x);
    o.y = f2b((v.y - mean) * rs * gv.y + bv.y);
    o.z = f2b((v.z - mean) * rs * gv.z + bv.z);
    o.w = f2b((v.w - mean) * rs * gv.w + bv.w);
    ((ushort4*)(out + (size_t)row * 256))[lane] = o;
}

// ====== Flash attention: d-split; block=(b,h,qc of 128 rows); f32 in, bf16 out ======
__global__ __launch_bounds__(256) void k_attn2(
    const float* __restrict__ qg, const float* __restrict__ kg, const float* __restrict__ vg,
    unsigned short* __restrict__ og)
{
    __shared__ float Ks[32][36], Vs[32][36];
    const int t = threadIdx.x;
    const int bid = blockIdx.x;                 // b*32 + h*4 + qc
    const int b = bid >> 5, hh = (bid >> 2) & 7, qc = bid & 3;
    const int lane = t & 63;
    const int row_in_blk = (t >> 6) * 32 + (lane & 31);
    const int half = lane >> 5;
    const size_t qbase = (size_t)(b * 512 + qc * 128 + row_in_blk) * 256 + hh * 32 + half * 16;
    float qr[16], acc[16];
    #pragma unroll
    for (int j4 = 0; j4 < 4; j4++) {
        float4 a = *(const float4*)(qg + qbase + j4 * 4);
        qr[j4 * 4 + 0] = a.x; qr[j4 * 4 + 1] = a.y; qr[j4 * 4 + 2] = a.z; qr[j4 * 4 + 3] = a.w;
        acc[j4 * 4 + 0] = 0.f; acc[j4 * 4 + 1] = 0.f; acc[j4 * 4 + 2] = 0.f; acc[j4 * 4 + 3] = 0.f;
    }
    float m = -1e30f, l = 0.f;
    const float scale = 0.17677669529663687f;
    for (int kt = 0; kt < 16; kt++) {
        __syncthreads();
        {
            int kk = t >> 3, dd = (t & 7) * 4;
            size_t base = (size_t)(b * 512 + kt * 32 + kk) * 256 + hh * 32 + dd;
            *(float4*)&Ks[kk][dd] = *(const float4*)(kg + base);
            *(float4*)&Vs[kk][dd] = *(const float4*)(vg + base);
        }
        __syncthreads();
        float s[32];
        #pragma unroll
        for (int kk = 0; kk < 32; kk++) {
            float d = 0.f;
            #pragma unroll
            for (int j4 = 0; j4 < 4; j4++) {
                float4 kf = *(const float4*)&Ks[kk][half * 16 + j4 * 4];
                d += qr[j4 * 4 + 0] * kf.x + qr[j4 * 4 + 1] * kf.y
                   + qr[j4 * 4 + 2] * kf.z + qr[j4 * 4 + 3] * kf.w;
            }
            d += __shfl_xor(d, 32, 64);
            s[kk] = d * scale;
        }
        float mt = s[0];
        #pragma unroll
        for (int kk = 1; kk < 32; kk++) mt = fmaxf(mt, s[kk]);
        float mn = fmaxf(m, mt);
        float cc = __expf(m - mn);
        l *= cc;
        #pragma unroll
        for (int j = 0; j < 16; j++) acc[j] *= cc;
        #pragma unroll
        for (int kk = 0; kk < 32; kk++) {
            float pw = __expf(s[kk] - mn);
            l += pw;
            #pragma unroll
            for (int j4 = 0; j4 < 4; j4++) {
                float4 vf = *(const float4*)&Vs[kk][half * 16 + j4 * 4];
                acc[j4 * 4 + 0] += pw * vf.x; acc[j4 * 4 + 1] += pw * vf.y;
                acc[j4 * 4 + 2] += pw * vf.z; acc[j4 * 4 + 3] += pw * vf.w;
            }
        }
        m = mn;
    }
    float inv = 1.f / l;
    #pragma unroll
    for (int j4 = 0; j4 < 4; j4++) {
        ushort4 o;
        o.x = f2b(acc[j4 * 4 + 0] * inv); o.y = f2b(acc[j4 * 4 + 1] * inv);
        o.z = f2b(acc[j4 * 4 + 2] * inv); o.w = f2b(acc[j4 * 4 + 3] * inv);
        *(ushort4*)(og + qbase + j4 * 4) = o;
    }
}

extern "C" void kernel_launch(void* const* d_in, const int* in_sizes, int n_in,
                              void* d_out, int out_size, void* d_ws, size_t ws_size,
                              hipStream_t stream)
{
    const float* img  = (const float*)d_in[0];
    const float* bfac = (const float*)d_in[1];
    const float* w0  = (const float*)d_in[2];  const float* b0c = (const float*)d_in[3];
    const float* g1  = (const float*)d_in[4];  const float* be1 = (const float*)d_in[5];
    const float* w1  = (const float*)d_in[6];  const float* b1c = (const float*)d_in[7];
    const float* g2  = (const float*)d_in[8];  const float* be2 = (const float*)d_in[9];
    const float* w2  = (const float*)d_in[10]; const float* b2c = (const float*)d_in[11];
    const float* g3  = (const float*)d_in[12]; const float* be3 = (const float*)d_in[13];
    const float* wu  = (const float*)d_in[14]; const float* bu  = (const float*)d_in[15];
    const float* pos = (const float*)d_in[16];
    const float* lndg = (const float*)d_in[17]; const float* lndb = (const float*)d_in[18];
    const float* lnpg = (const float*)d_in[19]; const float* lnpb = (const float*)d_in[20];
    const float* Wq = (const float*)d_in[21]; const float* bq = (const float*)d_in[22];
    const float* Wk = (const float*)d_in[23]; const float* bk = (const float*)d_in[24];
    const float* Wv = (const float*)d_in[25]; const float* bv = (const float*)d_in[26];
    const float* Wo = (const float*)d_in[27]; const float* bo = (const float*)d_in[28];
    const float* l1g = (const float*)d_in[29]; const float* l1b = (const float*)d_in[30];
    const float* l2g = (const float*)d_in[31]; const float* l2b = (const float*)d_in[32];
    const float* W1 = (const float*)d_in[33]; const float* bf1 = (const float*)d_in[34];
    const float* W2 = (const float*)d_in[35]; const float* bf2 = (const float*)d_in[36];

    float* ws = (float*)d_ws;
    // Persistent regions (floats):
    unsigned short* d0b  = (unsigned short*)(ws);               // [8192][2048] bf16 -> 8,388,608 fl
    float*          d1raw = ws + 8388608;                       // [8192][512] f32  -> 4,194,304 fl
    unsigned short* d1b  = (unsigned short*)(ws + 12582912);    // [8192][512] bf16 -> 2,097,152 fl
    float*          xb   = ws + 14680064;                       // [8192][256] f32  -> 2,097,152 fl
    // bf16 weight arena:
    unsigned short* w1T  = (unsigned short*)(ws + 16777216);    // 512x2048  -> 524,288 fl
    unsigned short* w2T  = (unsigned short*)(ws + 17301504);    // 128x512   -> 32,768 fl
    unsigned short* wuTb = (unsigned short*)(ws + 17334272);    // 256x128   -> 16,384 fl
    unsigned short* WqT  = (unsigned short*)(ws + 17350656);    // 8x256x256 -> 262,144 fl
    unsigned short* WkT  = (unsigned short*)(ws + 17612800);
    unsigned short* WvT  = (unsigned short*)(ws + 17874944);
    unsigned short* WoT  = (unsigned short*)(ws + 18137088);
    unsigned short* W1T  = (unsigned short*)(ws + 18399232);    // 8x1024x256 -> 1,048,576 fl
    unsigned short* W2T  = (unsigned short*)(ws + 19447808);    // 8x256x1024 -> 1,048,576 fl
    float*          b1x  = ws + 20496384;                       // 512 fl -> end 20,496,896 (82 MB)
    // Phase C overlay (d0b region, dead after conv1 GEMM):
    float*          d2raw = ws;                                 // [8192][128] f32 -> 1,048,576
    unsigned short* d2b   = (unsigned short*)(ws + 1048576);    // [8192][128] bf16 -> 524,288
    float*          ub    = ws + 1572864;                       // [8192][256] f32 -> 2,097,152
    // Phase D overlay:
    unsigned short* hb    = (unsigned short*)(ws);              // [8192][256] bf16 -> 1,048,576
    float*          qb    = ws + 1048576;
    float*          kb    = ws + 3145728;
    float*          vb    = ws + 5242880;
    unsigned short* obb   = (unsigned short*)(ws + 7340032);    // [8192][256] bf16
    unsigned short* m1b   = (unsigned short*)(ws + 8388608);    // [8192][1024] bf16 -> 4,194,304
    float* xout = (float*)d_out;

    // Weight prep (bf16, transposed)
    k_prep_w1T<<<4096, 256, 0, stream>>>(w1, w1T);
    k_prep_w2T<<<256, 256, 0, stream>>>(w2, w2T);
    k_prep_wuT<<<128, 256, 0, stream>>>(wu, wuTb);
    k_prep_b1<<<2, 256, 0, stream>>>(b1c, b1x);
    k_prep_T<<<dim3(256, 8), 256, 0, stream>>>(Wq, WqT, 256, 8);
    k_prep_T<<<dim3(256, 8), 256, 0, stream>>>(Wk, WkT, 256, 8);
    k_prep_T<<<dim3(256, 8), 256, 0, stream>>>(Wv, WvT, 256, 8);
    k_prep_T<<<dim3(256, 8), 256, 0, stream>>>(Wo, WoT, 256, 8);
    k_prep_T<<<dim3(1024, 8), 256, 0, stream>>>(W1, W1T, 1024, 8);
    k_prep_T<<<dim3(1024, 8), 256, 0, stream>>>(W2, W2T, 256, 10);

    // Encoder
    k_blur_conv0<<<8192, 256, 0, stream>>>(img, bfac, w0, b0c, g1, be1, d0b);
    k_gemm_bf16<128><<<dim3(8, 64), 256, 0, stream>>>(d0b, w1T, b1x, nullptr, d1raw, 8192, 512, 2048, 2, 0);
    k_gn2<<<4096, 256, 0, stream>>>(d1raw, g2, be2, d1b);
    k_gemm_bf16<64><<<dim3(2, 128), 256, 0, stream>>>(d1b, w2T, b2c, nullptr, d2raw, 8192, 128, 512, 2, 0);
    k_gn3<<<2048, 256, 0, stream>>>(d2raw, g3, be3, d2b);
    k_gemm_bf16<64><<<dim3(4, 128), 256, 0, stream>>>(d2b, wuTb, bu, nullptr, ub, 8192, 256, 128, 0, 0);
    k_lnpos<<<2048, 256, 0, stream>>>(ub, pos, lndg, lndb, lnpg, lnpb, xb);

    // Transformer
    for (int i = 0; i < 8; i++) {
        k_ln<<<2048, 256, 0, stream>>>(xb, l1g + i * 256, l1b + i * 256, hb);
        k_gemm_bf16<64><<<dim3(4, 128), 256, 0, stream>>>(hb, WqT + (size_t)i * 65536, bq + i * 256, nullptr, qb, 8192, 256, 256, 0, 0);
        k_gemm_bf16<64><<<dim3(4, 128), 256, 0, stream>>>(hb, WkT + (size_t)i * 65536, bk + i * 256, nullptr, kb, 8192, 256, 256, 0, 0);
        k_gemm_bf16<64><<<dim3(4, 128), 256, 0, stream>>>(hb, WvT + (size_t)i * 65536, bv + i * 256, nullptr, vb, 8192, 256, 256, 0, 0);
        k_attn2<<<512, 256, 0, stream>>>(qb, kb, vb, obb);
        k_gemm_bf16<64><<<dim3(4, 128), 256, 0, stream>>>(obb, WoT + (size_t)i * 65536, bo + i * 256, xb, xb, 8192, 256, 256, 0, 0);
        k_ln<<<2048, 256, 0, stream>>>(xb, l2g + i * 256, l2b + i * 256, hb);
        k_gemm_bf16<128><<<dim3(16, 64), 256, 0, stream>>>(hb, W1T + (size_t)i * 262144, bf1 + i * 1024, nullptr, m1b, 8192, 1024, 256, 1, 1);
        k_gemm_bf16<64><<<dim3(4, 128), 256, 0, stream>>>(m1b, W2T + (size_t)i * 262144, bf2 + i * 256, xb, (i == 7) ? xout : xb, 8192, 256, 1024, 0, 0);
    }
}

// Round 7
// 1120.792 us; speedup vs baseline: 5.3192x; 2.0351x over previous
//
#include <hip/hip_runtime.h>
#include <hip/hip_bf16.h>

#define PI2F 9.869604401089358f

typedef __attribute__((ext_vector_type(8))) short bf16x8;
typedef __attribute__((ext_vector_type(4))) float f32x4;

__device__ inline unsigned short f2b(float v) {
    union { float f; unsigned u; } x; x.f = v;
    unsigned r = x.u + 0x7fffu + ((x.u >> 16) & 1u);
    return (unsigned short)(r >> 16);
}

__device__ inline float gelu_tanh(float v) {
    float u = 0.7978845608028654f * (v + 0.044715f * v * v * v);
    float th = 1.f - 2.f / (1.f + __expf(2.f * u));
    return 0.5f * v * (1.f + th);
}

// =============== Kernel A: unfold + separable circular blur + conv0 + leaky + GN(G=4) ===========
// conv0 stage is vox-major per lane: half-wave shares vox -> pb broadcast, uniform branches;
// w0st transposed [tap][ch] -> stride-1 conflict-free; d0s [vox][33] padded.
__global__ __launch_bounds__(256) void k_blur_conv0(
    const float* __restrict__ img, const float* __restrict__ bfac,
    const float* __restrict__ w0, const float* __restrict__ b0c,
    const float* __restrict__ g1, const float* __restrict__ be1,
    unsigned short* __restrict__ d0)
{
    __shared__ float pa[512], pb[512], w0st[2048], d0s[64 * 33], hsm[8];
    __shared__ float2 gstat[4];
    const int t = threadIdx.x, blk = blockIdx.x;
    const int b = blk >> 9, rem = blk & 511;
    const int zh = rem >> 6, yh = (rem >> 3) & 7, xh = rem & 7;

    #pragma unroll
    for (int i = 0; i < 2; i++) {
        int v = t + 256 * i;
        int z = v >> 6, y = (v >> 3) & 7, x = v & 7;
        pa[v] = img[(((size_t)(b * 8 + zh) * 8 + z) * 64 + yh * 8 + y) * 64 + xh * 8 + x];
    }
    for (int i = t; i < 2048; i += 256) w0st[i] = w0[(i & 31) * 64 + (i >> 5)];
    if (t < 8) {
        float bf = bfac[blk];
        float c = bf * PI2F * (1.0f / 16.0f);
        float gk1 = __expf(-c), gk2 = __expf(-4.f * c), gk3 = __expf(-9.f * c), gk4 = __expf(-16.f * c);
        float d = (float)t;
        float h = 1.f + 2.f * (gk1 * cosf(0.7853981633974483f * d)
                             + gk2 * cosf(1.5707963267948966f * d)
                             + gk3 * cosf(2.356194490192345f * d))
                      + gk4 * cosf(3.141592653589793f * d);
        hsm[t] = 0.125f * h;
    }
    __syncthreads();
    #pragma unroll
    for (int i = 0; i < 2; i++) {
        int v = t + 256 * i; int x = v & 7; int base = v & ~7;
        float s = 0.f;
        #pragma unroll
        for (int m = 0; m < 8; m++) s += hsm[(x - m) & 7] * pa[base + m];
        pb[v] = s;
    }
    __syncthreads();
    #pragma unroll
    for (int i = 0; i < 2; i++) {
        int v = t + 256 * i; int y = (v >> 3) & 7; int base = (v & ~63) | (v & 7);
        float s = 0.f;
        #pragma unroll
        for (int m = 0; m < 8; m++) s += hsm[(y - m) & 7] * pb[base + m * 8];
        pa[v] = s;
    }
    __syncthreads();
    #pragma unroll
    for (int i = 0; i < 2; i++) {
        int v = t + 256 * i; int z = v >> 6; int base = v & 63;
        float s = 0.f;
        #pragma unroll
        for (int m = 0; m < 8; m++) s += hsm[(z - m) & 7] * pa[base + m * 64];
        pb[v] = s;
    }
    __syncthreads();
    // conv0, vox-major: lane c = oi&31, vox = oi>>5
    #pragma unroll
    for (int i = 0; i < 8; i++) {
        int oi = i * 256 + t;
        int c = oi & 31, vox = oi >> 5;
        int oz = vox >> 4, oy = (vox >> 2) & 3, ox = vox & 3;
        float s = b0c[c];
        #pragma unroll
        for (int kz = 0; kz < 4; kz++) {
            int sz = 2 * oz - 1 + kz; if (sz < 0 || sz > 7) continue;
            #pragma unroll
            for (int ky = 0; ky < 4; ky++) {
                int sy = 2 * oy - 1 + ky; if (sy < 0 || sy > 7) continue;
                #pragma unroll
                for (int kx = 0; kx < 4; kx++) {
                    int sx = 2 * ox - 1 + kx; if (sx < 0 || sx > 7) continue;
                    s += pb[sz * 64 + sy * 8 + sx] * w0st[(kz * 16 + ky * 4 + kx) * 32 + c];
                }
            }
        }
        s = s >= 0.f ? s : 0.2f * s;
        d0s[vox * 33 + c] = s;
    }
    __syncthreads();
    // GN: group g = wave id (8 ch each); lane = vox
    {
        int g = t >> 6, lane = t & 63;
        float s = 0.f, sq = 0.f;
        #pragma unroll
        for (int cc = 0; cc < 8; cc++) { float v = d0s[lane * 33 + g * 8 + cc]; s += v; sq += v * v; }
        #pragma unroll
        for (int m = 1; m < 64; m <<= 1) { s += __shfl_xor(s, m, 64); sq += __shfl_xor(sq, m, 64); }
        if (lane == 0) {
            float mean = s * (1.f / 512.f);
            float var = sq * (1.f / 512.f) - mean * mean;
            gstat[g] = make_float2(mean, rsqrtf(var + 1e-5f));
        }
    }
    __syncthreads();
    size_t obase = (size_t)blk * 2048;
    #pragma unroll
    for (int i = 0; i < 8; i++) {
        int oi = t + 256 * i;
        int c = oi >> 6, vox = oi & 63;
        float2 st = gstat[oi >> 9];
        d0[obase + oi] = f2b((d0s[vox * 33 + c] - st.x) * st.y * g1[c] + be1[c]);
    }
}

// =============== Weight prep kernels (f32 -> transposed bf16 [N][K]) ===============
__global__ __launch_bounds__(256) void k_prep_w1T(const float* __restrict__ w1, unsigned short* __restrict__ w1T)
{
    int idx = blockIdx.x * 256 + threadIdx.x;          // 512 x 2048
    int n = idx >> 11, k = idx & 2047;
    int oc = n >> 3, vox = n & 7;
    int oz = vox >> 2, oy = (vox >> 1) & 1, ox = vox & 1;
    int ci = k >> 6, sp = k & 63;
    int sz = sp >> 4, sy = (sp >> 2) & 3, sx = sp & 3;
    int kz = sz + 1 - 2 * oz, ky = sy + 1 - 2 * oy, kx = sx + 1 - 2 * ox;
    float v = 0.f;
    if ((unsigned)kz < 4u && (unsigned)ky < 4u && (unsigned)kx < 4u)
        v = w1[(size_t)oc * 2048 + ci * 64 + kz * 16 + ky * 4 + kx];
    w1T[idx] = f2b(v);
}

__global__ __launch_bounds__(256) void k_prep_w2T(const float* __restrict__ w2, unsigned short* __restrict__ w2T)
{
    int idx = blockIdx.x * 256 + threadIdx.x;          // 128 x 512
    int n = idx >> 9, k = idx & 511;
    int ci = k >> 3, v = k & 7;
    int z = v >> 2, y = (v >> 1) & 1, x = v & 1;
    w2T[idx] = f2b(w2[(size_t)n * 4096 + ci * 64 + (z + 1) * 16 + (y + 1) * 4 + (x + 1)]);
}

__global__ __launch_bounds__(256) void k_prep_wuT(const float* __restrict__ wu, unsigned short* __restrict__ wuT)
{
    int idx = blockIdx.x * 256 + threadIdx.x;          // wu already [256 out][128 in] = [N][K]
    wuT[idx] = f2b(wu[idx]);
}

__global__ __launch_bounds__(256) void k_prep_b1(const float* __restrict__ b1c, float* __restrict__ b1x)
{
    int idx = blockIdx.x * 256 + threadIdx.x;          // 512
    b1x[idx] = b1c[idx >> 3];
}

// generic: W [L][K][N] f32 -> WT [L][N][K] bf16; K = 1<<kshift
__global__ __launch_bounds__(256) void k_prep_T(const float* __restrict__ W, unsigned short* __restrict__ WT,
                                               int N, int kshift)
{
    int gid = blockIdx.x * 256 + threadIdx.x;
    int l = blockIdx.y;
    int K = 1 << kshift;
    int n = gid >> kshift, k = gid & (K - 1);
    size_t base = (size_t)l * ((size_t)N << kshift);
    WT[base + gid] = f2b(W[base + (size_t)k * N + n]);
}

// pack Wq|Wk|Wv -> WqkvT [L][768][256] bf16 + bqkv [L][768]
__global__ __launch_bounds__(256) void k_prep_qkv(
    const float* __restrict__ Wq, const float* __restrict__ Wk, const float* __restrict__ Wv,
    const float* __restrict__ bq, const float* __restrict__ bk, const float* __restrict__ bv,
    unsigned short* __restrict__ WT, float* __restrict__ bqkv)
{
    int n = blockIdx.x;        // 0..767
    int l = blockIdx.y;
    int k = threadIdx.x;       // 0..255
    int sel = n >> 8, col = n & 255;
    const float* W = sel == 0 ? Wq : sel == 1 ? Wk : Wv;
    const float* bb = sel == 0 ? bq : sel == 1 ? bk : bv;
    WT[((size_t)l * 768 + n) * 256 + k] = f2b(W[(size_t)l * 65536 + (size_t)k * 256 + col]);
    if (k == 0) bqkv[l * 768 + n] = bb[l * 256 + col];
}

// =============== MFMA GEMM: C[M][N] = act(A[M][K]bf16 @ WT[N][K]bf16^T + bias) (+res) ===========
template<int BM>
__global__ __launch_bounds__(256) void k_gemm_bf16(
    const unsigned short* __restrict__ A, const unsigned short* __restrict__ WT,
    const float* __restrict__ bias, const float* __restrict__ res,
    void* __restrict__ Cout, int M, int N, int K, int act, int obf)
{
    constexpr int MREP = BM / 32;
    __shared__ unsigned short Ash[BM][72];
    __shared__ unsigned short Bsh[64][72];
    const int t = threadIdx.x;
    const int c0 = blockIdx.x * 64;
    const int r0 = blockIdx.y * BM;
    const int wid = t >> 6, lane = t & 63;
    const int wr = wid >> 1, wc = wid & 1;
    const int lrow = lane & 15, lk = (lane >> 4) * 8;
    f32x4 acc[MREP][2] = {};
    for (int k0 = 0; k0 < K; k0 += 64) {
        __syncthreads();
        #pragma unroll
        for (int i = 0; i < BM / 32; i++) {
            int f = (i * 256 + t) * 8;
            int r = f >> 6, kk = f & 63;
            *(bf16x8*)&Ash[r][kk] = *(const bf16x8*)(A + (size_t)(r0 + r) * K + k0 + kk);
        }
        #pragma unroll
        for (int i = 0; i < 2; i++) {
            int f = (i * 256 + t) * 8;
            int r = f >> 6, kk = f & 63;
            *(bf16x8*)&Bsh[r][kk] = *(const bf16x8*)(WT + (size_t)(c0 + r) * K + k0 + kk);
        }
        __syncthreads();
        #pragma unroll
        for (int ks = 0; ks < 2; ks++) {
            bf16x8 b0 = *(const bf16x8*)&Bsh[wc * 32 + lrow][ks * 32 + lk];
            bf16x8 b1 = *(const bf16x8*)&Bsh[wc * 32 + 16 + lrow][ks * 32 + lk];
            #pragma unroll
            for (int m = 0; m < MREP; m++) {
                bf16x8 a = *(const bf16x8*)&Ash[wr * (BM / 2) + m * 16 + lrow][ks * 32 + lk];
                acc[m][0] = __builtin_amdgcn_mfma_f32_16x16x32_bf16(a, b0, acc[m][0], 0, 0, 0);
                acc[m][1] = __builtin_amdgcn_mfma_f32_16x16x32_bf16(a, b1, acc[m][1], 0, 0, 0);
            }
        }
    }
    const int rbase = r0 + wr * (BM / 2) + (lane >> 4) * 4;
    #pragma unroll
    for (int n = 0; n < 2; n++) {
        const int col = c0 + wc * 32 + n * 16 + lrow;
        const float bv = bias[col];
        #pragma unroll
        for (int m = 0; m < MREP; m++) {
            #pragma unroll
            for (int r = 0; r < 4; r++) {
                float v = acc[m][n][r] + bv;
                if (act == 1) v = gelu_tanh(v);
                else if (act == 2) v = v >= 0.f ? v : 0.2f * v;
                size_t off = (size_t)(rbase + m * 16 + r) * N + col;
                if (res) v += res[off];
                if (obf) ((unsigned short*)Cout)[off] = f2b(v);
                else ((float*)Cout)[off] = v;
            }
        }
    }
}

// =============== GN2 / GN3 / LNs ===============
__global__ __launch_bounds__(256) void k_gn2(
    const float* __restrict__ din, const float* __restrict__ g2, const float* __restrict__ be2,
    unsigned short* __restrict__ dout)
{
    const int t = threadIdx.x;
    const int w = t >> 6, lane = t & 63;
    const int p = blockIdx.x * 2 + (w >> 1), g = w & 1;
    float4 v = ((const float4*)(din + (size_t)p * 512 + g * 256))[lane];
    float s = v.x + v.y + v.z + v.w;
    float sq = v.x * v.x + v.y * v.y + v.z * v.z + v.w * v.w;
    #pragma unroll
    for (int m = 1; m < 64; m <<= 1) { s += __shfl_xor(s, m, 64); sq += __shfl_xor(sq, m, 64); }
    float mean = s * (1.f / 256.f);
    float rs = rsqrtf(sq * (1.f / 256.f) - mean * mean + 1e-5f);
    int oc = g * 32 + (lane >> 1);
    float gg = g2[oc], bb = be2[oc];
    ushort4 o;
    o.x = f2b((v.x - mean) * rs * gg + bb);
    o.y = f2b((v.y - mean) * rs * gg + bb);
    o.z = f2b((v.z - mean) * rs * gg + bb);
    o.w = f2b((v.w - mean) * rs * gg + bb);
    ((ushort4*)(dout + (size_t)p * 512 + g * 256))[lane] = o;
}

__global__ __launch_bounds__(256) void k_gn3(
    const float* __restrict__ din, const float* __restrict__ g3, const float* __restrict__ be3,
    unsigned short* __restrict__ dout)
{
    const int t = threadIdx.x;
    const int row = blockIdx.x * 4 + (t >> 6);
    const int lane = t & 63;
    float2 v = ((const float2*)(din + (size_t)row * 128))[lane];
    float s = v.x + v.y, sq = v.x * v.x + v.y * v.y;
    #pragma unroll
    for (int m = 1; m < 64; m <<= 1) { s += __shfl_xor(s, m, 64); sq += __shfl_xor(sq, m, 64); }
    float mean = s * (1.f / 128.f);
    float rs = rsqrtf(sq * (1.f / 128.f) - mean * mean + 1e-5f);
    float2 gv = ((const float2*)g3)[lane], bv = ((const float2*)be3)[lane];
    ushort2 o;
    o.x = f2b((v.x - mean) * rs * gv.x + bv.x);
    o.y = f2b((v.y - mean) * rs * gv.y + bv.y);
    ((ushort2*)(dout + (size_t)row * 128))[lane] = o;
}

__global__ __launch_bounds__(256) void k_lnpos(
    const float* __restrict__ u, const float* __restrict__ pos,
    const float* __restrict__ lndg, const float* __restrict__ lndb,
    const float* __restrict__ lnpg, const float* __restrict__ lnpb,
    float* __restrict__ xb)
{
    const int t = threadIdx.x;
    const int row = blockIdx.x * 4 + (t >> 6);
    const int lane = t & 63;
    float4 v = ((const float4*)(u + (size_t)row * 256))[lane];
    float4 w = ((const float4*)(pos + (size_t)(row & 511) * 256))[lane];
    float s = v.x + v.y + v.z + v.w;
    float sq = v.x * v.x + v.y * v.y + v.z * v.z + v.w * v.w;
    float sp = w.x + w.y + w.z + w.w;
    float qp = w.x * w.x + w.y * w.y + w.z * w.z + w.w * w.w;
    #pragma unroll
    for (int m = 1; m < 64; m <<= 1) {
        s += __shfl_xor(s, m, 64); sq += __shfl_xor(sq, m, 64);
        sp += __shfl_xor(sp, m, 64); qp += __shfl_xor(qp, m, 64);
    }
    float mu = s * (1.f / 256.f), ru = rsqrtf(sq * (1.f / 256.f) - mu * mu + 1e-5f);
    float mp = sp * (1.f / 256.f), rp = rsqrtf(qp * (1.f / 256.f) - mp * mp + 1e-5f);
    float4 ga = ((const float4*)lndg)[lane], ba = ((const float4*)lndb)[lane];
    float4 gp = ((const float4*)lnpg)[lane], bp = ((const float4*)lnpb)[lane];
    float4 o;
    o.x = (v.x - mu) * ru * ga.x + ba.x + (w.x - mp) * rp * gp.x + bp.x;
    o.y = (v.y - mu) * ru * ga.y + ba.y + (w.y - mp) * rp * gp.y + bp.y;
    o.z = (v.z - mu) * ru * ga.z + ba.z + (w.z - mp) * rp * gp.z + bp.z;
    o.w = (v.w - mu) * ru * ga.w + ba.w + (w.w - mp) * rp * gp.w + bp.w;
    ((float4*)(xb + (size_t)row * 256))[lane] = o;
}

__global__ __launch_bounds__(256) void k_ln(
    const float* __restrict__ xin, const float* __restrict__ g, const float* __restrict__ b,
    unsigned short* __restrict__ out)
{
    const int t = threadIdx.x;
    const int row = blockIdx.x * 4 + (t >> 6);
    const int lane = t & 63;
    float4 v = ((const float4*)(xin + (size_t)row * 256))[lane];
    float s = v.x + v.y + v.z + v.w;
    float sq = v.x * v.x + v.y * v.y + v.z * v.z + v.w * v.w;
    #pragma unroll
    for (int m = 1; m < 64; m <<= 1) { s += __shfl_xor(s, m, 64); sq += __shfl_xor(sq, m, 64); }
    float mean = s * (1.f / 256.f);
    float rs = rsqrtf(sq * (1.f / 256.f) - mean * mean + 1e-5f);
    float4 gv = ((const float4*)g)[lane], bv = ((const float4*)b)[lane];
    ushort4 o;
    o.x = f2b((v.x - mean) * rs * gv.x + bv.x);
    o.y = f2b((v.y - mean) * rs * gv.y + bv.y);
    o.z = f2b((v.z - mean) * rs * gv.z + bv.z);
    o.w = f2b((v.w - mean) * rs * gv.w + bv.w);
    ((ushort4*)(out + (size_t)row * 256))[lane] = o;
}

// ====== MFMA flash attention: qkv bf16 [8192][768] -> o bf16 [8192][256] ======
// block = (b, h, qtile of 64 rows); 4 waves x 16 q-rows. Per 64-kv chunk:
// 4 QK mfmas (hd=32 = one mfma K), online softmax in C-layout, P->LDS transpose, 4 PV mfmas.
__global__ __launch_bounds__(256) void k_attn3(
    const unsigned short* __restrict__ qkv, unsigned short* __restrict__ og)
{
    __shared__ unsigned short Ks[64][36];
    __shared__ unsigned short Vt[32][72];
    __shared__ unsigned short Pt[4][16][72];
    const int t = threadIdx.x;
    const int bid = blockIdx.x;            // b*64 + h*8 + qt
    const int b = bid >> 6, hh = (bid >> 3) & 7, qt = bid & 7;
    const int wid = t >> 6, lane = t & 63;
    const int lr = lane & 15, lk8 = (lane >> 4) * 8;
    const int qrow = b * 512 + qt * 64 + wid * 16 + lr;
    const bf16x8 qf = *(const bf16x8*)(qkv + (size_t)qrow * 768 + hh * 32 + lk8);
    f32x4 O0 = {}, O1 = {};
    float mreg[4] = { -1e30f, -1e30f, -1e30f, -1e30f };
    float lreg[4] = {};
    const float scale = 0.17677669529663687f;
    for (int kv0 = 0; kv0 < 512; kv0 += 64) {
        __syncthreads();
        {
            int kvr = t >> 2, dd = (t & 3) * 8;
            size_t base = (size_t)(b * 512 + kv0 + kvr) * 768 + hh * 32;
            *(bf16x8*)&Ks[kvr][dd] = *(const bf16x8*)(qkv + base + 256 + dd);
            bf16x8 v8 = *(const bf16x8*)(qkv + base + 512 + dd);
            #pragma unroll
            for (int j = 0; j < 8; j++) Vt[dd + j][kvr] = (unsigned short)v8[j];
        }
        __syncthreads();
        f32x4 st[4];
        #pragma unroll
        for (int tt = 0; tt < 4; tt++) {
            bf16x8 kf = *(const bf16x8*)&Ks[tt * 16 + lr][lk8];
            st[tt] = __builtin_amdgcn_mfma_f32_16x16x32_bf16(qf, kf, (f32x4){}, 0, 0, 0);
        }
        float mnew[4], csc[4], psum[4];
        #pragma unroll
        for (int r = 0; r < 4; r++) {
            st[0][r] *= scale; st[1][r] *= scale; st[2][r] *= scale; st[3][r] *= scale;
            float mx = fmaxf(fmaxf(st[0][r], st[1][r]), fmaxf(st[2][r], st[3][r]));
            mx = fmaxf(mx, __shfl_xor(mx, 1));
            mx = fmaxf(mx, __shfl_xor(mx, 2));
            mx = fmaxf(mx, __shfl_xor(mx, 4));
            mx = fmaxf(mx, __shfl_xor(mx, 8));
            mnew[r] = fmaxf(mreg[r], mx);
            csc[r] = __expf(mreg[r] - mnew[r]);
            mreg[r] = mnew[r];
            psum[r] = 0.f;
        }
        #pragma unroll
        for (int tt = 0; tt < 4; tt++)
            #pragma unroll
            for (int r = 0; r < 4; r++) {
                float p = __expf(st[tt][r] - mnew[r]);
                st[tt][r] = p;
                psum[r] += p;
            }
        #pragma unroll
        for (int r = 0; r < 4; r++) {
            psum[r] += __shfl_xor(psum[r], 1);
            psum[r] += __shfl_xor(psum[r], 2);
            psum[r] += __shfl_xor(psum[r], 4);
            psum[r] += __shfl_xor(psum[r], 8);
            lreg[r] = lreg[r] * csc[r] + psum[r];
            O0[r] *= csc[r]; O1[r] *= csc[r];
        }
        // P (C-layout: row=(lane>>4)*4+r, col=tt*16+lr) -> Pt[wid][q][kv] bf16
        #pragma unroll
        for (int tt = 0; tt < 4; tt++)
            #pragma unroll
            for (int r = 0; r < 4; r++)
                Pt[wid][(lane >> 4) * 4 + r][tt * 16 + lr] = f2b(st[tt][r]);
        // PV: A = P[16q][32kv], B = Vt[d][kv]
        #pragma unroll
        for (int half = 0; half < 2; half++) {
            bf16x8 pa  = *(const bf16x8*)&Pt[wid][lr][half * 32 + lk8];
            bf16x8 vlo = *(const bf16x8*)&Vt[lr][half * 32 + lk8];
            bf16x8 vhi = *(const bf16x8*)&Vt[16 + lr][half * 32 + lk8];
            O0 = __builtin_amdgcn_mfma_f32_16x16x32_bf16(pa, vlo, O0, 0, 0, 0);
            O1 = __builtin_amdgcn_mfma_f32_16x16x32_bf16(pa, vhi, O1, 0, 0, 0);
        }
    }
    #pragma unroll
    for (int r = 0; r < 4; r++) {
        float inv = 1.f / lreg[r];
        size_t orow = (size_t)(b * 512 + qt * 64 + wid * 16 + (lane >> 4) * 4 + r) * 256 + hh * 32;
        og[orow + lr] = f2b(O0[r] * inv);
        og[orow + 16 + lr] = f2b(O1[r] * inv);
    }
}

extern "C" void kernel_launch(void* const* d_in, const int* in_sizes, int n_in,
                              void* d_out, int out_size, void* d_ws, size_t ws_size,
                              hipStream_t stream)
{
    const float* img  = (const float*)d_in[0];
    const float* bfac = (const float*)d_in[1];
    const float* w0  = (const float*)d_in[2];  const float* b0c = (const float*)d_in[3];
    const float* g1  = (const float*)d_in[4];  const float* be1 = (const float*)d_in[5];
    const float* w1  = (const float*)d_in[6];  const float* b1c = (const float*)d_in[7];
    const float* g2  = (const float*)d_in[8];  const float* be2 = (const float*)d_in[9];
    const float* w2  = (const float*)d_in[10]; const float* b2c = (const float*)d_in[11];
    const float* g3  = (const float*)d_in[12]; const float* be3 = (const float*)d_in[13];
    const float* wu  = (const float*)d_in[14]; const float* bu  = (const float*)d_in[15];
    const float* pos = (const float*)d_in[16];
    const float* lndg = (const float*)d_in[17]; const float* lndb = (const float*)d_in[18];
    const float* lnpg = (const float*)d_in[19]; const float* lnpb = (const float*)d_in[20];
    const float* Wq = (const float*)d_in[21]; const float* bq = (const float*)d_in[22];
    const float* Wk = (const float*)d_in[23]; const float* bk = (const float*)d_in[24];
    const float* Wv = (const float*)d_in[25]; const float* bv = (const float*)d_in[26];
    const float* Wo = (const float*)d_in[27]; const float* bo = (const float*)d_in[28];
    const float* l1g = (const float*)d_in[29]; const float* l1b = (const float*)d_in[30];
    const float* l2g = (const float*)d_in[31]; const float* l2b = (const float*)d_in[32];
    const float* W1 = (const float*)d_in[33]; const float* bf1 = (const float*)d_in[34];
    const float* W2 = (const float*)d_in[35]; const float* bf2 = (const float*)d_in[36];

    float* ws = (float*)d_ws;
    // Persistent:
    unsigned short* d0b   = (unsigned short*)(ws);              // [8192][2048] bf16 -> 8,388,608 fl
    float*          d1raw = ws + 8388608;                       // [8192][512] f32
    unsigned short* d1b   = (unsigned short*)(ws + 12582912);   // [8192][512] bf16
    float*          xb    = ws + 14680064;                      // [8192][256] f32
    // Weights (bf16, transposed):
    unsigned short* w1T   = (unsigned short*)(ws + 16777216);   // 512x2048
    unsigned short* w2T   = (unsigned short*)(ws + 17301504);   // 128x512
    unsigned short* wuTb  = (unsigned short*)(ws + 17334272);   // 256x128
    unsigned short* WqkvT = (unsigned short*)(ws + 17350656);   // 8x768x256 -> 786,432 fl
    unsigned short* WoT   = (unsigned short*)(ws + 18137088);   // 8x256x256
    unsigned short* W1T   = (unsigned short*)(ws + 18399232);   // 8x1024x256
    unsigned short* W2T   = (unsigned short*)(ws + 19447808);   // 8x256x1024
    float*          b1x   = ws + 20496384;                      // 512
    float*          bqkv  = ws + 20496896;                      // 8x768 -> ends 20,503,040
    // Phase C overlay (d0b region dead after conv1 GEMM):
    float*          d2raw = ws;                                 // [8192][128] f32
    unsigned short* d2b   = (unsigned short*)(ws + 1048576);    // [8192][128] bf16
    float*          ub    = ws + 1572864;                       // [8192][256] f32
    // Phase D overlay:
    unsigned short* hb    = (unsigned short*)(ws);              // [8192][256] bf16
    unsigned short* qkvb  = (unsigned short*)(ws + 1048576);    // [8192][768] bf16 -> 3,145,728 fl
    unsigned short* obb   = (unsigned short*)(ws + 4194304);    // [8192][256] bf16
    unsigned short* m1b   = (unsigned short*)(ws + 5242880);    // [8192][1024] bf16 -> ends 9,437,184
    float* xout = (float*)d_out;

    // Weight prep
    k_prep_w1T<<<4096, 256, 0, stream>>>(w1, w1T);
    k_prep_w2T<<<256, 256, 0, stream>>>(w2, w2T);
    k_prep_wuT<<<128, 256, 0, stream>>>(wu, wuTb);
    k_prep_b1<<<2, 256, 0, stream>>>(b1c, b1x);
    k_prep_qkv<<<dim3(768, 8), 256, 0, stream>>>(Wq, Wk, Wv, bq, bk, bv, WqkvT, bqkv);
    k_prep_T<<<dim3(256, 8), 256, 0, stream>>>(Wo, WoT, 256, 8);
    k_prep_T<<<dim3(1024, 8), 256, 0, stream>>>(W1, W1T, 1024, 8);
    k_prep_T<<<dim3(1024, 8), 256, 0, stream>>>(W2, W2T, 256, 10);

    // Encoder
    k_blur_conv0<<<8192, 256, 0, stream>>>(img, bfac, w0, b0c, g1, be1, d0b);
    k_gemm_bf16<128><<<dim3(8, 64), 256, 0, stream>>>(d0b, w1T, b1x, nullptr, d1raw, 8192, 512, 2048, 2, 0);
    k_gn2<<<4096, 256, 0, stream>>>(d1raw, g2, be2, d1b);
    k_gemm_bf16<128><<<dim3(2, 64), 256, 0, stream>>>(d1b, w2T, b2c, nullptr, d2raw, 8192, 128, 512, 2, 0);
    k_gn3<<<2048, 256, 0, stream>>>(d2raw, g3, be3, d2b);
    k_gemm_bf16<128><<<dim3(4, 64), 256, 0, stream>>>(d2b, wuTb, bu, nullptr, ub, 8192, 256, 128, 0, 0);
    k_lnpos<<<2048, 256, 0, stream>>>(ub, pos, lndg, lndb, lnpg, lnpb, xb);

    // Transformer
    for (int i = 0; i < 8; i++) {
        k_ln<<<2048, 256, 0, stream>>>(xb, l1g + i * 256, l1b + i * 256, hb);
        k_gemm_bf16<128><<<dim3(12, 64), 256, 0, stream>>>(hb, WqkvT + (size_t)i * 196608, bqkv + i * 768, nullptr, qkvb, 8192, 768, 256, 0, 1);
        k_attn3<<<1024, 256, 0, stream>>>(qkvb, obb);
        k_gemm_bf16<128><<<dim3(4, 64), 256, 0, stream>>>(obb, WoT + (size_t)i * 65536, bo + i * 256, xb, xb, 8192, 256, 256, 0, 0);
        k_ln<<<2048, 256, 0, stream>>>(xb, l2g + i * 256, l2b + i * 256, hb);
        k_gemm_bf16<128><<<dim3(16, 64), 256, 0, stream>>>(hb, W1T + (size_t)i * 262144, bf1 + i * 1024, nullptr, m1b, 8192, 1024, 256, 1, 1);
        k_gemm_bf16<128><<<dim3(4, 64), 256, 0, stream>>>(m1b, W2T + (size_t)i * 262144, bf2 + i * 256, xb, (i == 7) ? xout : xb, 8192, 256, 1024, 0, 0);
    }
}

// Round 8
// 1025.827 us; speedup vs baseline: 5.8116x; 1.0926x over previous
//
#include <hip/hip_runtime.h>
#include <hip/hip_bf16.h>

#define PI2F 9.869604401089358f

typedef __attribute__((ext_vector_type(8))) short bf16x8;
typedef __attribute__((ext_vector_type(4))) float f32x4;

__device__ inline unsigned short f2b(float v) {
    union { float f; unsigned u; } x; x.f = v;
    unsigned r = x.u + 0x7fffu + ((x.u >> 16) & 1u);
    return (unsigned short)(r >> 16);
}

__device__ inline float gelu_tanh(float v) {
    float u = 0.7978845608028654f * (v + 0.044715f * v * v * v);
    float th = 1.f - 2.f / (1.f + __expf(2.f * u));
    return 0.5f * v * (1.f + th);
}

// =============== Kernel A: unfold + separable circular blur + conv0 + leaky + GN(G=4) ===========
// conv0: vox-major lanes (32 lanes share vox -> pb broadcast); w0 taps in REGISTERS (c = t&31).
__global__ __launch_bounds__(256) void k_blur_conv0(
    const float* __restrict__ img, const float* __restrict__ bfac,
    const float* __restrict__ w0, const float* __restrict__ b0c,
    const float* __restrict__ g1, const float* __restrict__ be1,
    unsigned short* __restrict__ d0)
{
    __shared__ float pa[512], pb[512], w0st[2048], d0s[64 * 33], hsm[8];
    __shared__ float2 gstat[4];
    const int t = threadIdx.x, blk = blockIdx.x;
    const int b = blk >> 9, rem = blk & 511;
    const int zh = rem >> 6, yh = (rem >> 3) & 7, xh = rem & 7;

    #pragma unroll
    for (int i = 0; i < 2; i++) {
        int v = t + 256 * i;
        int z = v >> 6, y = (v >> 3) & 7, x = v & 7;
        pa[v] = img[(((size_t)(b * 8 + zh) * 8 + z) * 64 + yh * 8 + y) * 64 + xh * 8 + x];
    }
    for (int i = t; i < 2048; i += 256) w0st[i] = w0[(i & 31) * 64 + (i >> 5)];
    if (t < 8) {
        float bf = bfac[blk];
        float c = bf * PI2F * (1.0f / 16.0f);
        float gk1 = __expf(-c), gk2 = __expf(-4.f * c), gk3 = __expf(-9.f * c), gk4 = __expf(-16.f * c);
        float d = (float)t;
        float h = 1.f + 2.f * (gk1 * cosf(0.7853981633974483f * d)
                             + gk2 * cosf(1.5707963267948966f * d)
                             + gk3 * cosf(2.356194490192345f * d))
                      + gk4 * cosf(3.141592653589793f * d);
        hsm[t] = 0.125f * h;
    }
    __syncthreads();
    #pragma unroll
    for (int i = 0; i < 2; i++) {
        int v = t + 256 * i; int x = v & 7; int base = v & ~7;
        float s = 0.f;
        #pragma unroll
        for (int m = 0; m < 8; m++) s += hsm[(x - m) & 7] * pa[base + m];
        pb[v] = s;
    }
    __syncthreads();
    #pragma unroll
    for (int i = 0; i < 2; i++) {
        int v = t + 256 * i; int y = (v >> 3) & 7; int base = (v & ~63) | (v & 7);
        float s = 0.f;
        #pragma unroll
        for (int m = 0; m < 8; m++) s += hsm[(y - m) & 7] * pb[base + m * 8];
        pa[v] = s;
    }
    __syncthreads();
    #pragma unroll
    for (int i = 0; i < 2; i++) {
        int v = t + 256 * i; int z = v >> 6; int base = v & 63;
        float s = 0.f;
        #pragma unroll
        for (int m = 0; m < 8; m++) s += hsm[(z - m) & 7] * pa[base + m * 64];
        pb[v] = s;
    }
    __syncthreads();
    // preload this thread's channel weights into registers
    float wreg[64];
    {
        const int c = t & 31;
        #pragma unroll
        for (int tap = 0; tap < 64; tap++) wreg[tap] = w0st[tap * 32 + c];
    }
    const float bias0 = b0c[t & 31];
    // conv0, vox-major: lane c = t&31, vox = (i*256+t)>>5
    #pragma unroll
    for (int i = 0; i < 8; i++) {
        int oi = i * 256 + t;
        int c = t & 31, vox = oi >> 5;
        int oz = vox >> 4, oy = (vox >> 2) & 3, ox = vox & 3;
        float s = bias0;
        #pragma unroll
        for (int kz = 0; kz < 4; kz++) {
            int sz = 2 * oz - 1 + kz; if (sz < 0 || sz > 7) continue;
            #pragma unroll
            for (int ky = 0; ky < 4; ky++) {
                int sy = 2 * oy - 1 + ky; if (sy < 0 || sy > 7) continue;
                #pragma unroll
                for (int kx = 0; kx < 4; kx++) {
                    int sx = 2 * ox - 1 + kx; if (sx < 0 || sx > 7) continue;
                    s += pb[sz * 64 + sy * 8 + sx] * wreg[kz * 16 + ky * 4 + kx];
                }
            }
        }
        s = s >= 0.f ? s : 0.2f * s;
        d0s[vox * 33 + c] = s;
    }
    __syncthreads();
    {
        int g = t >> 6, lane = t & 63;
        float s = 0.f, sq = 0.f;
        #pragma unroll
        for (int cc = 0; cc < 8; cc++) { float v = d0s[lane * 33 + g * 8 + cc]; s += v; sq += v * v; }
        #pragma unroll
        for (int m = 1; m < 64; m <<= 1) { s += __shfl_xor(s, m, 64); sq += __shfl_xor(sq, m, 64); }
        if (lane == 0) {
            float mean = s * (1.f / 512.f);
            float var = sq * (1.f / 512.f) - mean * mean;
            gstat[g] = make_float2(mean, rsqrtf(var + 1e-5f));
        }
    }
    __syncthreads();
    size_t obase = (size_t)blk * 2048;
    #pragma unroll
    for (int i = 0; i < 8; i++) {
        int oi = t + 256 * i;
        int c = oi >> 6, vox = oi & 63;
        float2 st = gstat[oi >> 9];
        d0[obase + oi] = f2b((d0s[vox * 33 + c] - st.x) * st.y * g1[c] + be1[c]);
    }
}

// =============== Weight prep kernels ===============
__global__ __launch_bounds__(256) void k_prep_w1T(const float* __restrict__ w1, unsigned short* __restrict__ w1T)
{
    int idx = blockIdx.x * 256 + threadIdx.x;
    int n = idx >> 11, k = idx & 2047;
    int oc = n >> 3, vox = n & 7;
    int oz = vox >> 2, oy = (vox >> 1) & 1, ox = vox & 1;
    int ci = k >> 6, sp = k & 63;
    int sz = sp >> 4, sy = (sp >> 2) & 3, sx = sp & 3;
    int kz = sz + 1 - 2 * oz, ky = sy + 1 - 2 * oy, kx = sx + 1 - 2 * ox;
    float v = 0.f;
    if ((unsigned)kz < 4u && (unsigned)ky < 4u && (unsigned)kx < 4u)
        v = w1[(size_t)oc * 2048 + ci * 64 + kz * 16 + ky * 4 + kx];
    w1T[idx] = f2b(v);
}

__global__ __launch_bounds__(256) void k_prep_w2T(const float* __restrict__ w2, unsigned short* __restrict__ w2T)
{
    int idx = blockIdx.x * 256 + threadIdx.x;
    int n = idx >> 9, k = idx & 511;
    int ci = k >> 3, v = k & 7;
    int z = v >> 2, y = (v >> 1) & 1, x = v & 1;
    w2T[idx] = f2b(w2[(size_t)n * 4096 + ci * 64 + (z + 1) * 16 + (y + 1) * 4 + (x + 1)]);
}

__global__ __launch_bounds__(256) void k_prep_wuT(const float* __restrict__ wu, unsigned short* __restrict__ wuT)
{
    int idx = blockIdx.x * 256 + threadIdx.x;
    wuT[idx] = f2b(wu[idx]);
}

__global__ __launch_bounds__(256) void k_prep_b1(const float* __restrict__ b1c, float* __restrict__ b1x)
{
    int idx = blockIdx.x * 256 + threadIdx.x;
    b1x[idx] = b1c[idx >> 3];
}

__global__ __launch_bounds__(256) void k_prep_T(const float* __restrict__ W, unsigned short* __restrict__ WT,
                                               int N, int kshift)
{
    int gid = blockIdx.x * 256 + threadIdx.x;
    int l = blockIdx.y;
    int K = 1 << kshift;
    int n = gid >> kshift, k = gid & (K - 1);
    size_t base = (size_t)l * ((size_t)N << kshift);
    WT[base + gid] = f2b(W[base + (size_t)k * N + n]);
}

__global__ __launch_bounds__(256) void k_prep_qkv(
    const float* __restrict__ Wq, const float* __restrict__ Wk, const float* __restrict__ Wv,
    const float* __restrict__ bq, const float* __restrict__ bk, const float* __restrict__ bv,
    unsigned short* __restrict__ WT, float* __restrict__ bqkv)
{
    int n = blockIdx.x;
    int l = blockIdx.y;
    int k = threadIdx.x;
    int sel = n >> 8, col = n & 255;
    const float* W = sel == 0 ? Wq : sel == 1 ? Wk : Wv;
    const float* bb = sel == 0 ? bq : sel == 1 ? bk : bv;
    WT[((size_t)l * 768 + n) * 256 + k] = f2b(W[(size_t)l * 65536 + (size_t)k * 256 + col]);
    if (k == 0) bqkv[l * 768 + n] = bb[l * 256 + col];
}

// =============== MFMA GEMM: C[M][N] = act(A@WT^T + bias) (+res) ===============
template<int BM>
__global__ __launch_bounds__(256) void k_gemm_bf16(
    const unsigned short* __restrict__ A, const unsigned short* __restrict__ WT,
    const float* __restrict__ bias, const float* __restrict__ res,
    void* __restrict__ Cout, int M, int N, int K, int act, int obf)
{
    constexpr int MREP = BM / 32;
    __shared__ unsigned short Ash[BM][72];
    __shared__ unsigned short Bsh[64][72];
    const int t = threadIdx.x;
    const int c0 = blockIdx.x * 64;
    const int r0 = blockIdx.y * BM;
    const int wid = t >> 6, lane = t & 63;
    const int wr = wid >> 1, wc = wid & 1;
    const int lrow = lane & 15, lk = (lane >> 4) * 8;
    f32x4 acc[MREP][2] = {};
    for (int k0 = 0; k0 < K; k0 += 64) {
        __syncthreads();
        #pragma unroll
        for (int i = 0; i < BM / 32; i++) {
            int f = (i * 256 + t) * 8;
            int r = f >> 6, kk = f & 63;
            *(bf16x8*)&Ash[r][kk] = *(const bf16x8*)(A + (size_t)(r0 + r) * K + k0 + kk);
        }
        #pragma unroll
        for (int i = 0; i < 2; i++) {
            int f = (i * 256 + t) * 8;
            int r = f >> 6, kk = f & 63;
            *(bf16x8*)&Bsh[r][kk] = *(const bf16x8*)(WT + (size_t)(c0 + r) * K + k0 + kk);
        }
        __syncthreads();
        #pragma unroll
        for (int ks = 0; ks < 2; ks++) {
            bf16x8 b0 = *(const bf16x8*)&Bsh[wc * 32 + lrow][ks * 32 + lk];
            bf16x8 b1 = *(const bf16x8*)&Bsh[wc * 32 + 16 + lrow][ks * 32 + lk];
            #pragma unroll
            for (int m = 0; m < MREP; m++) {
                bf16x8 a = *(const bf16x8*)&Ash[wr * (BM / 2) + m * 16 + lrow][ks * 32 + lk];
                acc[m][0] = __builtin_amdgcn_mfma_f32_16x16x32_bf16(a, b0, acc[m][0], 0, 0, 0);
                acc[m][1] = __builtin_amdgcn_mfma_f32_16x16x32_bf16(a, b1, acc[m][1], 0, 0, 0);
            }
        }
    }
    const int rbase = r0 + wr * (BM / 2) + (lane >> 4) * 4;
    #pragma unroll
    for (int n = 0; n < 2; n++) {
        const int col = c0 + wc * 32 + n * 16 + lrow;
        const float bv = bias[col];
        #pragma unroll
        for (int m = 0; m < MREP; m++) {
            #pragma unroll
            for (int r = 0; r < 4; r++) {
                float v = acc[m][n][r] + bv;
                if (act == 1) v = gelu_tanh(v);
                else if (act == 2) v = v >= 0.f ? v : 0.2f * v;
                size_t off = (size_t)(rbase + m * 16 + r) * N + col;
                if (res) v += res[off];
                if (obf) ((unsigned short*)Cout)[off] = f2b(v);
                else ((float*)Cout)[off] = v;
            }
        }
    }
}

// ====== Fused GEMM + residual + row-LN. BM=32, N=256 fixed, 512 threads (8 waves x 32 cols). ======
// Writes xnew[M][256] f32 (acc+bias+res) and, if lng!=null, h[M][256] bf16 = LN(xnew)*lng+lnb.
__global__ __launch_bounds__(512) void k_gemm_ln(
    const unsigned short* __restrict__ A, const unsigned short* __restrict__ WT,
    const float* __restrict__ bias, const float* __restrict__ res,
    const float* __restrict__ lng, const float* __restrict__ lnb,
    float* __restrict__ xnew, unsigned short* __restrict__ h, int K)
{
    __shared__ __align__(16) char smem[41472];
    unsigned short (*Ash)[72] = (unsigned short(*)[72])smem;                // 32 rows
    unsigned short (*Bsh)[72] = (unsigned short(*)[72])(smem + 4608);      // 256 rows
    float (*vals)[264] = (float(*)[264])smem;                              // 32 x 264
    const int t = threadIdx.x;
    const int r0 = blockIdx.x * 32;
    const int wid = t >> 6, lane = t & 63;
    const int lrow = lane & 15, lk8 = (lane >> 4) * 8;
    f32x4 acc[2][2] = {};
    for (int k0 = 0; k0 < K; k0 += 64) {
        __syncthreads();
        if (t < 256) {
            int f = t * 8;
            int r = f >> 6, kk = f & 63;
            *(bf16x8*)&Ash[r][kk] = *(const bf16x8*)(A + (size_t)(r0 + r) * K + k0 + kk);
        }
        #pragma unroll
        for (int i = 0; i < 4; i++) {
            int f = (i * 512 + t) * 8;
            int r = f >> 6, kk = f & 63;
            *(bf16x8*)&Bsh[r][kk] = *(const bf16x8*)(WT + (size_t)r * K + k0 + kk);
        }
        __syncthreads();
        #pragma unroll
        for (int ks = 0; ks < 2; ks++) {
            bf16x8 a0 = *(const bf16x8*)&Ash[lrow][ks * 32 + lk8];
            bf16x8 a1 = *(const bf16x8*)&Ash[16 + lrow][ks * 32 + lk8];
            #pragma unroll
            for (int nf = 0; nf < 2; nf++) {
                bf16x8 bfr = *(const bf16x8*)&Bsh[wid * 32 + nf * 16 + lrow][ks * 32 + lk8];
                acc[0][nf] = __builtin_amdgcn_mfma_f32_16x16x32_bf16(a0, bfr, acc[0][nf], 0, 0, 0);
                acc[1][nf] = __builtin_amdgcn_mfma_f32_16x16x32_bf16(a1, bfr, acc[1][nf], 0, 0, 0);
            }
        }
    }
    __syncthreads();
    #pragma unroll
    for (int m = 0; m < 2; m++)
        #pragma unroll
        for (int nf = 0; nf < 2; nf++) {
            int col = wid * 32 + nf * 16 + lrow;
            float bv = bias[col];
            #pragma unroll
            for (int r = 0; r < 4; r++) {
                int row = m * 16 + (lane >> 4) * 4 + r;
                vals[row][col] = acc[m][nf][r] + bv + res[(size_t)(r0 + row) * 256 + col];
            }
        }
    __syncthreads();
    // row-LN: 16 threads per row, 16 cols each (4x float4)
    const int row = t >> 4, c4 = (t & 15) * 4;
    float s = 0.f, sq = 0.f;
    #pragma unroll
    for (int j = 0; j < 4; j++) {
        float4 v4 = *(const float4*)&vals[row][c4 + j * 64];
        s += v4.x + v4.y + v4.z + v4.w;
        sq += v4.x * v4.x + v4.y * v4.y + v4.z * v4.z + v4.w * v4.w;
    }
    s += __shfl_xor(s, 1); sq += __shfl_xor(sq, 1);
    s += __shfl_xor(s, 2); sq += __shfl_xor(sq, 2);
    s += __shfl_xor(s, 4); sq += __shfl_xor(sq, 4);
    s += __shfl_xor(s, 8); sq += __shfl_xor(sq, 8);
    float mean = s * (1.f / 256.f);
    float rs = rsqrtf(sq * (1.f / 256.f) - mean * mean + 1e-5f);
    const size_t gbase = (size_t)(r0 + row) * 256;
    #pragma unroll
    for (int j = 0; j < 4; j++) {
        int col = c4 + j * 64;
        float4 v4 = *(const float4*)&vals[row][col];
        *(float4*)(xnew + gbase + col) = v4;
        if (lng) {
            float4 g4 = *(const float4*)(lng + col);
            float4 b4 = *(const float4*)(lnb + col);
            ushort4 o;
            o.x = f2b((v4.x - mean) * rs * g4.x + b4.x);
            o.y = f2b((v4.y - mean) * rs * g4.y + b4.y);
            o.z = f2b((v4.z - mean) * rs * g4.z + b4.z);
            o.w = f2b((v4.w - mean) * rs * g4.w + b4.w);
            *(ushort4*)(h + gbase + col) = o;
        }
    }
}

// =============== GN2 / GN3 ===============
__global__ __launch_bounds__(256) void k_gn2(
    const float* __restrict__ din, const float* __restrict__ g2, const float* __restrict__ be2,
    unsigned short* __restrict__ dout)
{
    const int t = threadIdx.x;
    const int w = t >> 6, lane = t & 63;
    const int p = blockIdx.x * 2 + (w >> 1), g = w & 1;
    float4 v = ((const float4*)(din + (size_t)p * 512 + g * 256))[lane];
    float s = v.x + v.y + v.z + v.w;
    float sq = v.x * v.x + v.y * v.y + v.z * v.z + v.w * v.w;
    #pragma unroll
    for (int m = 1; m < 64; m <<= 1) { s += __shfl_xor(s, m, 64); sq += __shfl_xor(sq, m, 64); }
    float mean = s * (1.f / 256.f);
    float rs = rsqrtf(sq * (1.f / 256.f) - mean * mean + 1e-5f);
    int oc = g * 32 + (lane >> 1);
    float gg = g2[oc], bb = be2[oc];
    ushort4 o;
    o.x = f2b((v.x - mean) * rs * gg + bb);
    o.y = f2b((v.y - mean) * rs * gg + bb);
    o.z = f2b((v.z - mean) * rs * gg + bb);
    o.w = f2b((v.w - mean) * rs * gg + bb);
    ((ushort4*)(dout + (size_t)p * 512 + g * 256))[lane] = o;
}

__global__ __launch_bounds__(256) void k_gn3(
    const float* __restrict__ din, const float* __restrict__ g3, const float* __restrict__ be3,
    unsigned short* __restrict__ dout)
{
    const int t = threadIdx.x;
    const int row = blockIdx.x * 4 + (t >> 6);
    const int lane = t & 63;
    float2 v = ((const float2*)(din + (size_t)row * 128))[lane];
    float s = v.x + v.y, sq = v.x * v.x + v.y * v.y;
    #pragma unroll
    for (int m = 1; m < 64; m <<= 1) { s += __shfl_xor(s, m, 64); sq += __shfl_xor(sq, m, 64); }
    float mean = s * (1.f / 128.f);
    float rs = rsqrtf(sq * (1.f / 128.f) - mean * mean + 1e-5f);
    float2 gv = ((const float2*)g3)[lane], bv = ((const float2*)be3)[lane];
    ushort2 o;
    o.x = f2b((v.x - mean) * rs * gv.x + bv.x);
    o.y = f2b((v.y - mean) * rs * gv.y + bv.y);
    ((ushort2*)(dout + (size_t)row * 128))[lane] = o;
}

// ====== LN(u)+LN(pos) -> xb f32, and hb = LN_{l1[0]}(xb) bf16. Wave per row. ======
__global__ __launch_bounds__(256) void k_lnpos(
    const float* __restrict__ u, const float* __restrict__ pos,
    const float* __restrict__ lndg, const float* __restrict__ lndb,
    const float* __restrict__ lnpg, const float* __restrict__ lnpb,
    const float* __restrict__ l1g0, const float* __restrict__ l1b0,
    float* __restrict__ xb, unsigned short* __restrict__ hb)
{
    const int t = threadIdx.x;
    const int row = blockIdx.x * 4 + (t >> 6);
    const int lane = t & 63;
    float4 v = ((const float4*)(u + (size_t)row * 256))[lane];
    float4 w = ((const float4*)(pos + (size_t)(row & 511) * 256))[lane];
    float s = v.x + v.y + v.z + v.w;
    float sq = v.x * v.x + v.y * v.y + v.z * v.z + v.w * v.w;
    float sp = w.x + w.y + w.z + w.w;
    float qp = w.x * w.x + w.y * w.y + w.z * w.z + w.w * w.w;
    #pragma unroll
    for (int m = 1; m < 64; m <<= 1) {
        s += __shfl_xor(s, m, 64); sq += __shfl_xor(sq, m, 64);
        sp += __shfl_xor(sp, m, 64); qp += __shfl_xor(qp, m, 64);
    }
    float mu = s * (1.f / 256.f), ru = rsqrtf(sq * (1.f / 256.f) - mu * mu + 1e-5f);
    float mp = sp * (1.f / 256.f), rp = rsqrtf(qp * (1.f / 256.f) - mp * mp + 1e-5f);
    float4 ga = ((const float4*)lndg)[lane], ba = ((const float4*)lndb)[lane];
    float4 gp = ((const float4*)lnpg)[lane], bp = ((const float4*)lnpb)[lane];
    float4 o;
    o.x = (v.x - mu) * ru * ga.x + ba.x + (w.x - mp) * rp * gp.x + bp.x;
    o.y = (v.y - mu) * ru * ga.y + ba.y + (w.y - mp) * rp * gp.y + bp.y;
    o.z = (v.z - mu) * ru * ga.z + ba.z + (w.z - mp) * rp * gp.z + bp.z;
    o.w = (v.w - mu) * ru * ga.w + ba.w + (w.w - mp) * rp * gp.w + bp.w;
    ((float4*)(xb + (size_t)row * 256))[lane] = o;
    // second LN over x with l1[0] params
    float s2 = o.x + o.y + o.z + o.w;
    float q2 = o.x * o.x + o.y * o.y + o.z * o.z + o.w * o.w;
    #pragma unroll
    for (int m = 1; m < 64; m <<= 1) { s2 += __shfl_xor(s2, m, 64); q2 += __shfl_xor(q2, m, 64); }
    float mu2 = s2 * (1.f / 256.f), r2 = rsqrtf(q2 * (1.f / 256.f) - mu2 * mu2 + 1e-5f);
    float4 g4 = ((const float4*)l1g0)[lane], b4 = ((const float4*)l1b0)[lane];
    ushort4 ho;
    ho.x = f2b((o.x - mu2) * r2 * g4.x + b4.x);
    ho.y = f2b((o.y - mu2) * r2 * g4.y + b4.y);
    ho.z = f2b((o.z - mu2) * r2 * g4.z + b4.z);
    ho.w = f2b((o.w - mu2) * r2 * g4.w + b4.w);
    ((ushort4*)(hb + (size_t)row * 256))[lane] = ho;
}

// ====== MFMA flash attention: qkv bf16 [8192][768] -> o bf16 [8192][256] ======
__global__ __launch_bounds__(256) void k_attn3(
    const unsigned short* __restrict__ qkv, unsigned short* __restrict__ og)
{
    __shared__ unsigned short Ks[64][36];
    __shared__ unsigned short Vt[32][72];
    __shared__ unsigned short Pt[4][16][72];
    const int t = threadIdx.x;
    const int bid = blockIdx.x;
    const int b = bid >> 6, hh = (bid >> 3) & 7, qt = bid & 7;
    const int wid = t >> 6, lane = t & 63;
    const int lr = lane & 15, lk8 = (lane >> 4) * 8;
    const int qrow = b * 512 + qt * 64 + wid * 16 + lr;
    const bf16x8 qf = *(const bf16x8*)(qkv + (size_t)qrow * 768 + hh * 32 + lk8);
    f32x4 O0 = {}, O1 = {};
    float mreg[4] = { -1e30f, -1e30f, -1e30f, -1e30f };
    float lreg[4] = {};
    const float scale = 0.17677669529663687f;
    for (int kv0 = 0; kv0 < 512; kv0 += 64) {
        __syncthreads();
        {
            int kvr = t >> 2, dd = (t & 3) * 8;
            size_t base = (size_t)(b * 512 + kv0 + kvr) * 768 + hh * 32;
            *(bf16x8*)&Ks[kvr][dd] = *(const bf16x8*)(qkv + base + 256 + dd);
            bf16x8 v8 = *(const bf16x8*)(qkv + base + 512 + dd);
            #pragma unroll
            for (int j = 0; j < 8; j++) Vt[dd + j][kvr] = (unsigned short)v8[j];
        }
        __syncthreads();
        f32x4 st[4];
        #pragma unroll
        for (int tt = 0; tt < 4; tt++) {
            bf16x8 kf = *(const bf16x8*)&Ks[tt * 16 + lr][lk8];
            st[tt] = __builtin_amdgcn_mfma_f32_16x16x32_bf16(qf, kf, (f32x4){}, 0, 0, 0);
        }
        float mnew[4], csc[4], psum[4];
        #pragma unroll
        for (int r = 0; r < 4; r++) {
            st[0][r] *= scale; st[1][r] *= scale; st[2][r] *= scale; st[3][r] *= scale;
            float mx = fmaxf(fmaxf(st[0][r], st[1][r]), fmaxf(st[2][r], st[3][r]));
            mx = fmaxf(mx, __shfl_xor(mx, 1));
            mx = fmaxf(mx, __shfl_xor(mx, 2));
            mx = fmaxf(mx, __shfl_xor(mx, 4));
            mx = fmaxf(mx, __shfl_xor(mx, 8));
            mnew[r] = fmaxf(mreg[r], mx);
            csc[r] = __expf(mreg[r] - mnew[r]);
            mreg[r] = mnew[r];
            psum[r] = 0.f;
        }
        #pragma unroll
        for (int tt = 0; tt < 4; tt++)
            #pragma unroll
            for (int r = 0; r < 4; r++) {
                float p = __expf(st[tt][r] - mnew[r]);
                st[tt][r] = p;
                psum[r] += p;
            }
        #pragma unroll
        for (int r = 0; r < 4; r++) {
            psum[r] += __shfl_xor(psum[r], 1);
            psum[r] += __shfl_xor(psum[r], 2);
            psum[r] += __shfl_xor(psum[r], 4);
            psum[r] += __shfl_xor(psum[r], 8);
            lreg[r] = lreg[r] * csc[r] + psum[r];
            O0[r] *= csc[r]; O1[r] *= csc[r];
        }
        #pragma unroll
        for (int tt = 0; tt < 4; tt++)
            #pragma unroll
            for (int r = 0; r < 4; r++)
                Pt[wid][(lane >> 4) * 4 + r][tt * 16 + lr] = f2b(st[tt][r]);
        #pragma unroll
        for (int half = 0; half < 2; half++) {
            bf16x8 pa  = *(const bf16x8*)&Pt[wid][lr][half * 32 + lk8];
            bf16x8 vlo = *(const bf16x8*)&Vt[lr][half * 32 + lk8];
            bf16x8 vhi = *(const bf16x8*)&Vt[16 + lr][half * 32 + lk8];
            O0 = __builtin_amdgcn_mfma_f32_16x16x32_bf16(pa, vlo, O0, 0, 0, 0);
            O1 = __builtin_amdgcn_mfma_f32_16x16x32_bf16(pa, vhi, O1, 0, 0, 0);
        }
    }
    #pragma unroll
    for (int r = 0; r < 4; r++) {
        float inv = 1.f / lreg[r];
        size_t orow = (size_t)(b * 512 + qt * 64 + wid * 16 + (lane >> 4) * 4 + r) * 256 + hh * 32;
        og[orow + lr] = f2b(O0[r] * inv);
        og[orow + 16 + lr] = f2b(O1[r] * inv);
    }
}

extern "C" void kernel_launch(void* const* d_in, const int* in_sizes, int n_in,
                              void* d_out, int out_size, void* d_ws, size_t ws_size,
                              hipStream_t stream)
{
    const float* img  = (const float*)d_in[0];
    const float* bfac = (const float*)d_in[1];
    const float* w0  = (const float*)d_in[2];  const float* b0c = (const float*)d_in[3];
    const float* g1  = (const float*)d_in[4];  const float* be1 = (const float*)d_in[5];
    const float* w1  = (const float*)d_in[6];  const float* b1c = (const float*)d_in[7];
    const float* g2  = (const float*)d_in[8];  const float* be2 = (const float*)d_in[9];
    const float* w2  = (const float*)d_in[10]; const float* b2c = (const float*)d_in[11];
    const float* g3  = (const float*)d_in[12]; const float* be3 = (const float*)d_in[13];
    const float* wu  = (const float*)d_in[14]; const float* bu  = (const float*)d_in[15];
    const float* pos = (const float*)d_in[16];
    const float* lndg = (const float*)d_in[17]; const float* lndb = (const float*)d_in[18];
    const float* lnpg = (const float*)d_in[19]; const float* lnpb = (const float*)d_in[20];
    const float* Wq = (const float*)d_in[21]; const float* bq = (const float*)d_in[22];
    const float* Wk = (const float*)d_in[23]; const float* bk = (const float*)d_in[24];
    const float* Wv = (const float*)d_in[25]; const float* bv = (const float*)d_in[26];
    const float* Wo = (const float*)d_in[27]; const float* bo = (const float*)d_in[28];
    const float* l1g = (const float*)d_in[29]; const float* l1b = (const float*)d_in[30];
    const float* l2g = (const float*)d_in[31]; const float* l2b = (const float*)d_in[32];
    const float* W1 = (const float*)d_in[33]; const float* bf1 = (const float*)d_in[34];
    const float* W2 = (const float*)d_in[35]; const float* bf2 = (const float*)d_in[36];

    float* ws = (float*)d_ws;
    unsigned short* d0b   = (unsigned short*)(ws);              // [8192][2048] bf16
    float*          d1raw = ws + 8388608;                       // [8192][512] f32
    unsigned short* d1b   = (unsigned short*)(ws + 12582912);   // [8192][512] bf16
    float*          xb    = ws + 14680064;                      // [8192][256] f32
    unsigned short* w1T   = (unsigned short*)(ws + 16777216);
    unsigned short* w2T   = (unsigned short*)(ws + 17301504);
    unsigned short* wuTb  = (unsigned short*)(ws + 17334272);
    unsigned short* WqkvT = (unsigned short*)(ws + 17350656);   // 8x768x256
    unsigned short* WoT   = (unsigned short*)(ws + 18137088);
    unsigned short* W1T   = (unsigned short*)(ws + 18399232);
    unsigned short* W2T   = (unsigned short*)(ws + 19447808);
    float*          b1x   = ws + 20496384;
    float*          bqkv  = ws + 20496896;
    // Phase C overlay:
    float*          d2raw = ws;
    unsigned short* d2b   = (unsigned short*)(ws + 1048576);
    float*          ub    = ws + 1572864;
    // Phase D overlay:
    unsigned short* hb    = (unsigned short*)(ws);              // [8192][256] bf16
    unsigned short* qkvb  = (unsigned short*)(ws + 1048576);    // [8192][768] bf16
    unsigned short* obb   = (unsigned short*)(ws + 4194304);    // [8192][256] bf16
    unsigned short* m1b   = (unsigned short*)(ws + 5242880);    // [8192][1024] bf16
    float* xout = (float*)d_out;

    k_prep_w1T<<<4096, 256, 0, stream>>>(w1, w1T);
    k_prep_w2T<<<256, 256, 0, stream>>>(w2, w2T);
    k_prep_wuT<<<128, 256, 0, stream>>>(wu, wuTb);
    k_prep_b1<<<2, 256, 0, stream>>>(b1c, b1x);
    k_prep_qkv<<<dim3(768, 8), 256, 0, stream>>>(Wq, Wk, Wv, bq, bk, bv, WqkvT, bqkv);
    k_prep_T<<<dim3(256, 8), 256, 0, stream>>>(Wo, WoT, 256, 8);
    k_prep_T<<<dim3(1024, 8), 256, 0, stream>>>(W1, W1T, 1024, 8);
    k_prep_T<<<dim3(1024, 8), 256, 0, stream>>>(W2, W2T, 256, 10);

    // Encoder
    k_blur_conv0<<<8192, 256, 0, stream>>>(img, bfac, w0, b0c, g1, be1, d0b);
    k_gemm_bf16<128><<<dim3(8, 64), 256, 0, stream>>>(d0b, w1T, b1x, nullptr, d1raw, 8192, 512, 2048, 2, 0);
    k_gn2<<<4096, 256, 0, stream>>>(d1raw, g2, be2, d1b);
    k_gemm_bf16<128><<<dim3(2, 64), 256, 0, stream>>>(d1b, w2T, b2c, nullptr, d2raw, 8192, 128, 512, 2, 0);
    k_gn3<<<2048, 256, 0, stream>>>(d2raw, g3, be3, d2b);
    k_gemm_bf16<128><<<dim3(4, 64), 256, 0, stream>>>(d2b, wuTb, bu, nullptr, ub, 8192, 256, 128, 0, 0);
    k_lnpos<<<2048, 256, 0, stream>>>(ub, pos, lndg, lndb, lnpg, lnpb, l1g, l1b, xb, hb);

    // Transformer: per layer {qkv, attn, Wo+res+LN(l2), W1(gelu), W2+res+LN(next l1)}
    for (int i = 0; i < 8; i++) {
        k_gemm_bf16<128><<<dim3(12, 64), 256, 0, stream>>>(hb, WqkvT + (size_t)i * 196608, bqkv + i * 768, nullptr, qkvb, 8192, 768, 256, 0, 1);
        k_attn3<<<1024, 256, 0, stream>>>(qkvb, obb);
        k_gemm_ln<<<256, 512, 0, stream>>>(obb, WoT + (size_t)i * 65536, bo + i * 256, xb,
                                           l2g + i * 256, l2b + i * 256, xb, hb, 256);
        k_gemm_bf16<128><<<dim3(16, 64), 256, 0, stream>>>(hb, W1T + (size_t)i * 262144, bf1 + i * 1024, nullptr, m1b, 8192, 1024, 256, 1, 1);
        if (i < 7) {
            k_gemm_ln<<<256, 512, 0, stream>>>(m1b, W2T + (size_t)i * 262144, bf2 + i * 256, xb,
                                               l1g + (i + 1) * 256, l1b + (i + 1) * 256, xb, hb, 1024);
        } else {
            k_gemm_ln<<<256, 512, 0, stream>>>(m1b, W2T + (size_t)i * 262144, bf2 + i * 256, xb,
                                               nullptr, nullptr, xout, nullptr, 1024);
        }
    }
}

// Round 9
// 898.305 us; speedup vs baseline: 6.6367x; 1.1420x over previous
//
#include <hip/hip_runtime.h>
#include <hip/hip_bf16.h>

#define PI2F 9.869604401089358f

typedef __attribute__((ext_vector_type(8))) short bf16x8;
typedef __attribute__((ext_vector_type(4))) float f32x4;

__device__ inline unsigned short f2b(float v) {
    union { float f; unsigned u; } x; x.f = v;
    unsigned r = x.u + 0x7fffu + ((x.u >> 16) & 1u);
    return (unsigned short)(r >> 16);
}

__device__ inline float gelu_tanh(float v) {
    float u = 0.7978845608028654f * (v + 0.044715f * v * v * v);
    float th = 1.f - 2.f / (1.f + __expf(2.f * u));
    return 0.5f * v * (1.f + th);
}

// =============== Kernel A: unfold + separable circular blur + MFMA conv0 + leaky + GN(G=4) =====
// conv0 as per-patch GEMM: C[64vox][32ch] = A[64vox][64tap] * W0[32ch][64tap]^T, A gathered
// directly into registers from the blurred patch (bf16), zero for out-of-range taps.
__global__ __launch_bounds__(256) void k_blur_conv0(
    const float* __restrict__ img, const float* __restrict__ bfac,
    const float* __restrict__ w0, const float* __restrict__ b0c,
    const float* __restrict__ g1, const float* __restrict__ be1,
    unsigned short* __restrict__ d0)
{
    __shared__ float pa[512], pb[512], hsm[8];
    __shared__ unsigned short pbb[512];
    __shared__ unsigned short w0b[32][72];
    __shared__ float d0s[64 * 33];
    __shared__ float2 gstat[4];
    const int t = threadIdx.x, blk = blockIdx.x;
    const int b = blk >> 9, rem = blk & 511;
    const int zh = rem >> 6, yh = (rem >> 3) & 7, xh = rem & 7;

    #pragma unroll
    for (int i = 0; i < 2; i++) {
        int v = t + 256 * i;
        int z = v >> 6, y = (v >> 3) & 7, x = v & 7;
        pa[v] = img[(((size_t)(b * 8 + zh) * 8 + z) * 64 + yh * 8 + y) * 64 + xh * 8 + x];
    }
    #pragma unroll
    for (int i = 0; i < 8; i++) {
        int idx = i * 256 + t;
        w0b[idx >> 6][idx & 63] = f2b(w0[idx]);
    }
    if (t < 8) {
        float bf = bfac[blk];
        float c = bf * PI2F * (1.0f / 16.0f);
        float gk1 = __expf(-c), gk2 = __expf(-4.f * c), gk3 = __expf(-9.f * c), gk4 = __expf(-16.f * c);
        float d = (float)t;
        float h = 1.f + 2.f * (gk1 * cosf(0.7853981633974483f * d)
                             + gk2 * cosf(1.5707963267948966f * d)
                             + gk3 * cosf(2.356194490192345f * d))
                      + gk4 * cosf(3.141592653589793f * d);
        hsm[t] = 0.125f * h;
    }
    __syncthreads();
    #pragma unroll
    for (int i = 0; i < 2; i++) {
        int v = t + 256 * i; int x = v & 7; int base = v & ~7;
        float s = 0.f;
        #pragma unroll
        for (int m = 0; m < 8; m++) s += hsm[(x - m) & 7] * pa[base + m];
        pb[v] = s;
    }
    __syncthreads();
    #pragma unroll
    for (int i = 0; i < 2; i++) {
        int v = t + 256 * i; int y = (v >> 3) & 7; int base = (v & ~63) | (v & 7);
        float s = 0.f;
        #pragma unroll
        for (int m = 0; m < 8; m++) s += hsm[(y - m) & 7] * pb[base + m * 8];
        pa[v] = s;
    }
    __syncthreads();
    #pragma unroll
    for (int i = 0; i < 2; i++) {
        int v = t + 256 * i; int z = v >> 6; int base = v & 63;
        float s = 0.f;
        #pragma unroll
        for (int m = 0; m < 8; m++) s += hsm[(z - m) & 7] * pa[base + m * 64];
        pb[v] = s;
        pbb[v] = f2b(s);
    }
    __syncthreads();
    // conv0 via MFMA: wave wid supplies A rows (vox) [16*wid, 16*wid+16)
    const int wid = t >> 6, lane = t & 63;
    const int lr = lane & 15, lk8 = (lane >> 4) * 8;
    {
        const int vox = wid * 16 + lr;
        const int szb = 2 * (vox >> 4) - 1, syb = 2 * ((vox >> 2) & 3) - 1, sxb = 2 * (vox & 3) - 1;
        f32x4 acc0 = {}, acc1 = {};
        #pragma unroll
        for (int ks = 0; ks < 2; ks++) {
            bf16x8 a;
            #pragma unroll
            for (int j = 0; j < 8; j++) {
                int tap = ks * 32 + lk8 + j;
                int sz = szb + (tap >> 4), sy = syb + ((tap >> 2) & 3), sx = sxb + (tap & 3);
                bool ok = (unsigned)sz < 8u && (unsigned)sy < 8u && (unsigned)sx < 8u;
                a[j] = ok ? (short)pbb[sz * 64 + sy * 8 + sx] : (short)0;
            }
            bf16x8 b0 = *(const bf16x8*)&w0b[lr][ks * 32 + lk8];
            bf16x8 b1 = *(const bf16x8*)&w0b[16 + lr][ks * 32 + lk8];
            acc0 = __builtin_amdgcn_mfma_f32_16x16x32_bf16(a, b0, acc0, 0, 0, 0);
            acc1 = __builtin_amdgcn_mfma_f32_16x16x32_bf16(a, b1, acc1, 0, 0, 0);
        }
        const float bA = b0c[lr], bB = b0c[16 + lr];
        #pragma unroll
        for (int r = 0; r < 4; r++) {
            int crow = wid * 16 + (lane >> 4) * 4 + r;
            float v0 = acc0[r] + bA; v0 = v0 >= 0.f ? v0 : 0.2f * v0;
            float v1 = acc1[r] + bB; v1 = v1 >= 0.f ? v1 : 0.2f * v1;
            d0s[crow * 33 + lr] = v0;
            d0s[crow * 33 + 16 + lr] = v1;
        }
    }
    __syncthreads();
    {
        int g = wid;
        float s = 0.f, sq = 0.f;
        #pragma unroll
        for (int cc = 0; cc < 8; cc++) { float v = d0s[lane * 33 + g * 8 + cc]; s += v; sq += v * v; }
        #pragma unroll
        for (int m = 1; m < 64; m <<= 1) { s += __shfl_xor(s, m, 64); sq += __shfl_xor(sq, m, 64); }
        if (lane == 0) {
            float mean = s * (1.f / 512.f);
            float var = sq * (1.f / 512.f) - mean * mean;
            gstat[g] = make_float2(mean, rsqrtf(var + 1e-5f));
        }
    }
    __syncthreads();
    size_t obase = (size_t)blk * 2048;
    #pragma unroll
    for (int i = 0; i < 8; i++) {
        int oi = t + 256 * i;
        int c = oi >> 6, vox = oi & 63;
        float2 st = gstat[oi >> 9];
        d0[obase + oi] = f2b((d0s[vox * 33 + c] - st.x) * st.y * g1[c] + be1[c]);
    }
}

// =============== ONE merged weight-prep kernel (blockIdx-range dispatch) ===============
__global__ __launch_bounds__(256) void k_prep_all(
    const float* __restrict__ w1, const float* __restrict__ w2, const float* __restrict__ wu,
    const float* __restrict__ b1c,
    const float* __restrict__ Wq, const float* __restrict__ Wk, const float* __restrict__ Wv,
    const float* __restrict__ bq, const float* __restrict__ bk, const float* __restrict__ bv,
    const float* __restrict__ Wo, const float* __restrict__ W1, const float* __restrict__ W2,
    unsigned short* __restrict__ w1T, unsigned short* __restrict__ w2T,
    unsigned short* __restrict__ wuT, float* __restrict__ b1x,
    unsigned short* __restrict__ WqkvT, float* __restrict__ bqkv,
    unsigned short* __restrict__ WoT, unsigned short* __restrict__ W1T, unsigned short* __restrict__ W2T)
{
    const int blk = blockIdx.x, t = threadIdx.x;
    if (blk < 4096) {                       // w1T [512][2048] with zero-padded taps
        int idx = blk * 256 + t;
        int n = idx >> 11, k = idx & 2047;
        int oc = n >> 3, vox = n & 7;
        int oz = vox >> 2, oy = (vox >> 1) & 1, ox = vox & 1;
        int ci = k >> 6, sp = k & 63;
        int sz = sp >> 4, sy = (sp >> 2) & 3, sx = sp & 3;
        int kz = sz + 1 - 2 * oz, ky = sy + 1 - 2 * oy, kx = sx + 1 - 2 * ox;
        float v = 0.f;
        if ((unsigned)kz < 4u && (unsigned)ky < 4u && (unsigned)kx < 4u)
            v = w1[(size_t)oc * 2048 + ci * 64 + kz * 16 + ky * 4 + kx];
        w1T[idx] = f2b(v);
    } else if (blk < 4352) {                // w2T [128][512]
        int idx = (blk - 4096) * 256 + t;
        int n = idx >> 9, k = idx & 511;
        int ci = k >> 3, v = k & 7;
        int z = v >> 2, y = (v >> 1) & 1, x = v & 1;
        w2T[idx] = f2b(w2[(size_t)n * 4096 + ci * 64 + (z + 1) * 16 + (y + 1) * 4 + (x + 1)]);
    } else if (blk < 4480) {                // wuT (already [N][K])
        int idx = (blk - 4352) * 256 + t;
        wuT[idx] = f2b(wu[idx]);
    } else if (blk < 4482) {                // b1x
        int idx = (blk - 4480) * 256 + t;
        b1x[idx] = b1c[idx >> 3];
    } else if (blk < 10626) {               // WqkvT [8][768][256] + bqkv
        int task = blk - 4482;
        int l = task / 768, n = task % 768;
        int sel = n >> 8, col = n & 255;
        const float* W = sel == 0 ? Wq : sel == 1 ? Wk : Wv;
        const float* bb = sel == 0 ? bq : sel == 1 ? bk : bv;
        WqkvT[((size_t)l * 768 + n) * 256 + t] = f2b(W[(size_t)l * 65536 + (size_t)t * 256 + col]);
        if (t == 0) bqkv[l * 768 + n] = bb[l * 256 + col];
    } else if (blk < 12674) {               // WoT [8][256][256]
        int gid = (blk - 10626) * 256 + t;
        int l = gid >> 16, w = gid & 65535;
        int n = w >> 8, k = w & 255;
        WoT[gid] = f2b(Wo[(size_t)l * 65536 + (size_t)k * 256 + n]);
    } else if (blk < 20866) {               // W1T [8][1024][256]
        int gid = (blk - 12674) * 256 + t;
        int l = gid >> 18, w = gid & 262143;
        int n = w >> 8, k = w & 255;
        W1T[gid] = f2b(W1[(size_t)l * 262144 + (size_t)k * 1024 + n]);
    } else {                                // W2T [8][256][1024]
        int gid = (blk - 20866) * 256 + t;
        int l = gid >> 18, w = gid & 262143;
        int n = w >> 10, k = w & 1023;
        W2T[gid] = f2b(W2[(size_t)l * 262144 + (size_t)k * 256 + n]);
    }
}

// =============== MFMA GEMM: C[M][N] = act(A@WT^T + bias) (+res) ===============
template<int BM>
__global__ __launch_bounds__(256) void k_gemm_bf16(
    const unsigned short* __restrict__ A, const unsigned short* __restrict__ WT,
    const float* __restrict__ bias, const float* __restrict__ res,
    void* __restrict__ Cout, int M, int N, int K, int act, int obf)
{
    constexpr int MREP = BM / 32;
    __shared__ unsigned short Ash[BM][72];
    __shared__ unsigned short Bsh[64][72];
    const int t = threadIdx.x;
    const int c0 = blockIdx.x * 64;
    const int r0 = blockIdx.y * BM;
    const int wid = t >> 6, lane = t & 63;
    const int wr = wid >> 1, wc = wid & 1;
    const int lrow = lane & 15, lk = (lane >> 4) * 8;
    f32x4 acc[MREP][2] = {};
    for (int k0 = 0; k0 < K; k0 += 64) {
        __syncthreads();
        #pragma unroll
        for (int i = 0; i < BM / 32; i++) {
            int f = (i * 256 + t) * 8;
            int r = f >> 6, kk = f & 63;
            *(bf16x8*)&Ash[r][kk] = *(const bf16x8*)(A + (size_t)(r0 + r) * K + k0 + kk);
        }
        #pragma unroll
        for (int i = 0; i < 2; i++) {
            int f = (i * 256 + t) * 8;
            int r = f >> 6, kk = f & 63;
            *(bf16x8*)&Bsh[r][kk] = *(const bf16x8*)(WT + (size_t)(c0 + r) * K + k0 + kk);
        }
        __syncthreads();
        #pragma unroll
        for (int ks = 0; ks < 2; ks++) {
            bf16x8 b0 = *(const bf16x8*)&Bsh[wc * 32 + lrow][ks * 32 + lk];
            bf16x8 b1 = *(const bf16x8*)&Bsh[wc * 32 + 16 + lrow][ks * 32 + lk];
            #pragma unroll
            for (int m = 0; m < MREP; m++) {
                bf16x8 a = *(const bf16x8*)&Ash[wr * (BM / 2) + m * 16 + lrow][ks * 32 + lk];
                acc[m][0] = __builtin_amdgcn_mfma_f32_16x16x32_bf16(a, b0, acc[m][0], 0, 0, 0);
                acc[m][1] = __builtin_amdgcn_mfma_f32_16x16x32_bf16(a, b1, acc[m][1], 0, 0, 0);
            }
        }
    }
    const int rbase = r0 + wr * (BM / 2) + (lane >> 4) * 4;
    #pragma unroll
    for (int n = 0; n < 2; n++) {
        const int col = c0 + wc * 32 + n * 16 + lrow;
        const float bv = bias[col];
        #pragma unroll
        for (int m = 0; m < MREP; m++) {
            #pragma unroll
            for (int r = 0; r < 4; r++) {
                float v = acc[m][n][r] + bv;
                if (act == 1) v = gelu_tanh(v);
                else if (act == 2) v = v >= 0.f ? v : 0.2f * v;
                size_t off = (size_t)(rbase + m * 16 + r) * N + col;
                if (res) v += res[off];
                if (obf) ((unsigned short*)Cout)[off] = f2b(v);
                else ((float*)Cout)[off] = v;
            }
        }
    }
}

// ====== Fused conv2 GEMM + leaky + row-GN(128) -> bf16. M=8192, K=512, N=128. BM=32, 512 thr. ==
__global__ __launch_bounds__(512) void k_gemm_gn(
    const unsigned short* __restrict__ A, const unsigned short* __restrict__ WT,
    const float* __restrict__ bias, const float* __restrict__ g3, const float* __restrict__ be3,
    unsigned short* __restrict__ out)
{
    __shared__ __align__(16) char smem[23040];
    unsigned short (*Ash)[72] = (unsigned short(*)[72])smem;               // 32 x 72
    unsigned short (*Bsh)[72] = (unsigned short(*)[72])(smem + 4608);      // 128 x 72
    float (*vals)[136] = (float(*)[136])smem;                              // 32 x 136
    const int t = threadIdx.x;
    const int r0 = blockIdx.x * 32;
    const int wid = t >> 6, lane = t & 63;
    const int mrow = wid >> 2, colq = wid & 3;
    const int lr = lane & 15, lk8 = (lane >> 4) * 8;
    f32x4 acc[2] = {};
    for (int k0 = 0; k0 < 512; k0 += 64) {
        __syncthreads();
        if (t < 256) {
            int f = t * 8;
            int r = f >> 6, kk = f & 63;
            *(bf16x8*)&Ash[r][kk] = *(const bf16x8*)(A + (size_t)(r0 + r) * 512 + k0 + kk);
        }
        #pragma unroll
        for (int i = 0; i < 2; i++) {
            int f = (i * 512 + t) * 8;
            int r = f >> 6, kk = f & 63;
            *(bf16x8*)&Bsh[r][kk] = *(const bf16x8*)(WT + (size_t)r * 512 + k0 + kk);
        }
        __syncthreads();
        #pragma unroll
        for (int ks = 0; ks < 2; ks++) {
            bf16x8 a = *(const bf16x8*)&Ash[mrow * 16 + lr][ks * 32 + lk8];
            #pragma unroll
            for (int nf = 0; nf < 2; nf++) {
                bf16x8 bb = *(const bf16x8*)&Bsh[colq * 32 + nf * 16 + lr][ks * 32 + lk8];
                acc[nf] = __builtin_amdgcn_mfma_f32_16x16x32_bf16(a, bb, acc[nf], 0, 0, 0);
            }
        }
    }
    __syncthreads();
    #pragma unroll
    for (int nf = 0; nf < 2; nf++) {
        int col = colq * 32 + nf * 16 + lr;
        float bv = bias[col];
        #pragma unroll
        for (int r = 0; r < 4; r++) {
            int row = mrow * 16 + (lane >> 4) * 4 + r;
            float v = acc[nf][r] + bv;
            vals[row][col] = v >= 0.f ? v : 0.2f * v;
        }
    }
    __syncthreads();
    // row-GN over 128: 16 threads/row, 8 cols each
    const int row = t >> 4, cc0 = (t & 15) * 8;
    float s = 0.f, sq = 0.f;
    #pragma unroll
    for (int j = 0; j < 8; j++) {
        float v = vals[row][cc0 + j];
        s += v; sq += v * v;
    }
    s += __shfl_xor(s, 1); sq += __shfl_xor(sq, 1);
    s += __shfl_xor(s, 2); sq += __shfl_xor(sq, 2);
    s += __shfl_xor(s, 4); sq += __shfl_xor(sq, 4);
    s += __shfl_xor(s, 8); sq += __shfl_xor(sq, 8);
    float mean = s * (1.f / 128.f);
    float rs = rsqrtf(sq * (1.f / 128.f) - mean * mean + 1e-5f);
    ushort4 o[2];
    #pragma unroll
    for (int h = 0; h < 2; h++) {
        #pragma unroll
        for (int j = 0; j < 4; j++) {
            int col = cc0 + h * 4 + j;
            float v = (vals[row][col] - mean) * rs * g3[col] + be3[col];
            ((unsigned short*)&o[h])[j] = f2b(v);
        }
    }
    *(ushort4*)(out + (size_t)(r0 + row) * 128 + cc0) = o[0];
    *(ushort4*)(out + (size_t)(r0 + row) * 128 + cc0 + 4) = o[1];
}

// ====== Fused GEMM + residual + row-LN. BM=32, N=256 fixed, 512 threads. ======
__global__ __launch_bounds__(512) void k_gemm_ln(
    const unsigned short* __restrict__ A, const unsigned short* __restrict__ WT,
    const float* __restrict__ bias, const float* __restrict__ res,
    const float* __restrict__ lng, const float* __restrict__ lnb,
    float* __restrict__ xnew, unsigned short* __restrict__ h, int K)
{
    __shared__ __align__(16) char smem[41472];
    unsigned short (*Ash)[72] = (unsigned short(*)[72])smem;
    unsigned short (*Bsh)[72] = (unsigned short(*)[72])(smem + 4608);
    float (*vals)[264] = (float(*)[264])smem;
    const int t = threadIdx.x;
    const int r0 = blockIdx.x * 32;
    const int wid = t >> 6, lane = t & 63;
    const int lrow = lane & 15, lk8 = (lane >> 4) * 8;
    f32x4 acc[2][2] = {};
    for (int k0 = 0; k0 < K; k0 += 64) {
        __syncthreads();
        if (t < 256) {
            int f = t * 8;
            int r = f >> 6, kk = f & 63;
            *(bf16x8*)&Ash[r][kk] = *(const bf16x8*)(A + (size_t)(r0 + r) * K + k0 + kk);
        }
        #pragma unroll
        for (int i = 0; i < 4; i++) {
            int f = (i * 512 + t) * 8;
            int r = f >> 6, kk = f & 63;
            *(bf16x8*)&Bsh[r][kk] = *(const bf16x8*)(WT + (size_t)r * K + k0 + kk);
        }
        __syncthreads();
        #pragma unroll
        for (int ks = 0; ks < 2; ks++) {
            bf16x8 a0 = *(const bf16x8*)&Ash[lrow][ks * 32 + lk8];
            bf16x8 a1 = *(const bf16x8*)&Ash[16 + lrow][ks * 32 + lk8];
            #pragma unroll
            for (int nf = 0; nf < 2; nf++) {
                bf16x8 bfr = *(const bf16x8*)&Bsh[wid * 32 + nf * 16 + lrow][ks * 32 + lk8];
                acc[0][nf] = __builtin_amdgcn_mfma_f32_16x16x32_bf16(a0, bfr, acc[0][nf], 0, 0, 0);
                acc[1][nf] = __builtin_amdgcn_mfma_f32_16x16x32_bf16(a1, bfr, acc[1][nf], 0, 0, 0);
            }
        }
    }
    __syncthreads();
    #pragma unroll
    for (int m = 0; m < 2; m++)
        #pragma unroll
        for (int nf = 0; nf < 2; nf++) {
            int col = wid * 32 + nf * 16 + lrow;
            float bv = bias[col];
            #pragma unroll
            for (int r = 0; r < 4; r++) {
                int row = m * 16 + (lane >> 4) * 4 + r;
                vals[row][col] = acc[m][nf][r] + bv + res[(size_t)(r0 + row) * 256 + col];
            }
        }
    __syncthreads();
    const int row = t >> 4, c4 = (t & 15) * 4;
    float s = 0.f, sq = 0.f;
    #pragma unroll
    for (int j = 0; j < 4; j++) {
        float4 v4 = *(const float4*)&vals[row][c4 + j * 64];
        s += v4.x + v4.y + v4.z + v4.w;
        sq += v4.x * v4.x + v4.y * v4.y + v4.z * v4.z + v4.w * v4.w;
    }
    s += __shfl_xor(s, 1); sq += __shfl_xor(sq, 1);
    s += __shfl_xor(s, 2); sq += __shfl_xor(sq, 2);
    s += __shfl_xor(s, 4); sq += __shfl_xor(sq, 4);
    s += __shfl_xor(s, 8); sq += __shfl_xor(sq, 8);
    float mean = s * (1.f / 256.f);
    float rs = rsqrtf(sq * (1.f / 256.f) - mean * mean + 1e-5f);
    const size_t gbase = (size_t)(r0 + row) * 256;
    #pragma unroll
    for (int j = 0; j < 4; j++) {
        int col = c4 + j * 64;
        float4 v4 = *(const float4*)&vals[row][col];
        *(float4*)(xnew + gbase + col) = v4;
        if (lng) {
            float4 g4 = *(const float4*)(lng + col);
            float4 b4 = *(const float4*)(lnb + col);
            ushort4 o;
            o.x = f2b((v4.x - mean) * rs * g4.x + b4.x);
            o.y = f2b((v4.y - mean) * rs * g4.y + b4.y);
            o.z = f2b((v4.z - mean) * rs * g4.z + b4.z);
            o.w = f2b((v4.w - mean) * rs * g4.w + b4.w);
            *(ushort4*)(h + gbase + col) = o;
        }
    }
}

// =============== GN2 ===============
__global__ __launch_bounds__(256) void k_gn2(
    const float* __restrict__ din, const float* __restrict__ g2, const float* __restrict__ be2,
    unsigned short* __restrict__ dout)
{
    const int t = threadIdx.x;
    const int w = t >> 6, lane = t & 63;
    const int p = blockIdx.x * 2 + (w >> 1), g = w & 1;
    float4 v = ((const float4*)(din + (size_t)p * 512 + g * 256))[lane];
    float s = v.x + v.y + v.z + v.w;
    float sq = v.x * v.x + v.y * v.y + v.z * v.z + v.w * v.w;
    #pragma unroll
    for (int m = 1; m < 64; m <<= 1) { s += __shfl_xor(s, m, 64); sq += __shfl_xor(sq, m, 64); }
    float mean = s * (1.f / 256.f);
    float rs = rsqrtf(sq * (1.f / 256.f) - mean * mean + 1e-5f);
    int oc = g * 32 + (lane >> 1);
    float gg = g2[oc], bb = be2[oc];
    ushort4 o;
    o.x = f2b((v.x - mean) * rs * gg + bb);
    o.y = f2b((v.y - mean) * rs * gg + bb);
    o.z = f2b((v.z - mean) * rs * gg + bb);
    o.w = f2b((v.w - mean) * rs * gg + bb);
    ((ushort4*)(dout + (size_t)p * 512 + g * 256))[lane] = o;
}

// ====== LN(u)+LN(pos) -> xb f32, and hb = LN_{l1[0]}(xb) bf16. Wave per row. ======
__global__ __launch_bounds__(256) void k_lnpos(
    const float* __restrict__ u, const float* __restrict__ pos,
    const float* __restrict__ lndg, const float* __restrict__ lndb,
    const float* __restrict__ lnpg, const float* __restrict__ lnpb,
    const float* __restrict__ l1g0, const float* __restrict__ l1b0,
    float* __restrict__ xb, unsigned short* __restrict__ hb)
{
    const int t = threadIdx.x;
    const int row = blockIdx.x * 4 + (t >> 6);
    const int lane = t & 63;
    float4 v = ((const float4*)(u + (size_t)row * 256))[lane];
    float4 w = ((const float4*)(pos + (size_t)(row & 511) * 256))[lane];
    float s = v.x + v.y + v.z + v.w;
    float sq = v.x * v.x + v.y * v.y + v.z * v.z + v.w * v.w;
    float sp = w.x + w.y + w.z + w.w;
    float qp = w.x * w.x + w.y * w.y + w.z * w.z + w.w * w.w;
    #pragma unroll
    for (int m = 1; m < 64; m <<= 1) {
        s += __shfl_xor(s, m, 64); sq += __shfl_xor(sq, m, 64);
        sp += __shfl_xor(sp, m, 64); qp += __shfl_xor(qp, m, 64);
    }
    float mu = s * (1.f / 256.f), ru = rsqrtf(sq * (1.f / 256.f) - mu * mu + 1e-5f);
    float mp = sp * (1.f / 256.f), rp = rsqrtf(qp * (1.f / 256.f) - mp * mp + 1e-5f);
    float4 ga = ((const float4*)lndg)[lane], ba = ((const float4*)lndb)[lane];
    float4 gp = ((const float4*)lnpg)[lane], bp = ((const float4*)lnpb)[lane];
    float4 o;
    o.x = (v.x - mu) * ru * ga.x + ba.x + (w.x - mp) * rp * gp.x + bp.x;
    o.y = (v.y - mu) * ru * ga.y + ba.y + (w.y - mp) * rp * gp.y + bp.y;
    o.z = (v.z - mu) * ru * ga.z + ba.z + (w.z - mp) * rp * gp.z + bp.z;
    o.w = (v.w - mu) * ru * ga.w + ba.w + (w.w - mp) * rp * gp.w + bp.w;
    ((float4*)(xb + (size_t)row * 256))[lane] = o;
    float s2 = o.x + o.y + o.z + o.w;
    float q2 = o.x * o.x + o.y * o.y + o.z * o.z + o.w * o.w;
    #pragma unroll
    for (int m = 1; m < 64; m <<= 1) { s2 += __shfl_xor(s2, m, 64); q2 += __shfl_xor(q2, m, 64); }
    float mu2 = s2 * (1.f / 256.f), r2 = rsqrtf(q2 * (1.f / 256.f) - mu2 * mu2 + 1e-5f);
    float4 g4 = ((const float4*)l1g0)[lane], b4 = ((const float4*)l1b0)[lane];
    ushort4 ho;
    ho.x = f2b((o.x - mu2) * r2 * g4.x + b4.x);
    ho.y = f2b((o.y - mu2) * r2 * g4.y + b4.y);
    ho.z = f2b((o.z - mu2) * r2 * g4.z + b4.z);
    ho.w = f2b((o.w - mu2) * r2 * g4.w + b4.w);
    ((ushort4*)(hb + (size_t)row * 256))[lane] = ho;
}

// ====== MFMA flash attention: qkv bf16 [8192][768] -> o bf16 [8192][256] ======
__global__ __launch_bounds__(256) void k_attn3(
    const unsigned short* __restrict__ qkv, unsigned short* __restrict__ og)
{
    __shared__ unsigned short Ks[64][36];
    __shared__ unsigned short Vt[32][72];
    __shared__ unsigned short Pt[4][16][72];
    const int t = threadIdx.x;
    const int bid = blockIdx.x;
    const int b = bid >> 6, hh = (bid >> 3) & 7, qt = bid & 7;
    const int wid = t >> 6, lane = t & 63;
    const int lr = lane & 15, lk8 = (lane >> 4) * 8;
    const int qrow = b * 512 + qt * 64 + wid * 16 + lr;
    const bf16x8 qf = *(const bf16x8*)(qkv + (size_t)qrow * 768 + hh * 32 + lk8);
    f32x4 O0 = {}, O1 = {};
    float mreg[4] = { -1e30f, -1e30f, -1e30f, -1e30f };
    float lreg[4] = {};
    const float scale = 0.17677669529663687f;
    for (int kv0 = 0; kv0 < 512; kv0 += 64) {
        __syncthreads();
        {
            int kvr = t >> 2, dd = (t & 3) * 8;
            size_t base = (size_t)(b * 512 + kv0 + kvr) * 768 + hh * 32;
            *(bf16x8*)&Ks[kvr][dd] = *(const bf16x8*)(qkv + base + 256 + dd);
            bf16x8 v8 = *(const bf16x8*)(qkv + base + 512 + dd);
            #pragma unroll
            for (int j = 0; j < 8; j++) Vt[dd + j][kvr] = (unsigned short)v8[j];
        }
        __syncthreads();
        f32x4 st[4];
        #pragma unroll
        for (int tt = 0; tt < 4; tt++) {
            bf16x8 kf = *(const bf16x8*)&Ks[tt * 16 + lr][lk8];
            st[tt] = __builtin_amdgcn_mfma_f32_16x16x32_bf16(qf, kf, (f32x4){}, 0, 0, 0);
        }
        float mnew[4], csc[4], psum[4];
        #pragma unroll
        for (int r = 0; r < 4; r++) {
            st[0][r] *= scale; st[1][r] *= scale; st[2][r] *= scale; st[3][r] *= scale;
            float mx = fmaxf(fmaxf(st[0][r], st[1][r]), fmaxf(st[2][r], st[3][r]));
            mx = fmaxf(mx, __shfl_xor(mx, 1));
            mx = fmaxf(mx, __shfl_xor(mx, 2));
            mx = fmaxf(mx, __shfl_xor(mx, 4));
            mx = fmaxf(mx, __shfl_xor(mx, 8));
            mnew[r] = fmaxf(mreg[r], mx);
            csc[r] = __expf(mreg[r] - mnew[r]);
            mreg[r] = mnew[r];
            psum[r] = 0.f;
        }
        #pragma unroll
        for (int tt = 0; tt < 4; tt++)
            #pragma unroll
            for (int r = 0; r < 4; r++) {
                float p = __expf(st[tt][r] - mnew[r]);
                st[tt][r] = p;
                psum[r] += p;
            }
        #pragma unroll
        for (int r = 0; r < 4; r++) {
            psum[r] += __shfl_xor(psum[r], 1);
            psum[r] += __shfl_xor(psum[r], 2);
            psum[r] += __shfl_xor(psum[r], 4);
            psum[r] += __shfl_xor(psum[r], 8);
            lreg[r] = lreg[r] * csc[r] + psum[r];
            O0[r] *= csc[r]; O1[r] *= csc[r];
        }
        #pragma unroll
        for (int tt = 0; tt < 4; tt++)
            #pragma unroll
            for (int r = 0; r < 4; r++)
                Pt[wid][(lane >> 4) * 4 + r][tt * 16 + lr] = f2b(st[tt][r]);
        #pragma unroll
        for (int half = 0; half < 2; half++) {
            bf16x8 pa  = *(const bf16x8*)&Pt[wid][lr][half * 32 + lk8];
            bf16x8 vlo = *(const bf16x8*)&Vt[lr][half * 32 + lk8];
            bf16x8 vhi = *(const bf16x8*)&Vt[16 + lr][half * 32 + lk8];
            O0 = __builtin_amdgcn_mfma_f32_16x16x32_bf16(pa, vlo, O0, 0, 0, 0);
            O1 = __builtin_amdgcn_mfma_f32_16x16x32_bf16(pa, vhi, O1, 0, 0, 0);
        }
    }
    #pragma unroll
    for (int r = 0; r < 4; r++) {
        float inv = 1.f / lreg[r];
        size_t orow = (size_t)(b * 512 + qt * 64 + wid * 16 + (lane >> 4) * 4 + r) * 256 + hh * 32;
        og[orow + lr] = f2b(O0[r] * inv);
        og[orow + 16 + lr] = f2b(O1[r] * inv);
    }
}

extern "C" void kernel_launch(void* const* d_in, const int* in_sizes, int n_in,
                              void* d_out, int out_size, void* d_ws, size_t ws_size,
                              hipStream_t stream)
{
    const float* img  = (const float*)d_in[0];
    const float* bfac = (const float*)d_in[1];
    const float* w0  = (const float*)d_in[2];  const float* b0c = (const float*)d_in[3];
    const float* g1  = (const float*)d_in[4];  const float* be1 = (const float*)d_in[5];
    const float* w1  = (const float*)d_in[6];  const float* b1c = (const float*)d_in[7];
    const float* g2  = (const float*)d_in[8];  const float* be2 = (const float*)d_in[9];
    const float* w2  = (const float*)d_in[10]; const float* b2c = (const float*)d_in[11];
    const float* g3  = (const float*)d_in[12]; const float* be3 = (const float*)d_in[13];
    const float* wu  = (const float*)d_in[14]; const float* bu  = (const float*)d_in[15];
    const float* pos = (const float*)d_in[16];
    const float* lndg = (const float*)d_in[17]; const float* lndb = (const float*)d_in[18];
    const float* lnpg = (const float*)d_in[19]; const float* lnpb = (const float*)d_in[20];
    const float* Wq = (const float*)d_in[21]; const float* bq = (const float*)d_in[22];
    const float* Wk = (const float*)d_in[23]; const float* bk = (const float*)d_in[24];
    const float* Wv = (const float*)d_in[25]; const float* bv = (const float*)d_in[26];
    const float* Wo = (const float*)d_in[27]; const float* bo = (const float*)d_in[28];
    const float* l1g = (const float*)d_in[29]; const float* l1b = (const float*)d_in[30];
    const float* l2g = (const float*)d_in[31]; const float* l2b = (const float*)d_in[32];
    const float* W1 = (const float*)d_in[33]; const float* bf1 = (const float*)d_in[34];
    const float* W2 = (const float*)d_in[35]; const float* bf2 = (const float*)d_in[36];

    float* ws = (float*)d_ws;
    unsigned short* d0b   = (unsigned short*)(ws);              // [8192][2048] bf16
    float*          d1raw = ws + 8388608;                       // [8192][512] f32
    unsigned short* d1b   = (unsigned short*)(ws + 12582912);   // [8192][512] bf16
    float*          xb    = ws + 14680064;                      // [8192][256] f32
    unsigned short* w1T   = (unsigned short*)(ws + 16777216);
    unsigned short* w2T   = (unsigned short*)(ws + 17301504);
    unsigned short* wuTb  = (unsigned short*)(ws + 17334272);
    unsigned short* WqkvT = (unsigned short*)(ws + 17350656);   // 8x768x256
    unsigned short* WoT   = (unsigned short*)(ws + 18137088);
    unsigned short* W1T   = (unsigned short*)(ws + 18399232);
    unsigned short* W2T   = (unsigned short*)(ws + 19447808);
    float*          b1x   = ws + 20496384;
    float*          bqkv  = ws + 20496896;
    // Phase C overlay (d0b dead after conv1 GEMM):
    unsigned short* d2b   = (unsigned short*)(ws + 1048576);    // [8192][128] bf16
    float*          ub    = ws + 1572864;                       // [8192][256] f32
    // Phase D overlay:
    unsigned short* hb    = (unsigned short*)(ws);              // [8192][256] bf16
    unsigned short* qkvb  = (unsigned short*)(ws + 1048576);    // [8192][768] bf16
    unsigned short* obb   = (unsigned short*)(ws + 4194304);    // [8192][256] bf16
    unsigned short* m1b   = (unsigned short*)(ws + 5242880);    // [8192][1024] bf16
    float* xout = (float*)d_out;

    // Weight prep: ONE launch
    k_prep_all<<<29058, 256, 0, stream>>>(w1, w2, wu, b1c, Wq, Wk, Wv, bq, bk, bv, Wo, W1, W2,
                                          w1T, w2T, wuTb, b1x, WqkvT, bqkv, WoT, W1T, W2T);

    // Encoder
    k_blur_conv0<<<8192, 256, 0, stream>>>(img, bfac, w0, b0c, g1, be1, d0b);
    k_gemm_bf16<128><<<dim3(8, 64), 256, 0, stream>>>(d0b, w1T, b1x, nullptr, d1raw, 8192, 512, 2048, 2, 0);
    k_gn2<<<4096, 256, 0, stream>>>(d1raw, g2, be2, d1b);
    k_gemm_gn<<<256, 512, 0, stream>>>(d1b, w2T, b2c, g3, be3, d2b);
    k_gemm_bf16<128><<<dim3(4, 64), 256, 0, stream>>>(d2b, wuTb, bu, nullptr, ub, 8192, 256, 128, 0, 0);
    k_lnpos<<<2048, 256, 0, stream>>>(ub, pos, lndg, lndb, lnpg, lnpb, l1g, l1b, xb, hb);

    // Transformer: per layer {qkv, attn, Wo+res+LN(l2), W1(gelu), W2+res+LN(next l1)}
    for (int i = 0; i < 8; i++) {
        k_gemm_bf16<128><<<dim3(12, 64), 256, 0, stream>>>(hb, WqkvT + (size_t)i * 196608, bqkv + i * 768, nullptr, qkvb, 8192, 768, 256, 0, 1);
        k_attn3<<<1024, 256, 0, stream>>>(qkvb, obb);
        k_gemm_ln<<<256, 512, 0, stream>>>(obb, WoT + (size_t)i * 65536, bo + i * 256, xb,
                                           l2g + i * 256, l2b + i * 256, xb, hb, 256);
        k_gemm_bf16<128><<<dim3(16, 64), 256, 0, stream>>>(hb, W1T + (size_t)i * 262144, bf1 + i * 1024, nullptr, m1b, 8192, 1024, 256, 1, 1);
        if (i < 7) {
            k_gemm_ln<<<256, 512, 0, stream>>>(m1b, W2T + (size_t)i * 262144, bf2 + i * 256, xb,
                                               l1g + (i + 1) * 256, l1b + (i + 1) * 256, xb, hb, 1024);
        } else {
            k_gemm_ln<<<256, 512, 0, stream>>>(m1b, W2T + (size_t)i * 262144, bf2 + i * 256, xb,
                                               nullptr, nullptr, xout, nullptr, 1024);
        }
    }
}

// Round 10
// 873.564 us; speedup vs baseline: 6.8246x; 1.0283x over previous
//
#include <hip/hip_runtime.h>
#include <hip/hip_bf16.h>

#define PI2F 9.869604401089358f

typedef __attribute__((ext_vector_type(8))) short bf16x8;
typedef __attribute__((ext_vector_type(4))) float f32x4;

__device__ inline unsigned short f2b(float v) {
    union { float f; unsigned u; } x; x.f = v;
    unsigned r = x.u + 0x7fffu + ((x.u >> 16) & 1u);
    return (unsigned short)(r >> 16);
}

__device__ inline float gelu_tanh(float v) {
    float u = 0.7978845608028654f * (v + 0.044715f * v * v * v);
    float th = 1.f - 2.f / (1.f + __expf(2.f * u));
    return 0.5f * v * (1.f + th);
}

// =============== Kernel A: unfold + separable circular blur + MFMA conv0 + leaky + GN(G=4) =====
__global__ __launch_bounds__(256) void k_blur_conv0(
    const float* __restrict__ img, const float* __restrict__ bfac,
    const float* __restrict__ w0, const float* __restrict__ b0c,
    const float* __restrict__ g1, const float* __restrict__ be1,
    unsigned short* __restrict__ d0)
{
    __shared__ float pa[512], pb[512], hsm[8];
    __shared__ unsigned short pbb[512];
    __shared__ unsigned short w0b[32][72];
    __shared__ float d0s[64 * 33];
    __shared__ float2 gstat[4];
    const int t = threadIdx.x, blk = blockIdx.x;
    const int b = blk >> 9, rem = blk & 511;
    const int zh = rem >> 6, yh = (rem >> 3) & 7, xh = rem & 7;

    #pragma unroll
    for (int i = 0; i < 2; i++) {
        int v = t + 256 * i;
        int z = v >> 6, y = (v >> 3) & 7, x = v & 7;
        pa[v] = img[(((size_t)(b * 8 + zh) * 8 + z) * 64 + yh * 8 + y) * 64 + xh * 8 + x];
    }
    #pragma unroll
    for (int i = 0; i < 8; i++) {
        int idx = i * 256 + t;
        w0b[idx >> 6][idx & 63] = f2b(w0[idx]);
    }
    if (t < 8) {
        float bf = bfac[blk];
        float c = bf * PI2F * (1.0f / 16.0f);
        float gk1 = __expf(-c), gk2 = __expf(-4.f * c), gk3 = __expf(-9.f * c), gk4 = __expf(-16.f * c);
        float d = (float)t;
        float h = 1.f + 2.f * (gk1 * cosf(0.7853981633974483f * d)
                             + gk2 * cosf(1.5707963267948966f * d)
                             + gk3 * cosf(2.356194490192345f * d))
                      + gk4 * cosf(3.141592653589793f * d);
        hsm[t] = 0.125f * h;
    }
    __syncthreads();
    #pragma unroll
    for (int i = 0; i < 2; i++) {
        int v = t + 256 * i; int x = v & 7; int base = v & ~7;
        float s = 0.f;
        #pragma unroll
        for (int m = 0; m < 8; m++) s += hsm[(x - m) & 7] * pa[base + m];
        pb[v] = s;
    }
    __syncthreads();
    #pragma unroll
    for (int i = 0; i < 2; i++) {
        int v = t + 256 * i; int y = (v >> 3) & 7; int base = (v & ~63) | (v & 7);
        float s = 0.f;
        #pragma unroll
        for (int m = 0; m < 8; m++) s += hsm[(y - m) & 7] * pb[base + m * 8];
        pa[v] = s;
    }
    __syncthreads();
    #pragma unroll
    for (int i = 0; i < 2; i++) {
        int v = t + 256 * i; int z = v >> 6; int base = v & 63;
        float s = 0.f;
        #pragma unroll
        for (int m = 0; m < 8; m++) s += hsm[(z - m) & 7] * pa[base + m * 64];
        pb[v] = s;
        pbb[v] = f2b(s);
    }
    __syncthreads();
    const int wid = t >> 6, lane = t & 63;
    const int lr = lane & 15, lk8 = (lane >> 4) * 8;
    {
        const int vox = wid * 16 + lr;
        const int szb = 2 * (vox >> 4) - 1, syb = 2 * ((vox >> 2) & 3) - 1, sxb = 2 * (vox & 3) - 1;
        f32x4 acc0 = {}, acc1 = {};
        #pragma unroll
        for (int ks = 0; ks < 2; ks++) {
            bf16x8 a;
            #pragma unroll
            for (int j = 0; j < 8; j++) {
                int tap = ks * 32 + lk8 + j;
                int sz = szb + (tap >> 4), sy = syb + ((tap >> 2) & 3), sx = sxb + (tap & 3);
                bool ok = (unsigned)sz < 8u && (unsigned)sy < 8u && (unsigned)sx < 8u;
                a[j] = ok ? (short)pbb[sz * 64 + sy * 8 + sx] : (short)0;
            }
            bf16x8 b0 = *(const bf16x8*)&w0b[lr][ks * 32 + lk8];
            bf16x8 b1 = *(const bf16x8*)&w0b[16 + lr][ks * 32 + lk8];
            acc0 = __builtin_amdgcn_mfma_f32_16x16x32_bf16(a, b0, acc0, 0, 0, 0);
            acc1 = __builtin_amdgcn_mfma_f32_16x16x32_bf16(a, b1, acc1, 0, 0, 0);
        }
        const float bA = b0c[lr], bB = b0c[16 + lr];
        #pragma unroll
        for (int r = 0; r < 4; r++) {
            int crow = wid * 16 + (lane >> 4) * 4 + r;
            float v0 = acc0[r] + bA; v0 = v0 >= 0.f ? v0 : 0.2f * v0;
            float v1 = acc1[r] + bB; v1 = v1 >= 0.f ? v1 : 0.2f * v1;
            d0s[crow * 33 + lr] = v0;
            d0s[crow * 33 + 16 + lr] = v1;
        }
    }
    __syncthreads();
    {
        int g = wid;
        float s = 0.f, sq = 0.f;
        #pragma unroll
        for (int cc = 0; cc < 8; cc++) { float v = d0s[lane * 33 + g * 8 + cc]; s += v; sq += v * v; }
        #pragma unroll
        for (int m = 1; m < 64; m <<= 1) { s += __shfl_xor(s, m, 64); sq += __shfl_xor(sq, m, 64); }
        if (lane == 0) {
            float mean = s * (1.f / 512.f);
            float var = sq * (1.f / 512.f) - mean * mean;
            gstat[g] = make_float2(mean, rsqrtf(var + 1e-5f));
        }
    }
    __syncthreads();
    size_t obase = (size_t)blk * 2048;
    #pragma unroll
    for (int i = 0; i < 8; i++) {
        int oi = t + 256 * i;
        int c = oi >> 6, vox = oi & 63;
        float2 st = gstat[oi >> 9];
        d0[obase + oi] = f2b((d0s[vox * 33 + c] - st.x) * st.y * g1[c] + be1[c]);
    }
}

// =============== ONE merged weight-prep kernel ===============
__global__ __launch_bounds__(256) void k_prep_all(
    const float* __restrict__ w1, const float* __restrict__ w2, const float* __restrict__ wu,
    const float* __restrict__ b1c,
    const float* __restrict__ Wq, const float* __restrict__ Wk, const float* __restrict__ Wv,
    const float* __restrict__ bq, const float* __restrict__ bk, const float* __restrict__ bv,
    const float* __restrict__ Wo, const float* __restrict__ W1, const float* __restrict__ W2,
    unsigned short* __restrict__ w1T, unsigned short* __restrict__ w2T,
    unsigned short* __restrict__ wuT, float* __restrict__ b1x,
    unsigned short* __restrict__ WqkvT, float* __restrict__ bqkv,
    unsigned short* __restrict__ WoT, unsigned short* __restrict__ W1T, unsigned short* __restrict__ W2T)
{
    const int blk = blockIdx.x, t = threadIdx.x;
    if (blk < 4096) {
        int idx = blk * 256 + t;
        int n = idx >> 11, k = idx & 2047;
        int oc = n >> 3, vox = n & 7;
        int oz = vox >> 2, oy = (vox >> 1) & 1, ox = vox & 1;
        int ci = k >> 6, sp = k & 63;
        int sz = sp >> 4, sy = (sp >> 2) & 3, sx = sp & 3;
        int kz = sz + 1 - 2 * oz, ky = sy + 1 - 2 * oy, kx = sx + 1 - 2 * ox;
        float v = 0.f;
        if ((unsigned)kz < 4u && (unsigned)ky < 4u && (unsigned)kx < 4u)
            v = w1[(size_t)oc * 2048 + ci * 64 + kz * 16 + ky * 4 + kx];
        w1T[idx] = f2b(v);
    } else if (blk < 4352) {
        int idx = (blk - 4096) * 256 + t;
        int n = idx >> 9, k = idx & 511;
        int ci = k >> 3, v = k & 7;
        int z = v >> 2, y = (v >> 1) & 1, x = v & 1;
        w2T[idx] = f2b(w2[(size_t)n * 4096 + ci * 64 + (z + 1) * 16 + (y + 1) * 4 + (x + 1)]);
    } else if (blk < 4480) {
        int idx = (blk - 4352) * 256 + t;
        wuT[idx] = f2b(wu[idx]);
    } else if (blk < 4482) {
        int idx = (blk - 4480) * 256 + t;
        b1x[idx] = b1c[idx >> 3];
    } else if (blk < 10626) {
        int task = blk - 4482;
        int l = task / 768, n = task % 768;
        int sel = n >> 8, col = n & 255;
        const float* W = sel == 0 ? Wq : sel == 1 ? Wk : Wv;
        const float* bb = sel == 0 ? bq : sel == 1 ? bk : bv;
        WqkvT[((size_t)l * 768 + n) * 256 + t] = f2b(W[(size_t)l * 65536 + (size_t)t * 256 + col]);
        if (t == 0) bqkv[l * 768 + n] = bb[l * 256 + col];
    } else if (blk < 12674) {
        int gid = (blk - 10626) * 256 + t;
        int l = gid >> 16, w = gid & 65535;
        int n = w >> 8, k = w & 255;
        WoT[gid] = f2b(Wo[(size_t)l * 65536 + (size_t)k * 256 + n]);
    } else if (blk < 20866) {
        int gid = (blk - 12674) * 256 + t;
        int l = gid >> 18, w = gid & 262143;
        int n = w >> 8, k = w & 255;
        W1T[gid] = f2b(W1[(size_t)l * 262144 + (size_t)k * 1024 + n]);
    } else {
        int gid = (blk - 20866) * 256 + t;
        int l = gid >> 18, w = gid & 262143;
        int n = w >> 10, k = w & 1023;
        W2T[gid] = f2b(W2[(size_t)l * 262144 + (size_t)k * 256 + n]);
    }
}

// ====== MFMA GEMM with XCD-chunk swizzle. 1-D grid = NXB*64 blocks; M = 64*BM rows. ======
// lb -> xcd=lb&7, j=lb>>3; tile (gy = xcd*8 + j/NXB, gx = j%NXB): each XCD owns 8 contiguous
// row-panels x all column-blocks -> A-panel re-reads hit the XCD-private L2.
template<int BM>
__global__ __launch_bounds__(256) void k_gemm_bf16(
    const unsigned short* __restrict__ A, const unsigned short* __restrict__ WT,
    const float* __restrict__ bias, const float* __restrict__ res,
    void* __restrict__ Cout, int NXB, int N, int K, int act, int obf)
{
    constexpr int MREP = BM / 32;
    __shared__ unsigned short Ash[BM][72];
    __shared__ unsigned short Bsh[64][72];
    const int t = threadIdx.x;
    const int lb = blockIdx.x;
    const int xcd = lb & 7, j = lb >> 3;
    const int gy = xcd * 8 + j / NXB, gx = j % NXB;
    const int c0 = gx * 64;
    const int r0 = gy * BM;
    const int wid = t >> 6, lane = t & 63;
    const int wr = wid >> 1, wc = wid & 1;
    const int lrow = lane & 15, lk = (lane >> 4) * 8;
    f32x4 acc[MREP][2] = {};
    for (int k0 = 0; k0 < K; k0 += 64) {
        __syncthreads();
        #pragma unroll
        for (int i = 0; i < BM / 32; i++) {
            int f = (i * 256 + t) * 8;
            int r = f >> 6, kk = f & 63;
            *(bf16x8*)&Ash[r][kk] = *(const bf16x8*)(A + (size_t)(r0 + r) * K + k0 + kk);
        }
        #pragma unroll
        for (int i = 0; i < 2; i++) {
            int f = (i * 256 + t) * 8;
            int r = f >> 6, kk = f & 63;
            *(bf16x8*)&Bsh[r][kk] = *(const bf16x8*)(WT + (size_t)(c0 + r) * K + k0 + kk);
        }
        __syncthreads();
        #pragma unroll
        for (int ks = 0; ks < 2; ks++) {
            bf16x8 b0 = *(const bf16x8*)&Bsh[wc * 32 + lrow][ks * 32 + lk];
            bf16x8 b1 = *(const bf16x8*)&Bsh[wc * 32 + 16 + lrow][ks * 32 + lk];
            #pragma unroll
            for (int m = 0; m < MREP; m++) {
                bf16x8 a = *(const bf16x8*)&Ash[wr * (BM / 2) + m * 16 + lrow][ks * 32 + lk];
                acc[m][0] = __builtin_amdgcn_mfma_f32_16x16x32_bf16(a, b0, acc[m][0], 0, 0, 0);
                acc[m][1] = __builtin_amdgcn_mfma_f32_16x16x32_bf16(a, b1, acc[m][1], 0, 0, 0);
            }
        }
    }
    const int rbase = r0 + wr * (BM / 2) + (lane >> 4) * 4;
    #pragma unroll
    for (int n = 0; n < 2; n++) {
        const int col = c0 + wc * 32 + n * 16 + lrow;
        const float bv = bias[col];
        #pragma unroll
        for (int m = 0; m < MREP; m++) {
            #pragma unroll
            for (int r = 0; r < 4; r++) {
                float v = acc[m][n][r] + bv;
                if (act == 1) v = gelu_tanh(v);
                else if (act == 2) v = v >= 0.f ? v : 0.2f * v;
                size_t off = (size_t)(rbase + m * 16 + r) * N + col;
                if (res) v += res[off];
                if (obf) ((unsigned short*)Cout)[off] = f2b(v);
                else ((float*)Cout)[off] = v;
            }
        }
    }
}

// ====== Fused conv2 GEMM + leaky + row-GN(128) -> bf16 ======
__global__ __launch_bounds__(512) void k_gemm_gn(
    const unsigned short* __restrict__ A, const unsigned short* __restrict__ WT,
    const float* __restrict__ bias, const float* __restrict__ g3, const float* __restrict__ be3,
    unsigned short* __restrict__ out)
{
    __shared__ __align__(16) char smem[23040];
    unsigned short (*Ash)[72] = (unsigned short(*)[72])smem;
    unsigned short (*Bsh)[72] = (unsigned short(*)[72])(smem + 4608);
    float (*vals)[136] = (float(*)[136])smem;
    const int t = threadIdx.x;
    const int r0 = blockIdx.x * 32;
    const int wid = t >> 6, lane = t & 63;
    const int mrow = wid >> 2, colq = wid & 3;
    const int lr = lane & 15, lk8 = (lane >> 4) * 8;
    f32x4 acc[2] = {};
    for (int k0 = 0; k0 < 512; k0 += 64) {
        __syncthreads();
        if (t < 256) {
            int f = t * 8;
            int r = f >> 6, kk = f & 63;
            *(bf16x8*)&Ash[r][kk] = *(const bf16x8*)(A + (size_t)(r0 + r) * 512 + k0 + kk);
        }
        #pragma unroll
        for (int i = 0; i < 2; i++) {
            int f = (i * 512 + t) * 8;
            int r = f >> 6, kk = f & 63;
            *(bf16x8*)&Bsh[r][kk] = *(const bf16x8*)(WT + (size_t)r * 512 + k0 + kk);
        }
        __syncthreads();
        #pragma unroll
        for (int ks = 0; ks < 2; ks++) {
            bf16x8 a = *(const bf16x8*)&Ash[mrow * 16 + lr][ks * 32 + lk8];
            #pragma unroll
            for (int nf = 0; nf < 2; nf++) {
                bf16x8 bb = *(const bf16x8*)&Bsh[colq * 32 + nf * 16 + lr][ks * 32 + lk8];
                acc[nf] = __builtin_amdgcn_mfma_f32_16x16x32_bf16(a, bb, acc[nf], 0, 0, 0);
            }
        }
    }
    __syncthreads();
    #pragma unroll
    for (int nf = 0; nf < 2; nf++) {
        int col = colq * 32 + nf * 16 + lr;
        float bv = bias[col];
        #pragma unroll
        for (int r = 0; r < 4; r++) {
            int row = mrow * 16 + (lane >> 4) * 4 + r;
            float v = acc[nf][r] + bv;
            vals[row][col] = v >= 0.f ? v : 0.2f * v;
        }
    }
    __syncthreads();
    const int row = t >> 4, cc0 = (t & 15) * 8;
    float s = 0.f, sq = 0.f;
    #pragma unroll
    for (int j = 0; j < 8; j++) {
        float v = vals[row][cc0 + j];
        s += v; sq += v * v;
    }
    s += __shfl_xor(s, 1); sq += __shfl_xor(sq, 1);
    s += __shfl_xor(s, 2); sq += __shfl_xor(sq, 2);
    s += __shfl_xor(s, 4); sq += __shfl_xor(sq, 4);
    s += __shfl_xor(s, 8); sq += __shfl_xor(sq, 8);
    float mean = s * (1.f / 128.f);
    float rs = rsqrtf(sq * (1.f / 128.f) - mean * mean + 1e-5f);
    ushort4 o[2];
    #pragma unroll
    for (int h = 0; h < 2; h++) {
        #pragma unroll
        for (int j = 0; j < 4; j++) {
            int col = cc0 + h * 4 + j;
            float v = (vals[row][col] - mean) * rs * g3[col] + be3[col];
            ((unsigned short*)&o[h])[j] = f2b(v);
        }
    }
    *(ushort4*)(out + (size_t)(r0 + row) * 128 + cc0) = o[0];
    *(ushort4*)(out + (size_t)(r0 + row) * 128 + cc0 + 4) = o[1];
}

// ====== Fused GEMM + residual + row-LN. BM=32, N=256 fixed, 512 threads. ======
__global__ __launch_bounds__(512) void k_gemm_ln(
    const unsigned short* __restrict__ A, const unsigned short* __restrict__ WT,
    const float* __restrict__ bias, const float* __restrict__ res,
    const float* __restrict__ lng, const float* __restrict__ lnb,
    float* __restrict__ xnew, unsigned short* __restrict__ h, int K)
{
    __shared__ __align__(16) char smem[41472];
    unsigned short (*Ash)[72] = (unsigned short(*)[72])smem;
    unsigned short (*Bsh)[72] = (unsigned short(*)[72])(smem + 4608);
    float (*vals)[264] = (float(*)[264])smem;
    const int t = threadIdx.x;
    const int r0 = blockIdx.x * 32;
    const int wid = t >> 6, lane = t & 63;
    const int lrow = lane & 15, lk8 = (lane >> 4) * 8;
    f32x4 acc[2][2] = {};
    for (int k0 = 0; k0 < K; k0 += 64) {
        __syncthreads();
        if (t < 256) {
            int f = t * 8;
            int r = f >> 6, kk = f & 63;
            *(bf16x8*)&Ash[r][kk] = *(const bf16x8*)(A + (size_t)(r0 + r) * K + k0 + kk);
        }
        #pragma unroll
        for (int i = 0; i < 4; i++) {
            int f = (i * 512 + t) * 8;
            int r = f >> 6, kk = f & 63;
            *(bf16x8*)&Bsh[r][kk] = *(const bf16x8*)(WT + (size_t)r * K + k0 + kk);
        }
        __syncthreads();
        #pragma unroll
        for (int ks = 0; ks < 2; ks++) {
            bf16x8 a0 = *(const bf16x8*)&Ash[lrow][ks * 32 + lk8];
            bf16x8 a1 = *(const bf16x8*)&Ash[16 + lrow][ks * 32 + lk8];
            #pragma unroll
            for (int nf = 0; nf < 2; nf++) {
                bf16x8 bfr = *(const bf16x8*)&Bsh[wid * 32 + nf * 16 + lrow][ks * 32 + lk8];
                acc[0][nf] = __builtin_amdgcn_mfma_f32_16x16x32_bf16(a0, bfr, acc[0][nf], 0, 0, 0);
                acc[1][nf] = __builtin_amdgcn_mfma_f32_16x16x32_bf16(a1, bfr, acc[1][nf], 0, 0, 0);
            }
        }
    }
    __syncthreads();
    #pragma unroll
    for (int m = 0; m < 2; m++)
        #pragma unroll
        for (int nf = 0; nf < 2; nf++) {
            int col = wid * 32 + nf * 16 + lrow;
            float bv = bias[col];
            #pragma unroll
            for (int r = 0; r < 4; r++) {
                int row = m * 16 + (lane >> 4) * 4 + r;
                vals[row][col] = acc[m][nf][r] + bv + res[(size_t)(r0 + row) * 256 + col];
            }
        }
    __syncthreads();
    const int row = t >> 4, c4 = (t & 15) * 4;
    float s = 0.f, sq = 0.f;
    #pragma unroll
    for (int j = 0; j < 4; j++) {
        float4 v4 = *(const float4*)&vals[row][c4 + j * 64];
        s += v4.x + v4.y + v4.z + v4.w;
        sq += v4.x * v4.x + v4.y * v4.y + v4.z * v4.z + v4.w * v4.w;
    }
    s += __shfl_xor(s, 1); sq += __shfl_xor(sq, 1);
    s += __shfl_xor(s, 2); sq += __shfl_xor(sq, 2);
    s += __shfl_xor(s, 4); sq += __shfl_xor(sq, 4);
    s += __shfl_xor(s, 8); sq += __shfl_xor(sq, 8);
    float mean = s * (1.f / 256.f);
    float rs = rsqrtf(sq * (1.f / 256.f) - mean * mean + 1e-5f);
    const size_t gbase = (size_t)(r0 + row) * 256;
    #pragma unroll
    for (int j = 0; j < 4; j++) {
        int col = c4 + j * 64;
        float4 v4 = *(const float4*)&vals[row][col];
        *(float4*)(xnew + gbase + col) = v4;
        if (lng) {
            float4 g4 = *(const float4*)(lng + col);
            float4 b4 = *(const float4*)(lnb + col);
            ushort4 o;
            o.x = f2b((v4.x - mean) * rs * g4.x + b4.x);
            o.y = f2b((v4.y - mean) * rs * g4.y + b4.y);
            o.z = f2b((v4.z - mean) * rs * g4.z + b4.z);
            o.w = f2b((v4.w - mean) * rs * g4.w + b4.w);
            *(ushort4*)(h + gbase + col) = o;
        }
    }
}

// =============== GN2 ===============
__global__ __launch_bounds__(256) void k_gn2(
    const float* __restrict__ din, const float* __restrict__ g2, const float* __restrict__ be2,
    unsigned short* __restrict__ dout)
{
    const int t = threadIdx.x;
    const int w = t >> 6, lane = t & 63;
    const int p = blockIdx.x * 2 + (w >> 1), g = w & 1;
    float4 v = ((const float4*)(din + (size_t)p * 512 + g * 256))[lane];
    float s = v.x + v.y + v.z + v.w;
    float sq = v.x * v.x + v.y * v.y + v.z * v.z + v.w * v.w;
    #pragma unroll
    for (int m = 1; m < 64; m <<= 1) { s += __shfl_xor(s, m, 64); sq += __shfl_xor(sq, m, 64); }
    float mean = s * (1.f / 256.f);
    float rs = rsqrtf(sq * (1.f / 256.f) - mean * mean + 1e-5f);
    int oc = g * 32 + (lane >> 1);
    float gg = g2[oc], bb = be2[oc];
    ushort4 o;
    o.x = f2b((v.x - mean) * rs * gg + bb);
    o.y = f2b((v.y - mean) * rs * gg + bb);
    o.z = f2b((v.z - mean) * rs * gg + bb);
    o.w = f2b((v.w - mean) * rs * gg + bb);
    ((ushort4*)(dout + (size_t)p * 512 + g * 256))[lane] = o;
}

// ====== LN(u)+LN(pos) -> xb f32, and hb = LN_{l1[0]}(xb) bf16. Wave per row. ======
__global__ __launch_bounds__(256) void k_lnpos(
    const float* __restrict__ u, const float* __restrict__ pos,
    const float* __restrict__ lndg, const float* __restrict__ lndb,
    const float* __restrict__ lnpg, const float* __restrict__ lnpb,
    const float* __restrict__ l1g0, const float* __restrict__ l1b0,
    float* __restrict__ xb, unsigned short* __restrict__ hb)
{
    const int t = threadIdx.x;
    const int row = blockIdx.x * 4 + (t >> 6);
    const int lane = t & 63;
    float4 v = ((const float4*)(u + (size_t)row * 256))[lane];
    float4 w = ((const float4*)(pos + (size_t)(row & 511) * 256))[lane];
    float s = v.x + v.y + v.z + v.w;
    float sq = v.x * v.x + v.y * v.y + v.z * v.z + v.w * v.w;
    float sp = w.x + w.y + w.z + w.w;
    float qp = w.x * w.x + w.y * w.y + w.z * w.z + w.w * w.w;
    #pragma unroll
    for (int m = 1; m < 64; m <<= 1) {
        s += __shfl_xor(s, m, 64); sq += __shfl_xor(sq, m, 64);
        sp += __shfl_xor(sp, m, 64); qp += __shfl_xor(qp, m, 64);
    }
    float mu = s * (1.f / 256.f), ru = rsqrtf(sq * (1.f / 256.f) - mu * mu + 1e-5f);
    float mp = sp * (1.f / 256.f), rp = rsqrtf(qp * (1.f / 256.f) - mp * mp + 1e-5f);
    float4 ga = ((const float4*)lndg)[lane], ba = ((const float4*)lndb)[lane];
    float4 gp = ((const float4*)lnpg)[lane], bp = ((const float4*)lnpb)[lane];
    float4 o;
    o.x = (v.x - mu) * ru * ga.x + ba.x + (w.x - mp) * rp * gp.x + bp.x;
    o.y = (v.y - mu) * ru * ga.y + ba.y + (w.y - mp) * rp * gp.y + bp.y;
    o.z = (v.z - mu) * ru * ga.z + ba.z + (w.z - mp) * rp * gp.z + bp.z;
    o.w = (v.w - mu) * ru * ga.w + ba.w + (w.w - mp) * rp * gp.w + bp.w;
    ((float4*)(xb + (size_t)row * 256))[lane] = o;
    float s2 = o.x + o.y + o.z + o.w;
    float q2 = o.x * o.x + o.y * o.y + o.z * o.z + o.w * o.w;
    #pragma unroll
    for (int m = 1; m < 64; m <<= 1) { s2 += __shfl_xor(s2, m, 64); q2 += __shfl_xor(q2, m, 64); }
    float mu2 = s2 * (1.f / 256.f), r2 = rsqrtf(q2 * (1.f / 256.f) - mu2 * mu2 + 1e-5f);
    float4 g4 = ((const float4*)l1g0)[lane], b4 = ((const float4*)l1b0)[lane];
    ushort4 ho;
    ho.x = f2b((o.x - mu2) * r2 * g4.x + b4.x);
    ho.y = f2b((o.y - mu2) * r2 * g4.y + b4.y);
    ho.z = f2b((o.z - mu2) * r2 * g4.z + b4.z);
    ho.w = f2b((o.w - mu2) * r2 * g4.w + b4.w);
    ((ushort4*)(hb + (size_t)row * 256))[lane] = ho;
}

// ====== MFMA flash attention: qkv bf16 [8192][768] -> o bf16 [8192][256] ======
__global__ __launch_bounds__(256) void k_attn3(
    const unsigned short* __restrict__ qkv, unsigned short* __restrict__ og)
{
    __shared__ unsigned short Ks[64][36];
    __shared__ unsigned short Vt[32][72];
    __shared__ unsigned short Pt[4][16][72];
    const int t = threadIdx.x;
    const int bid = blockIdx.x;
    const int b = bid >> 6, hh = (bid >> 3) & 7, qt = bid & 7;
    const int wid = t >> 6, lane = t & 63;
    const int lr = lane & 15, lk8 = (lane >> 4) * 8;
    const int qrow = b * 512 + qt * 64 + wid * 16 + lr;
    const bf16x8 qf = *(const bf16x8*)(qkv + (size_t)qrow * 768 + hh * 32 + lk8);
    f32x4 O0 = {}, O1 = {};
    float mreg[4] = { -1e30f, -1e30f, -1e30f, -1e30f };
    float lreg[4] = {};
    const float scale = 0.17677669529663687f;
    for (int kv0 = 0; kv0 < 512; kv0 += 64) {
        __syncthreads();
        {
            int kvr = t >> 2, dd = (t & 3) * 8;
            size_t base = (size_t)(b * 512 + kv0 + kvr) * 768 + hh * 32;
            *(bf16x8*)&Ks[kvr][dd] = *(const bf16x8*)(qkv + base + 256 + dd);
            bf16x8 v8 = *(const bf16x8*)(qkv + base + 512 + dd);
            #pragma unroll
            for (int j = 0; j < 8; j++) Vt[dd + j][kvr] = (unsigned short)v8[j];
        }
        __syncthreads();
        f32x4 st[4];
        #pragma unroll
        for (int tt = 0; tt < 4; tt++) {
            bf16x8 kf = *(const bf16x8*)&Ks[tt * 16 + lr][lk8];
            st[tt] = __builtin_amdgcn_mfma_f32_16x16x32_bf16(qf, kf, (f32x4){}, 0, 0, 0);
        }
        float mnew[4], csc[4], psum[4];
        #pragma unroll
        for (int r = 0; r < 4; r++) {
            st[0][r] *= scale; st[1][r] *= scale; st[2][r] *= scale; st[3][r] *= scale;
            float mx = fmaxf(fmaxf(st[0][r], st[1][r]), fmaxf(st[2][r], st[3][r]));
            mx = fmaxf(mx, __shfl_xor(mx, 1));
            mx = fmaxf(mx, __shfl_xor(mx, 2));
            mx = fmaxf(mx, __shfl_xor(mx, 4));
            mx = fmaxf(mx, __shfl_xor(mx, 8));
            mnew[r] = fmaxf(mreg[r], mx);
            csc[r] = __expf(mreg[r] - mnew[r]);
            mreg[r] = mnew[r];
            psum[r] = 0.f;
        }
        #pragma unroll
        for (int tt = 0; tt < 4; tt++)
            #pragma unroll
            for (int r = 0; r < 4; r++) {
                float p = __expf(st[tt][r] - mnew[r]);
                st[tt][r] = p;
                psum[r] += p;
            }
        #pragma unroll
        for (int r = 0; r < 4; r++) {
            psum[r] += __shfl_xor(psum[r], 1);
            psum[r] += __shfl_xor(psum[r], 2);
            psum[r] += __shfl_xor(psum[r], 4);
            psum[r] += __shfl_xor(psum[r], 8);
            lreg[r] = lreg[r] * csc[r] + psum[r];
            O0[r] *= csc[r]; O1[r] *= csc[r];
        }
        #pragma unroll
        for (int tt = 0; tt < 4; tt++)
            #pragma unroll
            for (int r = 0; r < 4; r++)
                Pt[wid][(lane >> 4) * 4 + r][tt * 16 + lr] = f2b(st[tt][r]);
        #pragma unroll
        for (int half = 0; half < 2; half++) {
            bf16x8 pa  = *(const bf16x8*)&Pt[wid][lr][half * 32 + lk8];
            bf16x8 vlo = *(const bf16x8*)&Vt[lr][half * 32 + lk8];
            bf16x8 vhi = *(const bf16x8*)&Vt[16 + lr][half * 32 + lk8];
            O0 = __builtin_amdgcn_mfma_f32_16x16x32_bf16(pa, vlo, O0, 0, 0, 0);
            O1 = __builtin_amdgcn_mfma_f32_16x16x32_bf16(pa, vhi, O1, 0, 0, 0);
        }
    }
    #pragma unroll
    for (int r = 0; r < 4; r++) {
        float inv = 1.f / lreg[r];
        size_t orow = (size_t)(b * 512 + qt * 64 + wid * 16 + (lane >> 4) * 4 + r) * 256 + hh * 32;
        og[orow + lr] = f2b(O0[r] * inv);
        og[orow + 16 + lr] = f2b(O1[r] * inv);
    }
}

extern "C" void kernel_launch(void* const* d_in, const int* in_sizes, int n_in,
                              void* d_out, int out_size, void* d_ws, size_t ws_size,
                              hipStream_t stream)
{
    const float* img  = (const float*)d_in[0];
    const float* bfac = (const float*)d_in[1];
    const float* w0  = (const float*)d_in[2];  const float* b0c = (const float*)d_in[3];
    const float* g1  = (const float*)d_in[4];  const float* be1 = (const float*)d_in[5];
    const float* w1  = (const float*)d_in[6];  const float* b1c = (const float*)d_in[7];
    const float* g2  = (const float*)d_in[8];  const float* be2 = (const float*)d_in[9];
    const float* w2  = (const float*)d_in[10]; const float* b2c = (const float*)d_in[11];
    const float* g3  = (const float*)d_in[12]; const float* be3 = (const float*)d_in[13];
    const float* wu  = (const float*)d_in[14]; const float* bu  = (const float*)d_in[15];
    const float* pos = (const float*)d_in[16];
    const float* lndg = (const float*)d_in[17]; const float* lndb = (const float*)d_in[18];
    const float* lnpg = (const float*)d_in[19]; const float* lnpb = (const float*)d_in[20];
    const float* Wq = (const float*)d_in[21]; const float* bq = (const float*)d_in[22];
    const float* Wk = (const float*)d_in[23]; const float* bk = (const float*)d_in[24];
    const float* Wv = (const float*)d_in[25]; const float* bv = (const float*)d_in[26];
    const float* Wo = (const float*)d_in[27]; const float* bo = (const float*)d_in[28];
    const float* l1g = (const float*)d_in[29]; const float* l1b = (const float*)d_in[30];
    const float* l2g = (const float*)d_in[31]; const float* l2b = (const float*)d_in[32];
    const float* W1 = (const float*)d_in[33]; const float* bf1 = (const float*)d_in[34];
    const float* W2 = (const float*)d_in[35]; const float* bf2 = (const float*)d_in[36];

    float* ws = (float*)d_ws;
    unsigned short* d0b   = (unsigned short*)(ws);              // [8192][2048] bf16
    float*          d1raw = ws + 8388608;                       // [8192][512] f32
    unsigned short* d1b   = (unsigned short*)(ws + 12582912);   // [8192][512] bf16
    float*          xb    = ws + 14680064;                      // [8192][256] f32
    unsigned short* w1T   = (unsigned short*)(ws + 16777216);
    unsigned short* w2T   = (unsigned short*)(ws + 17301504);
    unsigned short* wuTb  = (unsigned short*)(ws + 17334272);
    unsigned short* WqkvT = (unsigned short*)(ws + 17350656);   // 8x768x256
    unsigned short* WoT   = (unsigned short*)(ws + 18137088);
    unsigned short* W1T   = (unsigned short*)(ws + 18399232);
    unsigned short* W2T   = (unsigned short*)(ws + 19447808);
    float*          b1x   = ws + 20496384;
    float*          bqkv  = ws + 20496896;
    // Phase C overlay (d0b dead after conv1 GEMM):
    unsigned short* d2b   = (unsigned short*)(ws + 1048576);    // [8192][128] bf16
    float*          ub    = ws + 1572864;                       // [8192][256] f32
    // Phase D overlay:
    unsigned short* hb    = (unsigned short*)(ws);              // [8192][256] bf16
    unsigned short* qkvb  = (unsigned short*)(ws + 1048576);    // [8192][768] bf16
    unsigned short* obb   = (unsigned short*)(ws + 4194304);    // [8192][256] bf16
    unsigned short* m1b   = (unsigned short*)(ws + 5242880);    // [8192][1024] bf16
    float* xout = (float*)d_out;

    // Weight prep: ONE launch
    k_prep_all<<<29058, 256, 0, stream>>>(w1, w2, wu, b1c, Wq, Wk, Wv, bq, bk, bv, Wo, W1, W2,
                                          w1T, w2T, wuTb, b1x, WqkvT, bqkv, WoT, W1T, W2T);

    // Encoder
    k_blur_conv0<<<8192, 256, 0, stream>>>(img, bfac, w0, b0c, g1, be1, d0b);
    k_gemm_bf16<128><<<8 * 64, 256, 0, stream>>>(d0b, w1T, b1x, nullptr, d1raw, 8, 512, 2048, 2, 0);
    k_gn2<<<4096, 256, 0, stream>>>(d1raw, g2, be2, d1b);
    k_gemm_gn<<<256, 512, 0, stream>>>(d1b, w2T, b2c, g3, be3, d2b);
    k_gemm_bf16<128><<<4 * 64, 256, 0, stream>>>(d2b, wuTb, bu, nullptr, ub, 4, 256, 128, 0, 0);
    k_lnpos<<<2048, 256, 0, stream>>>(ub, pos, lndg, lndb, lnpg, lnpb, l1g, l1b, xb, hb);

    // Transformer: per layer {qkv, attn, Wo+res+LN(l2), W1(gelu), W2+res+LN(next l1)}
    for (int i = 0; i < 8; i++) {
        k_gemm_bf16<128><<<12 * 64, 256, 0, stream>>>(hb, WqkvT + (size_t)i * 196608, bqkv + i * 768, nullptr, qkvb, 12, 768, 256, 0, 1);
        k_attn3<<<1024, 256, 0, stream>>>(qkvb, obb);
        k_gemm_ln<<<256, 512, 0, stream>>>(obb, WoT + (size_t)i * 65536, bo + i * 256, xb,
                                           l2g + i * 256, l2b + i * 256, xb, hb, 256);
        k_gemm_bf16<128><<<16 * 64, 256, 0, stream>>>(hb, W1T + (size_t)i * 262144, bf1 + i * 1024, nullptr, m1b, 16, 1024, 256, 1, 1);
        if (i < 7) {
            k_gemm_ln<<<256, 512, 0, stream>>>(m1b, W2T + (size_t)i * 262144, bf2 + i * 256, xb,
                                               l1g + (i + 1) * 256, l1b + (i + 1) * 256, xb, hb, 1024);
        } else {
            k_gemm_ln<<<256, 512, 0, stream>>>(m1b, W2T + (size_t)i * 262144, bf2 + i * 256, xb,
                                               nullptr, nullptr, xout, nullptr, 1024);
        }
    }
}

// Round 11
// 827.385 us; speedup vs baseline: 7.2055x; 1.0558x over previous
//
#include <hip/hip_runtime.h>
#include <hip/hip_bf16.h>

#define PI2F 9.869604401089358f

typedef __attribute__((ext_vector_type(8))) short bf16x8;
typedef __attribute__((ext_vector_type(4))) float f32x4;

// async global->LDS, 16B per lane; LDS dest is wave-uniform base + lane*16
#define GLOAD16(g, l) __builtin_amdgcn_global_load_lds( \
    (const __attribute__((address_space(1))) void*)(g), \
    (__attribute__((address_space(3))) void*)(l), 16, 0, 0)

__device__ inline unsigned short f2b(float v) {
    union { float f; unsigned u; } x; x.f = v;
    unsigned r = x.u + 0x7fffu + ((x.u >> 16) & 1u);
    return (unsigned short)(r >> 16);
}

__device__ inline float gelu_tanh(float v) {
    float u = 0.7978845608028654f * (v + 0.044715f * v * v * v);
    float th = 1.f - 2.f / (1.f + __expf(2.f * u));
    return 0.5f * v * (1.f + th);
}

// =============== Kernel A: unfold + separable circular blur + MFMA conv0 + leaky + GN(G=4) =====
__global__ __launch_bounds__(256) void k_blur_conv0(
    const float* __restrict__ img, const float* __restrict__ bfac,
    const float* __restrict__ w0, const float* __restrict__ b0c,
    const float* __restrict__ g1, const float* __restrict__ be1,
    unsigned short* __restrict__ d0)
{
    __shared__ float pa[512], pb[512], hsm[8];
    __shared__ unsigned short pbb[512];
    __shared__ unsigned short w0b[32][72];
    __shared__ float d0s[64 * 33];
    __shared__ float2 gstat[4];
    const int t = threadIdx.x, blk = blockIdx.x;
    const int b = blk >> 9, rem = blk & 511;
    const int zh = rem >> 6, yh = (rem >> 3) & 7, xh = rem & 7;

    #pragma unroll
    for (int i = 0; i < 2; i++) {
        int v = t + 256 * i;
        int z = v >> 6, y = (v >> 3) & 7, x = v & 7;
        pa[v] = img[(((size_t)(b * 8 + zh) * 8 + z) * 64 + yh * 8 + y) * 64 + xh * 8 + x];
    }
    #pragma unroll
    for (int i = 0; i < 8; i++) {
        int idx = i * 256 + t;
        w0b[idx >> 6][idx & 63] = f2b(w0[idx]);
    }
    if (t < 8) {
        float bf = bfac[blk];
        float c = bf * PI2F * (1.0f / 16.0f);
        float gk1 = __expf(-c), gk2 = __expf(-4.f * c), gk3 = __expf(-9.f * c), gk4 = __expf(-16.f * c);
        float d = (float)t;
        float h = 1.f + 2.f * (gk1 * cosf(0.7853981633974483f * d)
                             + gk2 * cosf(1.5707963267948966f * d)
                             + gk3 * cosf(2.356194490192345f * d))
                      + gk4 * cosf(3.141592653589793f * d);
        hsm[t] = 0.125f * h;
    }
    __syncthreads();
    #pragma unroll
    for (int i = 0; i < 2; i++) {
        int v = t + 256 * i; int x = v & 7; int base = v & ~7;
        float s = 0.f;
        #pragma unroll
        for (int m = 0; m < 8; m++) s += hsm[(x - m) & 7] * pa[base + m];
        pb[v] = s;
    }
    __syncthreads();
    #pragma unroll
    for (int i = 0; i < 2; i++) {
        int v = t + 256 * i; int y = (v >> 3) & 7; int base = (v & ~63) | (v & 7);
        float s = 0.f;
        #pragma unroll
        for (int m = 0; m < 8; m++) s += hsm[(y - m) & 7] * pb[base + m * 8];
        pa[v] = s;
    }
    __syncthreads();
    #pragma unroll
    for (int i = 0; i < 2; i++) {
        int v = t + 256 * i; int z = v >> 6; int base = v & 63;
        float s = 0.f;
        #pragma unroll
        for (int m = 0; m < 8; m++) s += hsm[(z - m) & 7] * pa[base + m * 64];
        pb[v] = s;
        pbb[v] = f2b(s);
    }
    __syncthreads();
    const int wid = t >> 6, lane = t & 63;
    const int lr = lane & 15, lk8 = (lane >> 4) * 8;
    {
        const int vox = wid * 16 + lr;
        const int szb = 2 * (vox >> 4) - 1, syb = 2 * ((vox >> 2) & 3) - 1, sxb = 2 * (vox & 3) - 1;
        f32x4 acc0 = {}, acc1 = {};
        #pragma unroll
        for (int ks = 0; ks < 2; ks++) {
            bf16x8 a;
            #pragma unroll
            for (int j = 0; j < 8; j++) {
                int tap = ks * 32 + lk8 + j;
                int sz = szb + (tap >> 4), sy = syb + ((tap >> 2) & 3), sx = sxb + (tap & 3);
                bool ok = (unsigned)sz < 8u && (unsigned)sy < 8u && (unsigned)sx < 8u;
                a[j] = ok ? (short)pbb[sz * 64 + sy * 8 + sx] : (short)0;
            }
            bf16x8 b0 = *(const bf16x8*)&w0b[lr][ks * 32 + lk8];
            bf16x8 b1 = *(const bf16x8*)&w0b[16 + lr][ks * 32 + lk8];
            acc0 = __builtin_amdgcn_mfma_f32_16x16x32_bf16(a, b0, acc0, 0, 0, 0);
            acc1 = __builtin_amdgcn_mfma_f32_16x16x32_bf16(a, b1, acc1, 0, 0, 0);
        }
        const float bA = b0c[lr], bB = b0c[16 + lr];
        #pragma unroll
        for (int r = 0; r < 4; r++) {
            int crow = wid * 16 + (lane >> 4) * 4 + r;
            float v0 = acc0[r] + bA; v0 = v0 >= 0.f ? v0 : 0.2f * v0;
            float v1 = acc1[r] + bB; v1 = v1 >= 0.f ? v1 : 0.2f * v1;
            d0s[crow * 33 + lr] = v0;
            d0s[crow * 33 + 16 + lr] = v1;
        }
    }
    __syncthreads();
    {
        int g = wid;
        float s = 0.f, sq = 0.f;
        #pragma unroll
        for (int cc = 0; cc < 8; cc++) { float v = d0s[lane * 33 + g * 8 + cc]; s += v; sq += v * v; }
        #pragma unroll
        for (int m = 1; m < 64; m <<= 1) { s += __shfl_xor(s, m, 64); sq += __shfl_xor(sq, m, 64); }
        if (lane == 0) {
            float mean = s * (1.f / 512.f);
            float var = sq * (1.f / 512.f) - mean * mean;
            gstat[g] = make_float2(mean, rsqrtf(var + 1e-5f));
        }
    }
    __syncthreads();
    size_t obase = (size_t)blk * 2048;
    #pragma unroll
    for (int i = 0; i < 8; i++) {
        int oi = t + 256 * i;
        int c = oi >> 6, vox = oi & 63;
        float2 st = gstat[oi >> 9];
        d0[obase + oi] = f2b((d0s[vox * 33 + c] - st.x) * st.y * g1[c] + be1[c]);
    }
}

// =============== ONE merged weight-prep kernel ===============
__global__ __launch_bounds__(256) void k_prep_all(
    const float* __restrict__ w1, const float* __restrict__ w2, const float* __restrict__ wu,
    const float* __restrict__ b1c,
    const float* __restrict__ Wq, const float* __restrict__ Wk, const float* __restrict__ Wv,
    const float* __restrict__ bq, const float* __restrict__ bk, const float* __restrict__ bv,
    const float* __restrict__ Wo, const float* __restrict__ W1, const float* __restrict__ W2,
    unsigned short* __restrict__ w1T, unsigned short* __restrict__ w2T,
    unsigned short* __restrict__ wuT, float* __restrict__ b1x,
    unsigned short* __restrict__ WqkvT, float* __restrict__ bqkv,
    unsigned short* __restrict__ WoT, unsigned short* __restrict__ W1T, unsigned short* __restrict__ W2T)
{
    const int blk = blockIdx.x, t = threadIdx.x;
    if (blk < 4096) {
        int idx = blk * 256 + t;
        int n = idx >> 11, k = idx & 2047;
        int oc = n >> 3, vox = n & 7;
        int oz = vox >> 2, oy = (vox >> 1) & 1, ox = vox & 1;
        int ci = k >> 6, sp = k & 63;
        int sz = sp >> 4, sy = (sp >> 2) & 3, sx = sp & 3;
        int kz = sz + 1 - 2 * oz, ky = sy + 1 - 2 * oy, kx = sx + 1 - 2 * ox;
        float v = 0.f;
        if ((unsigned)kz < 4u && (unsigned)ky < 4u && (unsigned)kx < 4u)
            v = w1[(size_t)oc * 2048 + ci * 64 + kz * 16 + ky * 4 + kx];
        w1T[idx] = f2b(v);
    } else if (blk < 4352) {
        int idx = (blk - 4096) * 256 + t;
        int n = idx >> 9, k = idx & 511;
        int ci = k >> 3, v = k & 7;
        int z = v >> 2, y = (v >> 1) & 1, x = v & 1;
        w2T[idx] = f2b(w2[(size_t)n * 4096 + ci * 64 + (z + 1) * 16 + (y + 1) * 4 + (x + 1)]);
    } else if (blk < 4480) {
        int idx = (blk - 4352) * 256 + t;
        wuT[idx] = f2b(wu[idx]);
    } else if (blk < 4482) {
        int idx = (blk - 4480) * 256 + t;
        b1x[idx] = b1c[idx >> 3];
    } else if (blk < 10626) {
        int task = blk - 4482;
        int l = task / 768, n = task % 768;
        int sel = n >> 8, col = n & 255;
        const float* W = sel == 0 ? Wq : sel == 1 ? Wk : Wv;
        const float* bb = sel == 0 ? bq : sel == 1 ? bk : bv;
        WqkvT[((size_t)l * 768 + n) * 256 + t] = f2b(W[(size_t)l * 65536 + (size_t)t * 256 + col]);
        if (t == 0) bqkv[l * 768 + n] = bb[l * 256 + col];
    } else if (blk < 12674) {
        int gid = (blk - 10626) * 256 + t;
        int l = gid >> 16, w = gid & 65535;
        int n = w >> 8, k = w & 255;
        WoT[gid] = f2b(Wo[(size_t)l * 65536 + (size_t)k * 256 + n]);
    } else if (blk < 20866) {
        int gid = (blk - 12674) * 256 + t;
        int l = gid >> 18, w = gid & 262143;
        int n = w >> 8, k = w & 255;
        W1T[gid] = f2b(W1[(size_t)l * 262144 + (size_t)k * 1024 + n]);
    } else {
        int gid = (blk - 20866) * 256 + t;
        int l = gid >> 18, w = gid & 262143;
        int n = w >> 10, k = w & 1023;
        W2T[gid] = f2b(W2[(size_t)l * 262144 + (size_t)k * 256 + n]);
    }
}

// ====== MFMA GEMM, XCD-chunk swizzle + global_load_lds(16B) staging + T2 LDS swizzle ======
// LDS linear [rows][64]; involution col_phys = col ^ ((row&7)<<3): inverse-swizzled global
// source per lane (chunk (l&7)^(l>>3) of row l>>3), linear dest, swizzled ds_read.
template<int BM>
__global__ __launch_bounds__(256) void k_gemm_bf16(
    const unsigned short* __restrict__ A, const unsigned short* __restrict__ WT,
    const float* __restrict__ bias, const float* __restrict__ res,
    void* __restrict__ Cout, int NXB, int N, int K, int act, int obf)
{
    constexpr int MREP = BM / 32;
    __shared__ unsigned short Ash[BM][64];
    __shared__ unsigned short Bsh[64][64];
    const int t = threadIdx.x;
    const int lb = blockIdx.x;
    const int xcd = lb & 7, j = lb >> 3;
    const int gy = xcd * 8 + j / NXB, gx = j % NXB;
    const int c0 = gx * 64;
    const int r0 = gy * BM;
    const int wid = t >> 6, lane = t & 63;
    const int wr = wid >> 1, wc = wid & 1;
    const int lrow = lane & 15, lk = (lane >> 4) * 8;
    const int xsw = (lrow & 7) << 3;
    const int srcsw = ((lane & 7) ^ (lane >> 3)) << 3;   // element offset of the 16B chunk this lane fetches
    f32x4 acc[MREP][2] = {};
    for (int k0 = 0; k0 < K; k0 += 64) {
        __syncthreads();
        {   // A: wave wid stages rows wid*(BM/4) .. +BM/4-1, BM/32 insts of 8 rows
            const unsigned short* ga = A + (size_t)(r0 + wid * (BM / 4) + (lane >> 3)) * K + k0 + srcsw;
            unsigned short* la = &Ash[wid * (BM / 4)][0];
            #pragma unroll
            for (int i = 0; i < BM / 32; i++)
                GLOAD16(ga + (size_t)(i * 8) * K, la + i * 8 * 64);
        }
        {   // B: wave wid stages rows wid*16 .. +15, 2 insts
            const unsigned short* gb = WT + (size_t)(c0 + wid * 16 + (lane >> 3)) * K + k0 + srcsw;
            unsigned short* lbp = &Bsh[wid * 16][0];
            #pragma unroll
            for (int i = 0; i < 2; i++)
                GLOAD16(gb + (size_t)(i * 8) * K, lbp + i * 8 * 64);
        }
        __syncthreads();
        #pragma unroll
        for (int ks = 0; ks < 2; ks++) {
            bf16x8 b0 = *(const bf16x8*)&Bsh[wc * 32 + lrow][(ks * 32 + lk) ^ xsw];
            bf16x8 b1 = *(const bf16x8*)&Bsh[wc * 32 + 16 + lrow][(ks * 32 + lk) ^ xsw];
            #pragma unroll
            for (int m = 0; m < MREP; m++) {
                bf16x8 a = *(const bf16x8*)&Ash[wr * (BM / 2) + m * 16 + lrow][(ks * 32 + lk) ^ xsw];
                acc[m][0] = __builtin_amdgcn_mfma_f32_16x16x32_bf16(a, b0, acc[m][0], 0, 0, 0);
                acc[m][1] = __builtin_amdgcn_mfma_f32_16x16x32_bf16(a, b1, acc[m][1], 0, 0, 0);
            }
        }
    }
    const int rbase = r0 + wr * (BM / 2) + (lane >> 4) * 4;
    #pragma unroll
    for (int n = 0; n < 2; n++) {
        const int col = c0 + wc * 32 + n * 16 + lrow;
        const float bv = bias[col];
        #pragma unroll
        for (int m = 0; m < MREP; m++) {
            #pragma unroll
            for (int r = 0; r < 4; r++) {
                float v = acc[m][n][r] + bv;
                if (act == 1) v = gelu_tanh(v);
                else if (act == 2) v = v >= 0.f ? v : 0.2f * v;
                size_t off = (size_t)(rbase + m * 16 + r) * N + col;
                if (res) v += res[off];
                if (obf) ((unsigned short*)Cout)[off] = f2b(v);
                else ((float*)Cout)[off] = v;
            }
        }
    }
}

// ====== Fused conv2 GEMM + leaky + row-GN(128) -> bf16 (unchanged structure) ======
__global__ __launch_bounds__(512) void k_gemm_gn(
    const unsigned short* __restrict__ A, const unsigned short* __restrict__ WT,
    const float* __restrict__ bias, const float* __restrict__ g3, const float* __restrict__ be3,
    unsigned short* __restrict__ out)
{
    __shared__ __align__(16) char smem[23040];
    unsigned short (*Ash)[72] = (unsigned short(*)[72])smem;
    unsigned short (*Bsh)[72] = (unsigned short(*)[72])(smem + 4608);
    float (*vals)[136] = (float(*)[136])smem;
    const int t = threadIdx.x;
    const int r0 = blockIdx.x * 32;
    const int wid = t >> 6, lane = t & 63;
    const int mrow = wid >> 2, colq = wid & 3;
    const int lr = lane & 15, lk8 = (lane >> 4) * 8;
    f32x4 acc[2] = {};
    for (int k0 = 0; k0 < 512; k0 += 64) {
        __syncthreads();
        if (t < 256) {
            int f = t * 8;
            int r = f >> 6, kk = f & 63;
            *(bf16x8*)&Ash[r][kk] = *(const bf16x8*)(A + (size_t)(r0 + r) * 512 + k0 + kk);
        }
        #pragma unroll
        for (int i = 0; i < 2; i++) {
            int f = (i * 512 + t) * 8;
            int r = f >> 6, kk = f & 63;
            *(bf16x8*)&Bsh[r][kk] = *(const bf16x8*)(WT + (size_t)r * 512 + k0 + kk);
        }
        __syncthreads();
        #pragma unroll
        for (int ks = 0; ks < 2; ks++) {
            bf16x8 a = *(const bf16x8*)&Ash[mrow * 16 + lr][ks * 32 + lk8];
            #pragma unroll
            for (int nf = 0; nf < 2; nf++) {
                bf16x8 bb = *(const bf16x8*)&Bsh[colq * 32 + nf * 16 + lr][ks * 32 + lk8];
                acc[nf] = __builtin_amdgcn_mfma_f32_16x16x32_bf16(a, bb, acc[nf], 0, 0, 0);
            }
        }
    }
    __syncthreads();
    #pragma unroll
    for (int nf = 0; nf < 2; nf++) {
        int col = colq * 32 + nf * 16 + lr;
        float bv = bias[col];
        #pragma unroll
        for (int r = 0; r < 4; r++) {
            int row = mrow * 16 + (lane >> 4) * 4 + r;
            float v = acc[nf][r] + bv;
            vals[row][col] = v >= 0.f ? v : 0.2f * v;
        }
    }
    __syncthreads();
    const int row = t >> 4, cc0 = (t & 15) * 8;
    float s = 0.f, sq = 0.f;
    #pragma unroll
    for (int j = 0; j < 8; j++) {
        float v = vals[row][cc0 + j];
        s += v; sq += v * v;
    }
    s += __shfl_xor(s, 1); sq += __shfl_xor(sq, 1);
    s += __shfl_xor(s, 2); sq += __shfl_xor(sq, 2);
    s += __shfl_xor(s, 4); sq += __shfl_xor(sq, 4);
    s += __shfl_xor(s, 8); sq += __shfl_xor(sq, 8);
    float mean = s * (1.f / 128.f);
    float rs = rsqrtf(sq * (1.f / 128.f) - mean * mean + 1e-5f);
    ushort4 o[2];
    #pragma unroll
    for (int h = 0; h < 2; h++) {
        #pragma unroll
        for (int j = 0; j < 4; j++) {
            int col = cc0 + h * 4 + j;
            float v = (vals[row][col] - mean) * rs * g3[col] + be3[col];
            ((unsigned short*)&o[h])[j] = f2b(v);
        }
    }
    *(ushort4*)(out + (size_t)(r0 + row) * 128 + cc0) = o[0];
    *(ushort4*)(out + (size_t)(r0 + row) * 128 + cc0 + 4) = o[1];
}

// ====== Fused GEMM + residual + row-LN, global_load_lds staging + T2 swizzle ======
// BM=32, N=256, 512 threads (8 waves). Ash[32][64], Bsh[256][64] linear; vals overlays.
__global__ __launch_bounds__(512) void k_gemm_ln(
    const unsigned short* __restrict__ A, const unsigned short* __restrict__ WT,
    const float* __restrict__ bias, const float* __restrict__ res,
    const float* __restrict__ lng, const float* __restrict__ lnb,
    float* __restrict__ xnew, unsigned short* __restrict__ h, int K)
{
    __shared__ __align__(16) char smem[36864];
    unsigned short (*Ash)[64] = (unsigned short(*)[64])smem;               // 32 x 64
    unsigned short (*Bsh)[64] = (unsigned short(*)[64])(smem + 4096);      // 256 x 64
    float (*vals)[264] = (float(*)[264])smem;                              // 32 x 264 (33792B)
    const int t = threadIdx.x;
    const int r0 = blockIdx.x * 32;
    const int wid = t >> 6, lane = t & 63;
    const int lrow = lane & 15, lk8 = (lane >> 4) * 8;
    const int xsw = (lrow & 7) << 3;
    const int srcsw = ((lane & 7) ^ (lane >> 3)) << 3;
    f32x4 acc[2][2] = {};
    for (int k0 = 0; k0 < K; k0 += 64) {
        __syncthreads();
        if (wid < 4) {   // A: waves 0-3 stage rows wid*8 .. +7
            GLOAD16(A + (size_t)(r0 + wid * 8 + (lane >> 3)) * K + k0 + srcsw, &Ash[wid * 8][0]);
        }
        {   // B: all 8 waves, rows wid*32 + i*8
            const unsigned short* gb = WT + (size_t)(wid * 32 + (lane >> 3)) * K + k0 + srcsw;
            unsigned short* lbp = &Bsh[wid * 32][0];
            #pragma unroll
            for (int i = 0; i < 4; i++)
                GLOAD16(gb + (size_t)(i * 8) * K, lbp + i * 8 * 64);
        }
        __syncthreads();
        #pragma unroll
        for (int ks = 0; ks < 2; ks++) {
            bf16x8 a0 = *(const bf16x8*)&Ash[lrow][(ks * 32 + lk8) ^ xsw];
            bf16x8 a1 = *(const bf16x8*)&Ash[16 + lrow][(ks * 32 + lk8) ^ xsw];
            #pragma unroll
            for (int nf = 0; nf < 2; nf++) {
                bf16x8 bfr = *(const bf16x8*)&Bsh[wid * 32 + nf * 16 + lrow][(ks * 32 + lk8) ^ xsw];
                acc[0][nf] = __builtin_amdgcn_mfma_f32_16x16x32_bf16(a0, bfr, acc[0][nf], 0, 0, 0);
                acc[1][nf] = __builtin_amdgcn_mfma_f32_16x16x32_bf16(a1, bfr, acc[1][nf], 0, 0, 0);
            }
        }
    }
    __syncthreads();
    #pragma unroll
    for (int m = 0; m < 2; m++)
        #pragma unroll
        for (int nf = 0; nf < 2; nf++) {
            int col = wid * 32 + nf * 16 + lrow;
            float bv = bias[col];
            #pragma unroll
            for (int r = 0; r < 4; r++) {
                int row = m * 16 + (lane >> 4) * 4 + r;
                vals[row][col] = acc[m][nf][r] + bv + res[(size_t)(r0 + row) * 256 + col];
            }
        }
    __syncthreads();
    const int row = t >> 4, c4 = (t & 15) * 4;
    float s = 0.f, sq = 0.f;
    #pragma unroll
    for (int j = 0; j < 4; j++) {
        float4 v4 = *(const float4*)&vals[row][c4 + j * 64];
        s += v4.x + v4.y + v4.z + v4.w;
        sq += v4.x * v4.x + v4.y * v4.y + v4.z * v4.z + v4.w * v4.w;
    }
    s += __shfl_xor(s, 1); sq += __shfl_xor(sq, 1);
    s += __shfl_xor(s, 2); sq += __shfl_xor(sq, 2);
    s += __shfl_xor(s, 4); sq += __shfl_xor(sq, 4);
    s += __shfl_xor(s, 8); sq += __shfl_xor(sq, 8);
    float mean = s * (1.f / 256.f);
    float rs = rsqrtf(sq * (1.f / 256.f) - mean * mean + 1e-5f);
    const size_t gbase = (size_t)(r0 + row) * 256;
    #pragma unroll
    for (int j = 0; j < 4; j++) {
        int col = c4 + j * 64;
        float4 v4 = *(const float4*)&vals[row][col];
        *(float4*)(xnew + gbase + col) = v4;
        if (lng) {
            float4 g4 = *(const float4*)(lng + col);
            float4 b4 = *(const float4*)(lnb + col);
            ushort4 o;
            o.x = f2b((v4.x - mean) * rs * g4.x + b4.x);
            o.y = f2b((v4.y - mean) * rs * g4.y + b4.y);
            o.z = f2b((v4.z - mean) * rs * g4.z + b4.z);
            o.w = f2b((v4.w - mean) * rs * g4.w + b4.w);
            *(ushort4*)(h + gbase + col) = o;
        }
    }
}

// =============== GN2 ===============
__global__ __launch_bounds__(256) void k_gn2(
    const float* __restrict__ din, const float* __restrict__ g2, const float* __restrict__ be2,
    unsigned short* __restrict__ dout)
{
    const int t = threadIdx.x;
    const int w = t >> 6, lane = t & 63;
    const int p = blockIdx.x * 2 + (w >> 1), g = w & 1;
    float4 v = ((const float4*)(din + (size_t)p * 512 + g * 256))[lane];
    float s = v.x + v.y + v.z + v.w;
    float sq = v.x * v.x + v.y * v.y + v.z * v.z + v.w * v.w;
    #pragma unroll
    for (int m = 1; m < 64; m <<= 1) { s += __shfl_xor(s, m, 64); sq += __shfl_xor(sq, m, 64); }
    float mean = s * (1.f / 256.f);
    float rs = rsqrtf(sq * (1.f / 256.f) - mean * mean + 1e-5f);
    int oc = g * 32 + (lane >> 1);
    float gg = g2[oc], bb = be2[oc];
    ushort4 o;
    o.x = f2b((v.x - mean) * rs * gg + bb);
    o.y = f2b((v.y - mean) * rs * gg + bb);
    o.z = f2b((v.z - mean) * rs * gg + bb);
    o.w = f2b((v.w - mean) * rs * gg + bb);
    ((ushort4*)(dout + (size_t)p * 512 + g * 256))[lane] = o;
}

// ====== LN(u)+LN(pos) -> xb f32, and hb = LN_{l1[0]}(xb) bf16. Wave per row. ======
__global__ __launch_bounds__(256) void k_lnpos(
    const float* __restrict__ u, const float* __restrict__ pos,
    const float* __restrict__ lndg, const float* __restrict__ lndb,
    const float* __restrict__ lnpg, const float* __restrict__ lnpb,
    const float* __restrict__ l1g0, const float* __restrict__ l1b0,
    float* __restrict__ xb, unsigned short* __restrict__ hb)
{
    const int t = threadIdx.x;
    const int row = blockIdx.x * 4 + (t >> 6);
    const int lane = t & 63;
    float4 v = ((const float4*)(u + (size_t)row * 256))[lane];
    float4 w = ((const float4*)(pos + (size_t)(row & 511) * 256))[lane];
    float s = v.x + v.y + v.z + v.w;
    float sq = v.x * v.x + v.y * v.y + v.z * v.z + v.w * v.w;
    float sp = w.x + w.y + w.z + w.w;
    float qp = w.x * w.x + w.y * w.y + w.z * w.z + w.w * w.w;
    #pragma unroll
    for (int m = 1; m < 64; m <<= 1) {
        s += __shfl_xor(s, m, 64); sq += __shfl_xor(sq, m, 64);
        sp += __shfl_xor(sp, m, 64); qp += __shfl_xor(qp, m, 64);
    }
    float mu = s * (1.f / 256.f), ru = rsqrtf(sq * (1.f / 256.f) - mu * mu + 1e-5f);
    float mp = sp * (1.f / 256.f), rp = rsqrtf(qp * (1.f / 256.f) - mp * mp + 1e-5f);
    float4 ga = ((const float4*)lndg)[lane], ba = ((const float4*)lndb)[lane];
    float4 gp = ((const float4*)lnpg)[lane], bp = ((const float4*)lnpb)[lane];
    float4 o;
    o.x = (v.x - mu) * ru * ga.x + ba.x + (w.x - mp) * rp * gp.x + bp.x;
    o.y = (v.y - mu) * ru * ga.y + ba.y + (w.y - mp) * rp * gp.y + bp.y;
    o.z = (v.z - mu) * ru * ga.z + ba.z + (w.z - mp) * rp * gp.z + bp.z;
    o.w = (v.w - mu) * ru * ga.w + ba.w + (w.w - mp) * rp * gp.w + bp.w;
    ((float4*)(xb + (size_t)row * 256))[lane] = o;
    float s2 = o.x + o.y + o.z + o.w;
    float q2 = o.x * o.x + o.y * o.y + o.z * o.z + o.w * o.w;
    #pragma unroll
    for (int m = 1; m < 64; m <<= 1) { s2 += __shfl_xor(s2, m, 64); q2 += __shfl_xor(q2, m, 64); }
    float mu2 = s2 * (1.f / 256.f), r2 = rsqrtf(q2 * (1.f / 256.f) - mu2 * mu2 + 1e-5f);
    float4 g4 = ((const float4*)l1g0)[lane], b4 = ((const float4*)l1b0)[lane];
    ushort4 ho;
    ho.x = f2b((o.x - mu2) * r2 * g4.x + b4.x);
    ho.y = f2b((o.y - mu2) * r2 * g4.y + b4.y);
    ho.z = f2b((o.z - mu2) * r2 * g4.z + b4.z);
    ho.w = f2b((o.w - mu2) * r2 * g4.w + b4.w);
    ((ushort4*)(hb + (size_t)row * 256))[lane] = ho;
}

// ====== MFMA flash attention: qkv bf16 [8192][768] -> o bf16 [8192][256] ======
__global__ __launch_bounds__(256) void k_attn3(
    const unsigned short* __restrict__ qkv, unsigned short* __restrict__ og)
{
    __shared__ unsigned short Ks[64][36];
    __shared__ unsigned short Vt[32][72];
    __shared__ unsigned short Pt[4][16][72];
    const int t = threadIdx.x;
    const int bid = blockIdx.x;
    const int b = bid >> 6, hh = (bid >> 3) & 7, qt = bid & 7;
    const int wid = t >> 6, lane = t & 63;
    const int lr = lane & 15, lk8 = (lane >> 4) * 8;
    const int qrow = b * 512 + qt * 64 + wid * 16 + lr;
    const bf16x8 qf = *(const bf16x8*)(qkv + (size_t)qrow * 768 + hh * 32 + lk8);
    f32x4 O0 = {}, O1 = {};
    float mreg[4] = { -1e30f, -1e30f, -1e30f, -1e30f };
    float lreg[4] = {};
    const float scale = 0.17677669529663687f;
    for (int kv0 = 0; kv0 < 512; kv0 += 64) {
        __syncthreads();
        {
            int kvr = t >> 2, dd = (t & 3) * 8;
            size_t base = (size_t)(b * 512 + kv0 + kvr) * 768 + hh * 32;
            *(bf16x8*)&Ks[kvr][dd] = *(const bf16x8*)(qkv + base + 256 + dd);
            bf16x8 v8 = *(const bf16x8*)(qkv + base + 512 + dd);
            #pragma unroll
            for (int j = 0; j < 8; j++) Vt[dd + j][kvr] = (unsigned short)v8[j];
        }
        __syncthreads();
        f32x4 st[4];
        #pragma unroll
        for (int tt = 0; tt < 4; tt++) {
            bf16x8 kf = *(const bf16x8*)&Ks[tt * 16 + lr][lk8];
            st[tt] = __builtin_amdgcn_mfma_f32_16x16x32_bf16(qf, kf, (f32x4){}, 0, 0, 0);
        }
        float mnew[4], csc[4], psum[4];
        #pragma unroll
        for (int r = 0; r < 4; r++) {
            st[0][r] *= scale; st[1][r] *= scale; st[2][r] *= scale; st[3][r] *= scale;
            float mx = fmaxf(fmaxf(st[0][r], st[1][r]), fmaxf(st[2][r], st[3][r]));
            mx = fmaxf(mx, __shfl_xor(mx, 1));
            mx = fmaxf(mx, __shfl_xor(mx, 2));
            mx = fmaxf(mx, __shfl_xor(mx, 4));
            mx = fmaxf(mx, __shfl_xor(mx, 8));
            mnew[r] = fmaxf(mreg[r], mx);
            csc[r] = __expf(mreg[r] - mnew[r]);
            mreg[r] = mnew[r];
            psum[r] = 0.f;
        }
        #pragma unroll
        for (int tt = 0; tt < 4; tt++)
            #pragma unroll
            for (int r = 0; r < 4; r++) {
                float p = __expf(st[tt][r] - mnew[r]);
                st[tt][r] = p;
                psum[r] += p;
            }
        #pragma unroll
        for (int r = 0; r < 4; r++) {
            psum[r] += __shfl_xor(psum[r], 1);
            psum[r] += __shfl_xor(psum[r], 2);
            psum[r] += __shfl_xor(psum[r], 4);
            psum[r] += __shfl_xor(psum[r], 8);
            lreg[r] = lreg[r] * csc[r] + psum[r];
            O0[r] *= csc[r]; O1[r] *= csc[r];
        }
        #pragma unroll
        for (int tt = 0; tt < 4; tt++)
            #pragma unroll
            for (int r = 0; r < 4; r++)
                Pt[wid][(lane >> 4) * 4 + r][tt * 16 + lr] = f2b(st[tt][r]);
        #pragma unroll
        for (int half = 0; half < 2; half++) {
            bf16x8 pa  = *(const bf16x8*)&Pt[wid][lr][half * 32 + lk8];
            bf16x8 vlo = *(const bf16x8*)&Vt[lr][half * 32 + lk8];
            bf16x8 vhi = *(const bf16x8*)&Vt[16 + lr][half * 32 + lk8];
            O0 = __builtin_amdgcn_mfma_f32_16x16x32_bf16(pa, vlo, O0, 0, 0, 0);
            O1 = __builtin_amdgcn_mfma_f32_16x16x32_bf16(pa, vhi, O1, 0, 0, 0);
        }
    }
    #pragma unroll
    for (int r = 0; r < 4; r++) {
        float inv = 1.f / lreg[r];
        size_t orow = (size_t)(b * 512 + qt * 64 + wid * 16 + (lane >> 4) * 4 + r) * 256 + hh * 32;
        og[orow + lr] = f2b(O0[r] * inv);
        og[orow + 16 + lr] = f2b(O1[r] * inv);
    }
}

extern "C" void kernel_launch(void* const* d_in, const int* in_sizes, int n_in,
                              void* d_out, int out_size, void* d_ws, size_t ws_size,
                              hipStream_t stream)
{
    const float* img  = (const float*)d_in[0];
    const float* bfac = (const float*)d_in[1];
    const float* w0  = (const float*)d_in[2];  const float* b0c = (const float*)d_in[3];
    const float* g1  = (const float*)d_in[4];  const float* be1 = (const float*)d_in[5];
    const float* w1  = (const float*)d_in[6];  const float* b1c = (const float*)d_in[7];
    const float* g2  = (const float*)d_in[8];  const float* be2 = (const float*)d_in[9];
    const float* w2  = (const float*)d_in[10]; const float* b2c = (const float*)d_in[11];
    const float* g3  = (const float*)d_in[12]; const float* be3 = (const float*)d_in[13];
    const float* wu  = (const float*)d_in[14]; const float* bu  = (const float*)d_in[15];
    const float* pos = (const float*)d_in[16];
    const float* lndg = (const float*)d_in[17]; const float* lndb = (const float*)d_in[18];
    const float* lnpg = (const float*)d_in[19]; const float* lnpb = (const float*)d_in[20];
    const float* Wq = (const float*)d_in[21]; const float* bq = (const float*)d_in[22];
    const float* Wk = (const float*)d_in[23]; const float* bk = (const float*)d_in[24];
    const float* Wv = (const float*)d_in[25]; const float* bv = (const float*)d_in[26];
    const float* Wo = (const float*)d_in[27]; const float* bo = (const float*)d_in[28];
    const float* l1g = (const float*)d_in[29]; const float* l1b = (const float*)d_in[30];
    const float* l2g = (const float*)d_in[31]; const float* l2b = (const float*)d_in[32];
    const float* W1 = (const float*)d_in[33]; const float* bf1 = (const float*)d_in[34];
    const float* W2 = (const float*)d_in[35]; const float* bf2 = (const float*)d_in[36];

    float* ws = (float*)d_ws;
    unsigned short* d0b   = (unsigned short*)(ws);              // [8192][2048] bf16
    float*          d1raw = ws + 8388608;                       // [8192][512] f32
    unsigned short* d1b   = (unsigned short*)(ws + 12582912);   // [8192][512] bf16
    float*          xb    = ws + 14680064;                      // [8192][256] f32
    unsigned short* w1T   = (unsigned short*)(ws + 16777216);
    unsigned short* w2T   = (unsigned short*)(ws + 17301504);
    unsigned short* wuTb  = (unsigned short*)(ws + 17334272);
    unsigned short* WqkvT = (unsigned short*)(ws + 17350656);   // 8x768x256
    unsigned short* WoT   = (unsigned short*)(ws + 18137088);
    unsigned short* W1T   = (unsigned short*)(ws + 18399232);
    unsigned short* W2T   = (unsigned short*)(ws + 19447808);
    float*          b1x   = ws + 20496384;
    float*          bqkv  = ws + 20496896;
    // Phase C overlay (d0b dead after conv1 GEMM):
    unsigned short* d2b   = (unsigned short*)(ws + 1048576);    // [8192][128] bf16
    float*          ub    = ws + 1572864;                       // [8192][256] f32
    // Phase D overlay:
    unsigned short* hb    = (unsigned short*)(ws);              // [8192][256] bf16
    unsigned short* qkvb  = (unsigned short*)(ws + 1048576);    // [8192][768] bf16
    unsigned short* obb   = (unsigned short*)(ws + 4194304);    // [8192][256] bf16
    unsigned short* m1b   = (unsigned short*)(ws + 5242880);    // [8192][1024] bf16
    float* xout = (float*)d_out;

    // Weight prep: ONE launch
    k_prep_all<<<29058, 256, 0, stream>>>(w1, w2, wu, b1c, Wq, Wk, Wv, bq, bk, bv, Wo, W1, W2,
                                          w1T, w2T, wuTb, b1x, WqkvT, bqkv, WoT, W1T, W2T);

    // Encoder
    k_blur_conv0<<<8192, 256, 0, stream>>>(img, bfac, w0, b0c, g1, be1, d0b);
    k_gemm_bf16<128><<<8 * 64, 256, 0, stream>>>(d0b, w1T, b1x, nullptr, d1raw, 8, 512, 2048, 2, 0);
    k_gn2<<<4096, 256, 0, stream>>>(d1raw, g2, be2, d1b);
    k_gemm_gn<<<256, 512, 0, stream>>>(d1b, w2T, b2c, g3, be3, d2b);
    k_gemm_bf16<128><<<4 * 64, 256, 0, stream>>>(d2b, wuTb, bu, nullptr, ub, 4, 256, 128, 0, 0);
    k_lnpos<<<2048, 256, 0, stream>>>(ub, pos, lndg, lndb, lnpg, lnpb, l1g, l1b, xb, hb);

    // Transformer: per layer {qkv, attn, Wo+res+LN(l2), W1(gelu), W2+res+LN(next l1)}
    for (int i = 0; i < 8; i++) {
        k_gemm_bf16<128><<<12 * 64, 256, 0, stream>>>(hb, WqkvT + (size_t)i * 196608, bqkv + i * 768, nullptr, qkvb, 12, 768, 256, 0, 1);
        k_attn3<<<1024, 256, 0, stream>>>(qkvb, obb);
        k_gemm_ln<<<256, 512, 0, stream>>>(obb, WoT + (size_t)i * 65536, bo + i * 256, xb,
                                           l2g + i * 256, l2b + i * 256, xb, hb, 256);
        k_gemm_bf16<128><<<16 * 64, 256, 0, stream>>>(hb, W1T + (size_t)i * 262144, bf1 + i * 1024, nullptr, m1b, 16, 1024, 256, 1, 1);
        if (i < 7) {
            k_gemm_ln<<<256, 512, 0, stream>>>(m1b, W2T + (size_t)i * 262144, bf2 + i * 256, xb,
                                               l1g + (i + 1) * 256, l1b + (i + 1) * 256, xb, hb, 1024);
        } else {
            k_gemm_ln<<<256, 512, 0, stream>>>(m1b, W2T + (size_t)i * 262144, bf2 + i * 256, xb,
                                               nullptr, nullptr, xout, nullptr, 1024);
        }
    }
}